// Round 1
// baseline (2736.997 us; speedup 1.0000x reference)
//
#include <hip/hip_runtime.h>
#include <math.h>

#define DM   1024   // d_model
#define DI   2048   // d_inner
#define DST  16     // d_state
#define DTR  64     // dt_rank
#define LSEQ 1024   // L
#define NBAT 2      // B
#define BLROWS (NBAT*LSEQ)   // 2048 token rows

__device__ __forceinline__ float silu_f(float x) {
    return x / (1.f + expf(-x));
}
__device__ __forceinline__ float softplus_f(float x) {
    return (x > 20.f) ? x : log1pf(expf(x));
}

// ---------------------------------------------------------------------------
// LayerNorm: one block per token row (1024 elems), 256 threads.
// ---------------------------------------------------------------------------
__global__ __launch_bounds__(256) void ln_kernel(const float* __restrict__ x,
                                                 const float* __restrict__ g,
                                                 const float* __restrict__ b,
                                                 float* __restrict__ xn) {
    int row = blockIdx.x;
    const float* xr = x + (size_t)row * DM;
    float v[4];
    float s = 0.f, s2 = 0.f;
#pragma unroll
    for (int i = 0; i < 4; i++) {
        v[i] = xr[threadIdx.x + i * 256];
        s += v[i];
        s2 += v[i] * v[i];
    }
    // wave (64) reduce
#pragma unroll
    for (int off = 32; off; off >>= 1) {
        s  += __shfl_down(s, off);
        s2 += __shfl_down(s2, off);
    }
    __shared__ float ss[4], ss2[4];
    int wid = threadIdx.x >> 6, lane = threadIdx.x & 63;
    if (lane == 0) { ss[wid] = s; ss2[wid] = s2; }
    __syncthreads();
    if (threadIdx.x == 0) {
        float a = 0.f, a2 = 0.f;
#pragma unroll
        for (int i = 0; i < 4; i++) { a += ss[i]; a2 += ss2[i]; }
        ss[0] = a; ss2[0] = a2;
    }
    __syncthreads();
    float m   = ss[0] * (1.f / DM);
    float var = ss2[0] * (1.f / DM) - m * m;
    float inv = rsqrtf(var + 1e-5f);
#pragma unroll
    for (int i = 0; i < 4; i++) {
        int c = threadIdx.x + i * 256;
        xn[(size_t)row * DM + c] = (v[i] - m) * inv * g[c] + b[c];
    }
}

// ---------------------------------------------------------------------------
// Generic f32 NT GEMM: C[m,n] = sum_k A[m*lda+k] * W[n*ldw+k]  (+ epilogue)
// BM=BN=64, BK=16, 256 threads, 4x4 accum per thread.
// MODE 0: store   MODE 1: softplus(acc + bias[n])
// MODE 2: C = resid + acc   MODE 3: C += acc
// M must be a multiple of 64 and K a multiple of 16 (true for all uses).
// ---------------------------------------------------------------------------
template <int MODE>
__global__ __launch_bounds__(256) void gemm_nt(const float* __restrict__ A, int lda,
                                               const float* __restrict__ W, int ldw,
                                               const float* __restrict__ bias,
                                               const float* __restrict__ resid,
                                               float* __restrict__ C, int ldc,
                                               int M, int N, int K) {
    __shared__ float As[16][64];
    __shared__ float Ws[16][64];

    int tid  = threadIdx.x;
    int tx   = tid & 15;       // n quad
    int ty   = tid >> 4;       // m quad
    int m0   = blockIdx.y * 64;
    int n0   = blockIdx.x * 64;
    int lrow = tid >> 2;       // 0..63 tile row for loads
    int kgrp = (tid & 3) * 4;  // 0,4,8,12

    float acc[4][4] = {};

    for (int k0 = 0; k0 < K; k0 += 16) {
        // load A tile (64 rows x 16 k), transposed into As[k][m]
        {
            const float* p = A + (size_t)(m0 + lrow) * lda + k0 + kgrp;
            float4 a4 = *reinterpret_cast<const float4*>(p);
            As[kgrp + 0][lrow] = a4.x;
            As[kgrp + 1][lrow] = a4.y;
            As[kgrp + 2][lrow] = a4.z;
            As[kgrp + 3][lrow] = a4.w;
        }
        // load W tile (64 n-rows x 16 k), transposed into Ws[k][n]
        {
            int n = n0 + lrow;
            float4 w4 = make_float4(0.f, 0.f, 0.f, 0.f);
            if (n < N) {
                const float* p = W + (size_t)n * ldw + k0 + kgrp;
                w4 = *reinterpret_cast<const float4*>(p);
            }
            Ws[kgrp + 0][lrow] = w4.x;
            Ws[kgrp + 1][lrow] = w4.y;
            Ws[kgrp + 2][lrow] = w4.z;
            Ws[kgrp + 3][lrow] = w4.w;
        }
        __syncthreads();
#pragma unroll
        for (int kk = 0; kk < 16; kk++) {
            float4 av = *reinterpret_cast<const float4*>(&As[kk][ty * 4]);
            float4 wv = *reinterpret_cast<const float4*>(&Ws[kk][tx * 4]);
            float am[4] = {av.x, av.y, av.z, av.w};
            float wn[4] = {wv.x, wv.y, wv.z, wv.w};
#pragma unroll
            for (int i = 0; i < 4; i++)
#pragma unroll
                for (int j = 0; j < 4; j++)
                    acc[i][j] = fmaf(am[i], wn[j], acc[i][j]);
        }
        __syncthreads();
    }

#pragma unroll
    for (int i = 0; i < 4; i++) {
        int m = m0 + ty * 4 + i;
#pragma unroll
        for (int j = 0; j < 4; j++) {
            int n = n0 + tx * 4 + j;
            if (n >= N) continue;
            size_t off = (size_t)m * ldc + n;
            float v = acc[i][j];
            if (MODE == 0) {
                C[off] = v;
            } else if (MODE == 1) {
                C[off] = softplus_f(v + bias[n]);
            } else if (MODE == 2) {
                C[off] = resid[off] + v;
            } else { // MODE 3
                C[off] += v;
            }
        }
    }
}

// ---------------------------------------------------------------------------
// Causal conv1d (k=4) + SiLU over the u half of U (cols [0,2048)).
// dir=0: taps u[t-3+k]*w[k]   dir=1 (time-reversed branch, original coords):
//        taps u[t+3-k]*w[k]
// ---------------------------------------------------------------------------
__global__ __launch_bounds__(256) void conv_silu_kernel(const float* __restrict__ U,
                                                        const float* __restrict__ cw,
                                                        const float* __restrict__ cb,
                                                        float* __restrict__ uc,
                                                        int dir) {
    int idx = blockIdx.x * 256 + threadIdx.x;       // over 2*1024*2048
    int c = idx & (DI - 1);
    int t = (idx >> 11) & (LSEQ - 1);
    int b = idx >> 21;
    float acc = cb[c];
#pragma unroll
    for (int k = 0; k < 4; k++) {
        int tt = dir ? (t + 3 - k) : (t - 3 + k);
        if (tt >= 0 && tt < LSEQ)
            acc = fmaf(cw[c * 4 + k], U[((size_t)(b * LSEQ + tt)) * (2 * DI) + c], acc);
    }
    uc[idx] = silu_f(acc);
}

// ---------------------------------------------------------------------------
// Selective scan. 16 lanes per (b,c) channel, one state per lane.
// block = 256 threads = 16 channel groups; grid = 4096/16 = 256 blocks.
// dir=0: t = 0..L-1 ; dir=1: t = L-1..0 (results written at original t).
// Epilogue fused: y = (sum_n h_n*C_n) + u*D;  G = y * silu(z).
// ---------------------------------------------------------------------------
__global__ __launch_bounds__(256) void scan_kernel(const float* __restrict__ dtv,
                                                   const float* __restrict__ uc,
                                                   const float* __restrict__ dbc,
                                                   const float* __restrict__ U,
                                                   const float* __restrict__ A_log,
                                                   const float* __restrict__ Dp,
                                                   float* __restrict__ G,
                                                   int dir) {
    int gid = blockIdx.x * 16 + (threadIdx.x >> 4);   // 0..4095
    int n   = threadIdx.x & 15;
    int b   = gid >> 11;
    int c   = gid & (DI - 1);

    float A  = -expf(A_log[c * DST + n]);
    float Dv = Dp[c];
    float h  = 0.f;

    for (int s = 0; s < LSEQ; s++) {
        int t = dir ? (LSEQ - 1 - s) : s;
        size_t row = (size_t)b * LSEQ + t;
        float dt = dtv[row * DI + c];
        float u  = uc[row * DI + c];
        float Bn = dbc[row * 96 + DTR + n];
        float Cn = dbc[row * 96 + DTR + DST + n];
        h = expf(dt * A) * h + dt * u * Bn;
        float y = h * Cn;
#pragma unroll
        for (int m = 8; m; m >>= 1) y += __shfl_xor(y, m);
        if (n == 0) {
            float yy = y + u * Dv;
            float z  = U[row * (2 * DI) + DI + c];
            G[row * DI + c] = yy * silu_f(z);
        }
    }
}

// ---------------------------------------------------------------------------
extern "C" void kernel_launch(void* const* d_in, const int* in_sizes, int n_in,
                              void* d_out, int out_size, void* d_ws, size_t ws_size,
                              hipStream_t stream) {
    const float* x    = (const float*)d_in[0];
    const float* ln_g = (const float*)d_in[1];
    const float* ln_b = (const float*)d_in[2];
    float* out = (float*)d_out;

    float* ws  = (float*)d_ws;
    float* xn  = ws;                    // 2,097,152
    float* U   = xn  + (size_t)BLROWS * DM;        // 2048*4096 = 8,388,608
    float* uc  = U   + (size_t)BLROWS * 2 * DI;    // 4,194,304
    float* dbc = uc  + (size_t)BLROWS * DI;        // 2048*96
    float* dtv = dbc + (size_t)BLROWS * 96;        // 4,194,304
    float* G   = dtv + (size_t)BLROWS * DI;        // 4,194,304

    ln_kernel<<<BLROWS, 256, 0, stream>>>(x, ln_g, ln_b, xn);

    for (int br = 0; br < 2; br++) {
        const float* in_w    = (const float*)d_in[3 + 9 * br + 0];
        const float* conv_w  = (const float*)d_in[3 + 9 * br + 1];
        const float* conv_b  = (const float*)d_in[3 + 9 * br + 2];
        const float* xproj_w = (const float*)d_in[3 + 9 * br + 3];
        const float* dt_w    = (const float*)d_in[3 + 9 * br + 4];
        const float* dt_b    = (const float*)d_in[3 + 9 * br + 5];
        const float* A_log   = (const float*)d_in[3 + 9 * br + 6];
        const float* Dp      = (const float*)d_in[3 + 9 * br + 7];
        const float* out_w   = (const float*)d_in[3 + 9 * br + 8];

        // U = xn @ in_w.T   (2048 x 1024 x 4096)
        gemm_nt<0><<<dim3(2 * DI / 64, BLROWS / 64), 256, 0, stream>>>(
            xn, DM, in_w, DM, nullptr, nullptr, U, 2 * DI, BLROWS, 2 * DI, DM);

        // uc = silu(conv1d(u) + cb)
        conv_silu_kernel<<<(BLROWS * DI) / 256, 256, 0, stream>>>(U, conv_w, conv_b, uc, br);

        // dbc = uc @ xproj_w.T   (2048 x 2048 x 96)
        gemm_nt<0><<<dim3((96 + 63) / 64, BLROWS / 64), 256, 0, stream>>>(
            uc, DI, xproj_w, DI, nullptr, nullptr, dbc, 96, BLROWS, 96, DI);

        // dtv = softplus(dbc[:, :64] @ dt_w.T + dt_b)   (2048 x 64 x 2048)
        gemm_nt<1><<<dim3(DI / 64, BLROWS / 64), 256, 0, stream>>>(
            dbc, 96, dt_w, DTR, dt_b, nullptr, dtv, DI, BLROWS, DI, DTR);

        // selective scan + gating -> G
        scan_kernel<<<(NBAT * DI) / 16, 256, 0, stream>>>(dtv, uc, dbc, U, A_log, Dp, G, br);

        // out (+)= G @ out_w.T  (+ x residual on first branch)
        if (br == 0) {
            gemm_nt<2><<<dim3(DM / 64, BLROWS / 64), 256, 0, stream>>>(
                G, DI, out_w, DI, nullptr, x, out, DM, BLROWS, DM, DI);
        } else {
            gemm_nt<3><<<dim3(DM / 64, BLROWS / 64), 256, 0, stream>>>(
                G, DI, out_w, DI, nullptr, nullptr, out, DM, BLROWS, DM, DI);
        }
    }
}

// Round 2
// 1464.806 us; speedup vs baseline: 1.8685x; 1.8685x over previous
//
#include <hip/hip_runtime.h>
#include <math.h>

#define DM   1024   // d_model
#define DI   2048   // d_inner
#define DST  16     // d_state
#define DTR  64     // dt_rank
#define LSEQ 1024   // L
#define NBAT 2      // B
#define BLROWS (NBAT*LSEQ)   // 2048 token rows
#define NCHUNK 16
#define CLEN   64   // LSEQ / NCHUNK

__device__ __forceinline__ float silu_f(float x) {
    return x / (1.f + expf(-x));
}
__device__ __forceinline__ float softplus_f(float x) {
    return (x > 20.f) ? x : log1pf(expf(x));
}

// ---------------------------------------------------------------------------
// LayerNorm: one block per token row (1024 elems), 256 threads.
// ---------------------------------------------------------------------------
__global__ __launch_bounds__(256) void ln_kernel(const float* __restrict__ x,
                                                 const float* __restrict__ g,
                                                 const float* __restrict__ b,
                                                 float* __restrict__ xn) {
    int row = blockIdx.x;
    const float* xr = x + (size_t)row * DM;
    float v[4];
    float s = 0.f, s2 = 0.f;
#pragma unroll
    for (int i = 0; i < 4; i++) {
        v[i] = xr[threadIdx.x + i * 256];
        s += v[i];
        s2 += v[i] * v[i];
    }
#pragma unroll
    for (int off = 32; off; off >>= 1) {
        s  += __shfl_down(s, off);
        s2 += __shfl_down(s2, off);
    }
    __shared__ float ss[4], ss2[4];
    int wid = threadIdx.x >> 6, lane = threadIdx.x & 63;
    if (lane == 0) { ss[wid] = s; ss2[wid] = s2; }
    __syncthreads();
    if (threadIdx.x == 0) {
        float a = 0.f, a2 = 0.f;
#pragma unroll
        for (int i = 0; i < 4; i++) { a += ss[i]; a2 += ss2[i]; }
        ss[0] = a; ss2[0] = a2;
    }
    __syncthreads();
    float m   = ss[0] * (1.f / DM);
    float var = ss2[0] * (1.f / DM) - m * m;
    float inv = rsqrtf(var + 1e-5f);
#pragma unroll
    for (int i = 0; i < 4; i++) {
        int c = threadIdx.x + i * 256;
        xn[(size_t)row * DM + c] = (v[i] - m) * inv * g[c] + b[c];
    }
}

// ---------------------------------------------------------------------------
// Generic f32 NT GEMM: C[m,n] = sum_k A[m*lda+k] * W[n*ldw+k]  (+ epilogue)
// BM=BN=64, BK=16, 256 threads, 4x4 accum per thread.
// MODE 0: store   MODE 1: softplus(acc + bias[n])
// MODE 2: C = resid + acc   MODE 3: C += acc
// ---------------------------------------------------------------------------
template <int MODE>
__global__ __launch_bounds__(256) void gemm_nt(const float* __restrict__ A, int lda,
                                               const float* __restrict__ W, int ldw,
                                               const float* __restrict__ bias,
                                               const float* __restrict__ resid,
                                               float* __restrict__ C, int ldc,
                                               int M, int N, int K) {
    __shared__ float As[16][64];
    __shared__ float Ws[16][64];

    int tid  = threadIdx.x;
    int tx   = tid & 15;       // n quad
    int ty   = tid >> 4;       // m quad
    int m0   = blockIdx.y * 64;
    int n0   = blockIdx.x * 64;
    int lrow = tid >> 2;       // 0..63 tile row for loads
    int kgrp = (tid & 3) * 4;  // 0,4,8,12

    float acc[4][4] = {};

    for (int k0 = 0; k0 < K; k0 += 16) {
        {
            const float* p = A + (size_t)(m0 + lrow) * lda + k0 + kgrp;
            float4 a4 = *reinterpret_cast<const float4*>(p);
            As[kgrp + 0][lrow] = a4.x;
            As[kgrp + 1][lrow] = a4.y;
            As[kgrp + 2][lrow] = a4.z;
            As[kgrp + 3][lrow] = a4.w;
        }
        {
            int n = n0 + lrow;
            float4 w4 = make_float4(0.f, 0.f, 0.f, 0.f);
            if (n < N) {
                const float* p = W + (size_t)n * ldw + k0 + kgrp;
                w4 = *reinterpret_cast<const float4*>(p);
            }
            Ws[kgrp + 0][lrow] = w4.x;
            Ws[kgrp + 1][lrow] = w4.y;
            Ws[kgrp + 2][lrow] = w4.z;
            Ws[kgrp + 3][lrow] = w4.w;
        }
        __syncthreads();
#pragma unroll
        for (int kk = 0; kk < 16; kk++) {
            float4 av = *reinterpret_cast<const float4*>(&As[kk][ty * 4]);
            float4 wv = *reinterpret_cast<const float4*>(&Ws[kk][tx * 4]);
            float am[4] = {av.x, av.y, av.z, av.w};
            float wn[4] = {wv.x, wv.y, wv.z, wv.w};
#pragma unroll
            for (int i = 0; i < 4; i++)
#pragma unroll
                for (int j = 0; j < 4; j++)
                    acc[i][j] = fmaf(am[i], wn[j], acc[i][j]);
        }
        __syncthreads();
    }

#pragma unroll
    for (int i = 0; i < 4; i++) {
        int m = m0 + ty * 4 + i;
#pragma unroll
        for (int j = 0; j < 4; j++) {
            int n = n0 + tx * 4 + j;
            if (n >= N) continue;
            size_t off = (size_t)m * ldc + n;
            float v = acc[i][j];
            if (MODE == 0) {
                C[off] = v;
            } else if (MODE == 1) {
                C[off] = softplus_f(v + bias[n]);
            } else if (MODE == 2) {
                C[off] = resid[off] + v;
            } else { // MODE 3
                C[off] += v;
            }
        }
    }
}

// ---------------------------------------------------------------------------
// Causal conv1d (k=4) + SiLU over the u half of U (cols [0,2048)).
// ---------------------------------------------------------------------------
__global__ __launch_bounds__(256) void conv_silu_kernel(const float* __restrict__ U,
                                                        const float* __restrict__ cw,
                                                        const float* __restrict__ cb,
                                                        float* __restrict__ uc,
                                                        int dir) {
    int idx = blockIdx.x * 256 + threadIdx.x;       // over 2*1024*2048
    int c = idx & (DI - 1);
    int t = (idx >> 11) & (LSEQ - 1);
    int b = idx >> 21;
    float acc = cb[c];
#pragma unroll
    for (int k = 0; k < 4; k++) {
        int tt = dir ? (t + 3 - k) : (t - 3 + k);
        if (tt >= 0 && tt < LSEQ)
            acc = fmaf(cw[c * 4 + k], U[((size_t)(b * LSEQ + tt)) * (2 * DI) + c], acc);
    }
    uc[idx] = silu_f(acc);
}

// ---------------------------------------------------------------------------
// Chunked selective scan, 3 phases.
// Group = 16 lanes (one per state n) handling one (b, chunk, c).
// Block = 256 threads = 16 groups covering 16 consecutive channels c.
// gid = ((b*16 + chunk)*2048) + c  -> groups in a block share (b,chunk).
// sigma = logical scan step 0..1023; t = dir ? 1023-sigma : sigma.
// ---------------------------------------------------------------------------
__global__ __launch_bounds__(256) void scan_p1(const float* __restrict__ dtv,
                                               const float* __restrict__ uc,
                                               const float* __restrict__ dbc,
                                               const float* __restrict__ A_log,
                                               float* __restrict__ hend,
                                               float* __restrict__ Pprod,
                                               int dir) {
    int gid   = blockIdx.x * 16 + (threadIdx.x >> 4);
    int n     = threadIdx.x & 15;
    int c     = gid & (DI - 1);
    int chunk = (gid >> 11) & (NCHUNK - 1);
    int b     = gid >> 15;

    float A = -expf(A_log[c * DST + n]);
    float h = 0.f;
    float P = 1.f;

    int s0 = chunk * CLEN;
    for (int s = 0; s < CLEN; s++) {
        int sigma = s0 + s;
        int t = dir ? (LSEQ - 1 - sigma) : sigma;
        size_t row = (size_t)b * LSEQ + t;
        float dt = dtv[row * DI + c];
        float u  = uc[row * DI + c];
        float Bn = dbc[row * 96 + DTR + n];
        float dA = expf(dt * A);
        h = dA * h + dt * u * Bn;
        P *= dA;
    }
    size_t hidx = (size_t)gid * DST + n;
    hend[hidx]  = h;
    Pprod[hidx] = P;
}

// Combine: per (b,c,n), prefix over the 16 chunks -> initial state per chunk.
__global__ __launch_bounds__(256) void scan_p2(const float* __restrict__ hend,
                                               const float* __restrict__ Pprod,
                                               float* __restrict__ h0) {
    int id = blockIdx.x * 256 + threadIdx.x;     // 0 .. 2*2048*16-1
    size_t base = (size_t)(id & 32767) + (size_t)(id >> 15) * (NCHUNK * DI * DST);
    float h = 0.f;
#pragma unroll
    for (int k = 0; k < NCHUNK; k++) {
        size_t idx = base + (size_t)k * (DI * DST);
        h0[idx] = h;
        h = Pprod[idx] * h + hend[idx];
    }
}

__global__ __launch_bounds__(256) void scan_p3(const float* __restrict__ dtv,
                                               const float* __restrict__ uc,
                                               const float* __restrict__ dbc,
                                               const float* __restrict__ U,
                                               const float* __restrict__ A_log,
                                               const float* __restrict__ Dp,
                                               const float* __restrict__ h0,
                                               float* __restrict__ G,
                                               int dir) {
    int gid   = blockIdx.x * 16 + (threadIdx.x >> 4);
    int n     = threadIdx.x & 15;
    int c     = gid & (DI - 1);
    int chunk = (gid >> 11) & (NCHUNK - 1);
    int b     = gid >> 15;

    float A  = -expf(A_log[c * DST + n]);
    float Dv = Dp[c];
    float h  = h0[(size_t)gid * DST + n];

    int s0 = chunk * CLEN;
    for (int s = 0; s < CLEN; s++) {
        int sigma = s0 + s;
        int t = dir ? (LSEQ - 1 - sigma) : sigma;
        size_t row = (size_t)b * LSEQ + t;
        float dt = dtv[row * DI + c];
        float u  = uc[row * DI + c];
        float Bn = dbc[row * 96 + DTR + n];
        float Cn = dbc[row * 96 + DTR + DST + n];
        float dA = expf(dt * A);
        h = dA * h + dt * u * Bn;
        float y = h * Cn;
#pragma unroll
        for (int m = 8; m; m >>= 1) y += __shfl_xor(y, m);
        if (n == 0) {
            float yy = y + u * Dv;
            float z  = U[row * (2 * DI) + DI + c];
            G[row * DI + c] = yy * silu_f(z);
        }
    }
}

// ---------------------------------------------------------------------------
extern "C" void kernel_launch(void* const* d_in, const int* in_sizes, int n_in,
                              void* d_out, int out_size, void* d_ws, size_t ws_size,
                              hipStream_t stream) {
    const float* x    = (const float*)d_in[0];
    const float* ln_g = (const float*)d_in[1];
    const float* ln_b = (const float*)d_in[2];
    float* out = (float*)d_out;

    float* ws    = (float*)d_ws;
    float* xn    = ws;
    float* U     = xn    + (size_t)BLROWS * DM;
    float* uc    = U     + (size_t)BLROWS * 2 * DI;
    float* dbc   = uc    + (size_t)BLROWS * DI;
    float* dtv   = dbc   + (size_t)BLROWS * 96;
    float* G     = dtv   + (size_t)BLROWS * DI;
    float* hend  = G     + (size_t)BLROWS * DI;      // 2*16*2048*16 = 1M floats
    float* Pprod = hend  + (size_t)NBAT * NCHUNK * DI * DST;
    float* h0    = Pprod + (size_t)NBAT * NCHUNK * DI * DST;

    ln_kernel<<<BLROWS, 256, 0, stream>>>(x, ln_g, ln_b, xn);

    const int ngroups = NBAT * NCHUNK * DI;          // 65536

    for (int br = 0; br < 2; br++) {
        const float* in_w    = (const float*)d_in[3 + 9 * br + 0];
        const float* conv_w  = (const float*)d_in[3 + 9 * br + 1];
        const float* conv_b  = (const float*)d_in[3 + 9 * br + 2];
        const float* xproj_w = (const float*)d_in[3 + 9 * br + 3];
        const float* dt_w    = (const float*)d_in[3 + 9 * br + 4];
        const float* dt_b    = (const float*)d_in[3 + 9 * br + 5];
        const float* A_log   = (const float*)d_in[3 + 9 * br + 6];
        const float* Dp      = (const float*)d_in[3 + 9 * br + 7];
        const float* out_w   = (const float*)d_in[3 + 9 * br + 8];

        // U = xn @ in_w.T   (2048 x 4096 x 1024)
        gemm_nt<0><<<dim3(2 * DI / 64, BLROWS / 64), 256, 0, stream>>>(
            xn, DM, in_w, DM, nullptr, nullptr, U, 2 * DI, BLROWS, 2 * DI, DM);

        // uc = silu(conv1d(u) + cb)
        conv_silu_kernel<<<(BLROWS * DI) / 256, 256, 0, stream>>>(U, conv_w, conv_b, uc, br);

        // dbc = uc @ xproj_w.T   (2048 x 96 x 2048)
        gemm_nt<0><<<dim3((96 + 63) / 64, BLROWS / 64), 256, 0, stream>>>(
            uc, DI, xproj_w, DI, nullptr, nullptr, dbc, 96, BLROWS, 96, DI);

        // dtv = softplus(dbc[:, :64] @ dt_w.T + dt_b)   (2048 x 2048 x 64)
        gemm_nt<1><<<dim3(DI / 64, BLROWS / 64), 256, 0, stream>>>(
            dbc, 96, dt_w, DTR, dt_b, nullptr, dtv, DI, BLROWS, DI, DTR);

        // chunked selective scan + gating -> G
        scan_p1<<<ngroups / 16, 256, 0, stream>>>(dtv, uc, dbc, A_log, hend, Pprod, br);
        scan_p2<<<(NBAT * DI * DST) / 256, 256, 0, stream>>>(hend, Pprod, h0);
        scan_p3<<<ngroups / 16, 256, 0, stream>>>(dtv, uc, dbc, U, A_log, Dp, h0, G, br);

        // out (+)= G @ out_w.T  (+ x residual on first branch)
        if (br == 0) {
            gemm_nt<2><<<dim3(DM / 64, BLROWS / 64), 256, 0, stream>>>(
                G, DI, out_w, DI, nullptr, x, out, DM, BLROWS, DM, DI);
        } else {
            gemm_nt<3><<<dim3(DM / 64, BLROWS / 64), 256, 0, stream>>>(
                G, DI, out_w, DI, nullptr, nullptr, out, DM, BLROWS, DM, DI);
        }
    }
}

// Round 3
// 887.452 us; speedup vs baseline: 3.0841x; 1.6506x over previous
//
#include <hip/hip_runtime.h>
#include <math.h>

#define DM   1024   // d_model
#define DI   2048   // d_inner
#define DST  16     // d_state
#define DTR  64     // dt_rank
#define LSEQ 1024   // L
#define NBAT 2      // B
#define BLROWS (NBAT*LSEQ)   // 2048 token rows
#define NCHUNK 16
#define CLEN   64   // LSEQ / NCHUNK

typedef __bf16 bf16x8 __attribute__((ext_vector_type(8)));
typedef float  f32x4  __attribute__((ext_vector_type(4)));

__device__ __forceinline__ float silu_f(float x) {
    return x / (1.f + expf(-x));
}
__device__ __forceinline__ float softplus_f(float x) {
    return (x > 20.f) ? x : log1pf(expf(x));
}
// round-to-nearest-even f32 -> bf16 (as ushort)
__device__ __forceinline__ unsigned short f2bf(float f) {
    unsigned int u = __float_as_uint(f);
    u = (u + 0x7FFFu + ((u >> 16) & 1u)) >> 16;
    return (unsigned short)u;
}

__device__ __forceinline__ const __attribute__((address_space(1))) void* as1(const void* p) {
    return (const __attribute__((address_space(1))) void*)(uintptr_t)p;
}
__device__ __forceinline__ __attribute__((address_space(3))) void* as3(void* p) {
    return (__attribute__((address_space(3))) void*)(uintptr_t)p;
}

// ---------------------------------------------------------------------------
// f32 -> bf16 cast, vectorized. n must be a multiple of 1024.
// ---------------------------------------------------------------------------
__global__ __launch_bounds__(256) void cast_kernel(const float* __restrict__ in,
                                                   unsigned short* __restrict__ out,
                                                   int n) {
    int i = (blockIdx.x * 256 + threadIdx.x) * 4;
    if (i >= n) return;
    float4 v = *reinterpret_cast<const float4*>(in + i);
    ushort4 o;
    o.x = f2bf(v.x); o.y = f2bf(v.y); o.z = f2bf(v.z); o.w = f2bf(v.w);
    *reinterpret_cast<ushort4*>(out + i) = o;
}

// ---------------------------------------------------------------------------
// LayerNorm: one block per token row (1024 elems), 256 threads. Writes bf16.
// ---------------------------------------------------------------------------
__global__ __launch_bounds__(256) void ln_kernel(const float* __restrict__ x,
                                                 const float* __restrict__ g,
                                                 const float* __restrict__ b,
                                                 unsigned short* __restrict__ xnb) {
    int row = blockIdx.x;
    const float* xr = x + (size_t)row * DM;
    float v[4];
    float s = 0.f, s2 = 0.f;
#pragma unroll
    for (int i = 0; i < 4; i++) {
        v[i] = xr[threadIdx.x + i * 256];
        s += v[i];
        s2 += v[i] * v[i];
    }
#pragma unroll
    for (int off = 32; off; off >>= 1) {
        s  += __shfl_down(s, off);
        s2 += __shfl_down(s2, off);
    }
    __shared__ float ss[4], ss2[4];
    int wid = threadIdx.x >> 6, lane = threadIdx.x & 63;
    if (lane == 0) { ss[wid] = s; ss2[wid] = s2; }
    __syncthreads();
    if (threadIdx.x == 0) {
        float a = 0.f, a2 = 0.f;
#pragma unroll
        for (int i = 0; i < 4; i++) { a += ss[i]; a2 += ss2[i]; }
        ss[0] = a; ss2[0] = a2;
    }
    __syncthreads();
    float m   = ss[0] * (1.f / DM);
    float var = ss2[0] * (1.f / DM) - m * m;
    float inv = rsqrtf(var + 1e-5f);
#pragma unroll
    for (int i = 0; i < 4; i++) {
        int c = threadIdx.x + i * 256;
        xnb[(size_t)row * DM + c] = f2bf((v[i] - m) * inv * g[c] + b[c]);
    }
}

// ---------------------------------------------------------------------------
// bf16 MFMA NT GEMM: C[m,n] = sum_k A[m][k] * W[n][k], f32 accumulate.
// 128x128 tile, BK=32, 256 threads (4 waves, 2x2), 16x16x32 MFMA, 4x4 frags.
// global_load_lds width-16 staging, 2-barrier loop (m97 structure).
// M, N multiples of 128; K multiple of 32.
// MODE 0: C = acc   MODE 2: C = resid + acc   MODE 3: C += acc
// ---------------------------------------------------------------------------
template <int MODE>
__global__ __launch_bounds__(256) void gemm_mfma(const unsigned short* __restrict__ A,
                                                 const unsigned short* __restrict__ W,
                                                 const float* __restrict__ resid,
                                                 float* __restrict__ C, int ldc,
                                                 int K) {
    __shared__ unsigned short As[128 * 32];
    __shared__ unsigned short Bs[128 * 32];

    int tid  = threadIdx.x;
    int lane = tid & 63;
    int w    = tid >> 6;         // wave 0..3
    int wr   = w >> 1;           // wave row (2)
    int wc   = w & 1;            // wave col (2)
    int m_blk = blockIdx.y * 128;
    int n_blk = blockIdx.x * 128;

    // staging: 8 x 1KB insts per tile; wave w does insts 2w, 2w+1.
    // inst s covers rows s*16 + (lane>>2), cols (lane&3)*8 .. +7
    int srow = (2 * w) * 16 + (lane >> 2);
    int scol = (lane & 3) * 8;
    const unsigned short* Ag0 = A + (size_t)(m_blk + srow) * K + scol;
    const unsigned short* Ag1 = Ag0 + (size_t)16 * K;
    const unsigned short* Wg0 = W + (size_t)(n_blk + srow) * K + scol;
    const unsigned short* Wg1 = Wg0 + (size_t)16 * K;
    unsigned short* AsD0 = &As[(2 * w) * 512];
    unsigned short* AsD1 = &As[(2 * w + 1) * 512];
    unsigned short* BsD0 = &Bs[(2 * w) * 512];
    unsigned short* BsD1 = &Bs[(2 * w + 1) * 512];

    f32x4 acc[4][4] = {};

    for (int k0 = 0; k0 < K; k0 += 32) {
        __builtin_amdgcn_global_load_lds(as1(Ag0 + k0), as3(AsD0), 16, 0, 0);
        __builtin_amdgcn_global_load_lds(as1(Ag1 + k0), as3(AsD1), 16, 0, 0);
        __builtin_amdgcn_global_load_lds(as1(Wg0 + k0), as3(BsD0), 16, 0, 0);
        __builtin_amdgcn_global_load_lds(as1(Wg1 + k0), as3(BsD1), 16, 0, 0);
        __syncthreads();

        bf16x8 af[4], wf[4];
#pragma unroll
        for (int i = 0; i < 4; i++)
            af[i] = *reinterpret_cast<const bf16x8*>(
                &As[(wr * 64 + i * 16 + (lane & 15)) * 32 + (lane >> 4) * 8]);
#pragma unroll
        for (int j = 0; j < 4; j++)
            wf[j] = *reinterpret_cast<const bf16x8*>(
                &Bs[(wc * 64 + j * 16 + (lane & 15)) * 32 + (lane >> 4) * 8]);
#pragma unroll
        for (int i = 0; i < 4; i++)
#pragma unroll
            for (int j = 0; j < 4; j++)
                acc[i][j] = __builtin_amdgcn_mfma_f32_16x16x32_bf16(af[i], wf[j], acc[i][j], 0, 0, 0);
        __syncthreads();
    }

    // C/D layout: col = lane&15, row = (lane>>4)*4 + reg
    int colb = n_blk + wc * 64 + (lane & 15);
    int rowb = m_blk + wr * 64 + (lane >> 4) * 4;
#pragma unroll
    for (int i = 0; i < 4; i++) {
#pragma unroll
        for (int j = 0; j < 4; j++) {
#pragma unroll
            for (int r = 0; r < 4; r++) {
                int row = rowb + i * 16 + r;
                int col = colb + j * 16;
                size_t off = (size_t)row * ldc + col;
                float v = acc[i][j][r];
                if (MODE == 0)      C[off] = v;
                else if (MODE == 2) C[off] = resid[off] + v;
                else                C[off] += v;
            }
        }
    }
}

// ---------------------------------------------------------------------------
// Generic f32 NT GEMM (small shapes: xproj N=96, dt K=64).
// MODE 0: store   MODE 1: softplus(acc + bias[n])
// ---------------------------------------------------------------------------
template <int MODE>
__global__ __launch_bounds__(256) void gemm_nt(const float* __restrict__ A, int lda,
                                               const float* __restrict__ W, int ldw,
                                               const float* __restrict__ bias,
                                               float* __restrict__ C, int ldc,
                                               int M, int N, int K) {
    __shared__ float As[16][64];
    __shared__ float Ws[16][64];

    int tid  = threadIdx.x;
    int tx   = tid & 15;
    int ty   = tid >> 4;
    int m0   = blockIdx.y * 64;
    int n0   = blockIdx.x * 64;
    int lrow = tid >> 2;
    int kgrp = (tid & 3) * 4;

    float acc[4][4] = {};

    for (int k0 = 0; k0 < K; k0 += 16) {
        {
            const float* p = A + (size_t)(m0 + lrow) * lda + k0 + kgrp;
            float4 a4 = *reinterpret_cast<const float4*>(p);
            As[kgrp + 0][lrow] = a4.x;
            As[kgrp + 1][lrow] = a4.y;
            As[kgrp + 2][lrow] = a4.z;
            As[kgrp + 3][lrow] = a4.w;
        }
        {
            int n = n0 + lrow;
            float4 w4 = make_float4(0.f, 0.f, 0.f, 0.f);
            if (n < N) {
                const float* p = W + (size_t)n * ldw + k0 + kgrp;
                w4 = *reinterpret_cast<const float4*>(p);
            }
            Ws[kgrp + 0][lrow] = w4.x;
            Ws[kgrp + 1][lrow] = w4.y;
            Ws[kgrp + 2][lrow] = w4.z;
            Ws[kgrp + 3][lrow] = w4.w;
        }
        __syncthreads();
#pragma unroll
        for (int kk = 0; kk < 16; kk++) {
            float4 av = *reinterpret_cast<const float4*>(&As[kk][ty * 4]);
            float4 wv = *reinterpret_cast<const float4*>(&Ws[kk][tx * 4]);
            float am[4] = {av.x, av.y, av.z, av.w};
            float wn[4] = {wv.x, wv.y, wv.z, wv.w};
#pragma unroll
            for (int i = 0; i < 4; i++)
#pragma unroll
                for (int j = 0; j < 4; j++)
                    acc[i][j] = fmaf(am[i], wn[j], acc[i][j]);
        }
        __syncthreads();
    }

#pragma unroll
    for (int i = 0; i < 4; i++) {
        int m = m0 + ty * 4 + i;
#pragma unroll
        for (int j = 0; j < 4; j++) {
            int n = n0 + tx * 4 + j;
            if (n >= N) continue;
            size_t off = (size_t)m * ldc + n;
            float v = acc[i][j];
            if (MODE == 0)      C[off] = v;
            else                C[off] = softplus_f(v + bias[n]);
        }
    }
}

// ---------------------------------------------------------------------------
// Causal conv1d (k=4) + SiLU over the u half of U (cols [0,2048)).
// ---------------------------------------------------------------------------
__global__ __launch_bounds__(256) void conv_silu_kernel(const float* __restrict__ U,
                                                        const float* __restrict__ cw,
                                                        const float* __restrict__ cb,
                                                        float* __restrict__ uc,
                                                        int dir) {
    int idx = blockIdx.x * 256 + threadIdx.x;       // over 2*1024*2048
    int c = idx & (DI - 1);
    int t = (idx >> 11) & (LSEQ - 1);
    int b = idx >> 21;
    float acc = cb[c];
#pragma unroll
    for (int k = 0; k < 4; k++) {
        int tt = dir ? (t + 3 - k) : (t - 3 + k);
        if (tt >= 0 && tt < LSEQ)
            acc = fmaf(cw[c * 4 + k], U[((size_t)(b * LSEQ + tt)) * (2 * DI) + c], acc);
    }
    uc[idx] = silu_f(acc);
}

// ---------------------------------------------------------------------------
// Chunked selective scan, 3 phases (see round-1 comments).
// ---------------------------------------------------------------------------
__global__ __launch_bounds__(256) void scan_p1(const float* __restrict__ dtv,
                                               const float* __restrict__ uc,
                                               const float* __restrict__ dbc,
                                               const float* __restrict__ A_log,
                                               float* __restrict__ hend,
                                               float* __restrict__ Pprod,
                                               int dir) {
    int gid   = blockIdx.x * 16 + (threadIdx.x >> 4);
    int n     = threadIdx.x & 15;
    int c     = gid & (DI - 1);
    int chunk = (gid >> 11) & (NCHUNK - 1);
    int b     = gid >> 15;

    float A = -expf(A_log[c * DST + n]);
    float h = 0.f;
    float P = 1.f;

    int s0 = chunk * CLEN;
    for (int s = 0; s < CLEN; s++) {
        int sigma = s0 + s;
        int t = dir ? (LSEQ - 1 - sigma) : sigma;
        size_t row = (size_t)b * LSEQ + t;
        float dt = dtv[row * DI + c];
        float u  = uc[row * DI + c];
        float Bn = dbc[row * 96 + DTR + n];
        float dA = expf(dt * A);
        h = dA * h + dt * u * Bn;
        P *= dA;
    }
    size_t hidx = (size_t)gid * DST + n;
    hend[hidx]  = h;
    Pprod[hidx] = P;
}

__global__ __launch_bounds__(256) void scan_p2(const float* __restrict__ hend,
                                               const float* __restrict__ Pprod,
                                               float* __restrict__ h0) {
    int id = blockIdx.x * 256 + threadIdx.x;     // 0 .. 2*2048*16-1
    size_t base = (size_t)(id & 32767) + (size_t)(id >> 15) * (NCHUNK * DI * DST);
    float h = 0.f;
#pragma unroll
    for (int k = 0; k < NCHUNK; k++) {
        size_t idx = base + (size_t)k * (DI * DST);
        h0[idx] = h;
        h = Pprod[idx] * h + hend[idx];
    }
}

__global__ __launch_bounds__(256) void scan_p3(const float* __restrict__ dtv,
                                               const float* __restrict__ uc,
                                               const float* __restrict__ dbc,
                                               const float* __restrict__ U,
                                               const float* __restrict__ A_log,
                                               const float* __restrict__ Dp,
                                               const float* __restrict__ h0,
                                               unsigned short* __restrict__ Gb,
                                               int dir) {
    int gid   = blockIdx.x * 16 + (threadIdx.x >> 4);
    int n     = threadIdx.x & 15;
    int c     = gid & (DI - 1);
    int chunk = (gid >> 11) & (NCHUNK - 1);
    int b     = gid >> 15;

    float A  = -expf(A_log[c * DST + n]);
    float Dv = Dp[c];
    float h  = h0[(size_t)gid * DST + n];

    int s0 = chunk * CLEN;
    for (int s = 0; s < CLEN; s++) {
        int sigma = s0 + s;
        int t = dir ? (LSEQ - 1 - sigma) : sigma;
        size_t row = (size_t)b * LSEQ + t;
        float dt = dtv[row * DI + c];
        float u  = uc[row * DI + c];
        float Bn = dbc[row * 96 + DTR + n];
        float Cn = dbc[row * 96 + DTR + DST + n];
        float dA = expf(dt * A);
        h = dA * h + dt * u * Bn;
        float y = h * Cn;
#pragma unroll
        for (int m = 8; m; m >>= 1) y += __shfl_xor(y, m);
        if (n == 0) {
            float yy = y + u * Dv;
            float z  = U[row * (2 * DI) + DI + c];
            Gb[row * DI + c] = f2bf(yy * silu_f(z));
        }
    }
}

// ---------------------------------------------------------------------------
extern "C" void kernel_launch(void* const* d_in, const int* in_sizes, int n_in,
                              void* d_out, int out_size, void* d_ws, size_t ws_size,
                              hipStream_t stream) {
    const float* x    = (const float*)d_in[0];
    const float* ln_g = (const float*)d_in[1];
    const float* ln_b = (const float*)d_in[2];
    float* out = (float*)d_out;

    char* wp = (char*)d_ws;
    unsigned short* xnb = (unsigned short*)wp; wp += (size_t)BLROWS * DM * 2;     // 4 MB
    float* U    = (float*)wp; wp += (size_t)BLROWS * 2 * DI * 4;                  // 32 MB
    float* uc   = (float*)wp; wp += (size_t)BLROWS * DI * 4;                      // 16 MB
    float* dbc  = (float*)wp; wp += (size_t)BLROWS * 96 * 4;                      // .75 MB
    float* dtv  = (float*)wp; wp += (size_t)BLROWS * DI * 4;                      // 16 MB
    unsigned short* Gb = (unsigned short*)wp; wp += (size_t)BLROWS * DI * 2;      // 8 MB
    float* hend  = (float*)wp; wp += (size_t)NBAT * NCHUNK * DI * DST * 4;        // 4 MB
    float* Pprod = (float*)wp; wp += (size_t)NBAT * NCHUNK * DI * DST * 4;        // 4 MB
    float* h0    = (float*)wp; wp += (size_t)NBAT * NCHUNK * DI * DST * 4;        // 4 MB
    unsigned short* in_wb  = (unsigned short*)wp; wp += (size_t)2 * DI * DM * 2;  // 8 MB
    unsigned short* out_wb = (unsigned short*)wp; wp += (size_t)DM * DI * 2;      // 4 MB

    ln_kernel<<<BLROWS, 256, 0, stream>>>(x, ln_g, ln_b, xnb);

    const int ngroups = NBAT * NCHUNK * DI;          // 65536

    for (int br = 0; br < 2; br++) {
        const float* in_w    = (const float*)d_in[3 + 9 * br + 0];
        const float* conv_w  = (const float*)d_in[3 + 9 * br + 1];
        const float* conv_b  = (const float*)d_in[3 + 9 * br + 2];
        const float* xproj_w = (const float*)d_in[3 + 9 * br + 3];
        const float* dt_w    = (const float*)d_in[3 + 9 * br + 4];
        const float* dt_b    = (const float*)d_in[3 + 9 * br + 5];
        const float* A_log   = (const float*)d_in[3 + 9 * br + 6];
        const float* Dp      = (const float*)d_in[3 + 9 * br + 7];
        const float* out_w   = (const float*)d_in[3 + 9 * br + 8];

        // cast weights to bf16
        cast_kernel<<<(2 * DI * DM) / 1024, 256, 0, stream>>>(in_w, in_wb, 2 * DI * DM);
        cast_kernel<<<(DM * DI) / 1024, 256, 0, stream>>>(out_w, out_wb, DM * DI);

        // U = xnb @ in_wb.T   (2048 x 4096 x 1024) -> f32
        gemm_mfma<0><<<dim3(2 * DI / 128, BLROWS / 128), 256, 0, stream>>>(
            xnb, in_wb, nullptr, U, 2 * DI, DM);

        // uc = silu(conv1d(u) + cb)
        conv_silu_kernel<<<(BLROWS * DI) / 256, 256, 0, stream>>>(U, conv_w, conv_b, uc, br);

        // dbc = uc @ xproj_w.T   (2048 x 96 x 2048)  f32
        gemm_nt<0><<<dim3(2, BLROWS / 64), 256, 0, stream>>>(
            uc, DI, xproj_w, DI, nullptr, dbc, 96, BLROWS, 96, DI);

        // dtv = softplus(dbc[:, :64] @ dt_w.T + dt_b)   (2048 x 2048 x 64)  f32
        gemm_nt<1><<<dim3(DI / 64, BLROWS / 64), 256, 0, stream>>>(
            dbc, 96, dt_w, DTR, dt_b, dtv, DI, BLROWS, DI, DTR);

        // chunked selective scan + gating -> Gb (bf16)
        scan_p1<<<ngroups / 16, 256, 0, stream>>>(dtv, uc, dbc, A_log, hend, Pprod, br);
        scan_p2<<<(NBAT * DI * DST) / 256, 256, 0, stream>>>(hend, Pprod, h0);
        scan_p3<<<ngroups / 16, 256, 0, stream>>>(dtv, uc, dbc, U, A_log, Dp, h0, Gb, br);

        // out (+)= Gb @ out_wb.T  (+ x residual on first branch)
        if (br == 0) {
            gemm_mfma<2><<<dim3(DM / 128, BLROWS / 128), 256, 0, stream>>>(
                Gb, out_wb, x, out, DM, DI);
        } else {
            gemm_mfma<3><<<dim3(DM / 128, BLROWS / 128), 256, 0, stream>>>(
                Gb, out_wb, nullptr, out, DM, DI);
        }
    }
}

// Round 4
// 661.420 us; speedup vs baseline: 4.1381x; 1.3417x over previous
//
#include <hip/hip_runtime.h>
#include <math.h>

#define DM   1024   // d_model
#define DI   2048   // d_inner
#define DST  16     // d_state
#define DTR  64     // dt_rank
#define LSEQ 1024   // L
#define NBAT 2      // B
#define BLROWS (NBAT*LSEQ)   // 2048 token rows
#define NCHUNK 32
#define CLEN   32   // LSEQ / NCHUNK

typedef __bf16 bf16x8 __attribute__((ext_vector_type(8)));
typedef float  f32x4  __attribute__((ext_vector_type(4)));

__device__ __forceinline__ float silu_f(float x) {
    return x / (1.f + __expf(-x));
}
__device__ __forceinline__ float softplus_f(float x) {
    return (x > 20.f) ? x : __logf(1.f + __expf(x));
}
// round-to-nearest-even f32 -> bf16 (as ushort)
__device__ __forceinline__ unsigned short f2bf(float f) {
    unsigned int u = __float_as_uint(f);
    u = (u + 0x7FFFu + ((u >> 16) & 1u)) >> 16;
    return (unsigned short)u;
}

__device__ __forceinline__ const __attribute__((address_space(1))) void* as1(const void* p) {
    return (const __attribute__((address_space(1))) void*)(uintptr_t)p;
}
__device__ __forceinline__ __attribute__((address_space(3))) void* as3(void* p) {
    return (__attribute__((address_space(3))) void*)(uintptr_t)p;
}

// ---------------------------------------------------------------------------
// f32 -> bf16 cast, vectorized. n must be a multiple of 1024.
// ---------------------------------------------------------------------------
__global__ __launch_bounds__(256) void cast_kernel(const float* __restrict__ in,
                                                   unsigned short* __restrict__ out,
                                                   int n) {
    int i = (blockIdx.x * 256 + threadIdx.x) * 4;
    if (i >= n) return;
    float4 v = *reinterpret_cast<const float4*>(in + i);
    ushort4 o;
    o.x = f2bf(v.x); o.y = f2bf(v.y); o.z = f2bf(v.z); o.w = f2bf(v.w);
    *reinterpret_cast<ushort4*>(out + i) = o;
}

// ---------------------------------------------------------------------------
// LayerNorm: one block per token row (1024 elems), 256 threads. Writes bf16.
// ---------------------------------------------------------------------------
__global__ __launch_bounds__(256) void ln_kernel(const float* __restrict__ x,
                                                 const float* __restrict__ g,
                                                 const float* __restrict__ b,
                                                 unsigned short* __restrict__ xnb) {
    int row = blockIdx.x;
    const float* xr = x + (size_t)row * DM;
    float v[4];
    float s = 0.f, s2 = 0.f;
#pragma unroll
    for (int i = 0; i < 4; i++) {
        v[i] = xr[threadIdx.x + i * 256];
        s += v[i];
        s2 += v[i] * v[i];
    }
#pragma unroll
    for (int off = 32; off; off >>= 1) {
        s  += __shfl_down(s, off);
        s2 += __shfl_down(s2, off);
    }
    __shared__ float ss[4], ss2[4];
    int wid = threadIdx.x >> 6, lane = threadIdx.x & 63;
    if (lane == 0) { ss[wid] = s; ss2[wid] = s2; }
    __syncthreads();
    if (threadIdx.x == 0) {
        float a = 0.f, a2 = 0.f;
#pragma unroll
        for (int i = 0; i < 4; i++) { a += ss[i]; a2 += ss2[i]; }
        ss[0] = a; ss2[0] = a2;
    }
    __syncthreads();
    float m   = ss[0] * (1.f / DM);
    float var = ss2[0] * (1.f / DM) - m * m;
    float inv = rsqrtf(var + 1e-5f);
#pragma unroll
    for (int i = 0; i < 4; i++) {
        int c = threadIdx.x + i * 256;
        xnb[(size_t)row * DM + c] = f2bf((v[i] - m) * inv * g[c] + b[c]);
    }
}

// ---------------------------------------------------------------------------
// bf16 MFMA NT GEMM (m97 structure): 128x128 tile, BK=32, 4 waves.
// MODE 0: C = acc   MODE 2: C = resid + acc   MODE 3: C += acc
// ---------------------------------------------------------------------------
template <int MODE>
__global__ __launch_bounds__(256) void gemm_mfma(const unsigned short* __restrict__ A,
                                                 const unsigned short* __restrict__ W,
                                                 const float* __restrict__ resid,
                                                 float* __restrict__ C, int ldc,
                                                 int K) {
    __shared__ unsigned short As[128 * 32];
    __shared__ unsigned short Bs[128 * 32];

    int tid  = threadIdx.x;
    int lane = tid & 63;
    int w    = tid >> 6;
    int wr   = w >> 1;
    int wc   = w & 1;
    int m_blk = blockIdx.y * 128;
    int n_blk = blockIdx.x * 128;

    int srow = (2 * w) * 16 + (lane >> 2);
    int scol = (lane & 3) * 8;
    const unsigned short* Ag0 = A + (size_t)(m_blk + srow) * K + scol;
    const unsigned short* Ag1 = Ag0 + (size_t)16 * K;
    const unsigned short* Wg0 = W + (size_t)(n_blk + srow) * K + scol;
    const unsigned short* Wg1 = Wg0 + (size_t)16 * K;
    unsigned short* AsD0 = &As[(2 * w) * 512];
    unsigned short* AsD1 = &As[(2 * w + 1) * 512];
    unsigned short* BsD0 = &Bs[(2 * w) * 512];
    unsigned short* BsD1 = &Bs[(2 * w + 1) * 512];

    f32x4 acc[4][4] = {};

    for (int k0 = 0; k0 < K; k0 += 32) {
        __builtin_amdgcn_global_load_lds(as1(Ag0 + k0), as3(AsD0), 16, 0, 0);
        __builtin_amdgcn_global_load_lds(as1(Ag1 + k0), as3(AsD1), 16, 0, 0);
        __builtin_amdgcn_global_load_lds(as1(Wg0 + k0), as3(BsD0), 16, 0, 0);
        __builtin_amdgcn_global_load_lds(as1(Wg1 + k0), as3(BsD1), 16, 0, 0);
        __syncthreads();

        bf16x8 af[4], wf[4];
#pragma unroll
        for (int i = 0; i < 4; i++)
            af[i] = *reinterpret_cast<const bf16x8*>(
                &As[(wr * 64 + i * 16 + (lane & 15)) * 32 + (lane >> 4) * 8]);
#pragma unroll
        for (int j = 0; j < 4; j++)
            wf[j] = *reinterpret_cast<const bf16x8*>(
                &Bs[(wc * 64 + j * 16 + (lane & 15)) * 32 + (lane >> 4) * 8]);
#pragma unroll
        for (int i = 0; i < 4; i++)
#pragma unroll
            for (int j = 0; j < 4; j++)
                acc[i][j] = __builtin_amdgcn_mfma_f32_16x16x32_bf16(af[i], wf[j], acc[i][j], 0, 0, 0);
        __syncthreads();
    }

    int colb = n_blk + wc * 64 + (lane & 15);
    int rowb = m_blk + wr * 64 + (lane >> 4) * 4;
#pragma unroll
    for (int i = 0; i < 4; i++) {
#pragma unroll
        for (int j = 0; j < 4; j++) {
#pragma unroll
            for (int r = 0; r < 4; r++) {
                int row = rowb + i * 16 + r;
                int col = colb + j * 16;
                size_t off = (size_t)row * ldc + col;
                float v = acc[i][j][r];
                if (MODE == 0)      C[off] = v;
                else if (MODE == 2) C[off] = resid[off] + v;
                else                C[off] += v;
            }
        }
    }
}

// ---------------------------------------------------------------------------
// Generic f32 NT GEMM (small shapes: xproj N=96, dt K=64).
// MODE 0: store   MODE 1: softplus(acc + bias[n])
// ---------------------------------------------------------------------------
template <int MODE>
__global__ __launch_bounds__(256) void gemm_nt(const float* __restrict__ A, int lda,
                                               const float* __restrict__ W, int ldw,
                                               const float* __restrict__ bias,
                                               float* __restrict__ C, int ldc,
                                               int M, int N, int K) {
    __shared__ float As[16][64];
    __shared__ float Ws[16][64];

    int tid  = threadIdx.x;
    int tx   = tid & 15;
    int ty   = tid >> 4;
    int m0   = blockIdx.y * 64;
    int n0   = blockIdx.x * 64;
    int lrow = tid >> 2;
    int kgrp = (tid & 3) * 4;

    float acc[4][4] = {};

    for (int k0 = 0; k0 < K; k0 += 16) {
        {
            const float* p = A + (size_t)(m0 + lrow) * lda + k0 + kgrp;
            float4 a4 = *reinterpret_cast<const float4*>(p);
            As[kgrp + 0][lrow] = a4.x;
            As[kgrp + 1][lrow] = a4.y;
            As[kgrp + 2][lrow] = a4.z;
            As[kgrp + 3][lrow] = a4.w;
        }
        {
            int n = n0 + lrow;
            float4 w4 = make_float4(0.f, 0.f, 0.f, 0.f);
            if (n < N) {
                const float* p = W + (size_t)n * ldw + k0 + kgrp;
                w4 = *reinterpret_cast<const float4*>(p);
            }
            Ws[kgrp + 0][lrow] = w4.x;
            Ws[kgrp + 1][lrow] = w4.y;
            Ws[kgrp + 2][lrow] = w4.z;
            Ws[kgrp + 3][lrow] = w4.w;
        }
        __syncthreads();
#pragma unroll
        for (int kk = 0; kk < 16; kk++) {
            float4 av = *reinterpret_cast<const float4*>(&As[kk][ty * 4]);
            float4 wv = *reinterpret_cast<const float4*>(&Ws[kk][tx * 4]);
            float am[4] = {av.x, av.y, av.z, av.w};
            float wn[4] = {wv.x, wv.y, wv.z, wv.w};
#pragma unroll
            for (int i = 0; i < 4; i++)
#pragma unroll
                for (int j = 0; j < 4; j++)
                    acc[i][j] = fmaf(am[i], wn[j], acc[i][j]);
        }
        __syncthreads();
    }

#pragma unroll
    for (int i = 0; i < 4; i++) {
        int m = m0 + ty * 4 + i;
#pragma unroll
        for (int j = 0; j < 4; j++) {
            int n = n0 + tx * 4 + j;
            if (n >= N) continue;
            size_t off = (size_t)m * ldc + n;
            float v = acc[i][j];
            if (MODE == 0)      C[off] = v;
            else                C[off] = softplus_f(v + bias[n]);
        }
    }
}

// ---------------------------------------------------------------------------
// Causal conv1d (k=4) + SiLU over the u half of U (cols [0,2048)).
// ---------------------------------------------------------------------------
__global__ __launch_bounds__(256) void conv_silu_kernel(const float* __restrict__ U,
                                                        const float* __restrict__ cw,
                                                        const float* __restrict__ cb,
                                                        float* __restrict__ uc,
                                                        int dir) {
    int idx = blockIdx.x * 256 + threadIdx.x;       // over 2*1024*2048
    int c = idx & (DI - 1);
    int t = (idx >> 11) & (LSEQ - 1);
    int b = idx >> 21;
    float acc = cb[c];
#pragma unroll
    for (int k = 0; k < 4; k++) {
        int tt = dir ? (t + 3 - k) : (t - 3 + k);
        if (tt >= 0 && tt < LSEQ)
            acc = fmaf(cw[c * 4 + k], U[((size_t)(b * LSEQ + tt)) * (2 * DI) + c], acc);
    }
    uc[idx] = silu_f(acc);
}

// ---------------------------------------------------------------------------
// Chunked selective scan, lane-per-channel layout.
// Each thread owns one channel c and its 16 states in registers.
// grid = (DI/256, NCHUNK, NBAT), block = 256.
// sigma = logical scan step; t = dir ? L-1-sigma : sigma.
// ---------------------------------------------------------------------------
__global__ __launch_bounds__(256) void scan_p1(const float* __restrict__ dtv,
                                               const float* __restrict__ uc,
                                               const float* __restrict__ dbc,
                                               const float* __restrict__ A_log,
                                               float* __restrict__ hend,
                                               float* __restrict__ Pprod,
                                               int dir) {
    int c     = blockIdx.x * 256 + threadIdx.x;
    int chunk = blockIdx.y;
    int b     = blockIdx.z;

    __shared__ float Bs[CLEN][16];
    for (int i = threadIdx.x; i < CLEN * 16; i += 256) {
        int s = i >> 4, j = i & 15;
        int sigma = chunk * CLEN + s;
        int t = dir ? (LSEQ - 1 - sigma) : sigma;
        Bs[s][j] = dbc[((size_t)b * LSEQ + t) * 96 + DTR + j];
    }
    __syncthreads();

    const float LOG2E = 1.4426950408889634f;
    float A2[16], h[16], P[16];
#pragma unroll
    for (int n = 0; n < 16; n++) {
        A2[n] = -__expf(A_log[c * DST + n]) * LOG2E;
        h[n] = 0.f;
        P[n] = 1.f;
    }

    int s0 = chunk * CLEN;
#pragma unroll 2
    for (int s = 0; s < CLEN; s++) {
        int sigma = s0 + s;
        int t = dir ? (LSEQ - 1 - sigma) : sigma;
        size_t row = (size_t)b * LSEQ + t;
        float dt = dtv[row * DI + c];
        float u  = uc[row * DI + c];
        float du = dt * u;
        float Bv[16];
#pragma unroll
        for (int q = 0; q < 4; q++)
            reinterpret_cast<float4*>(Bv)[q] = reinterpret_cast<const float4*>(Bs[s])[q];
#pragma unroll
        for (int n = 0; n < 16; n++) {
            float dA = exp2f(dt * A2[n]);
            h[n] = dA * h[n] + du * Bv[n];
            P[n] *= dA;
        }
    }
    size_t base = (((size_t)b * NCHUNK + chunk) * DI + c) * DST;
#pragma unroll
    for (int n = 0; n < 16; n++) {
        hend[base + n]  = h[n];
        Pprod[base + n] = P[n];
    }
}

// Combine: per (b,c,n), prefix over chunks. h0 ALIASES Pprod (read P first!).
__global__ __launch_bounds__(256) void scan_p2(const float* __restrict__ hend,
                                               float* __restrict__ P_h0) {
    int id = blockIdx.x * 256 + threadIdx.x;     // 0 .. NBAT*DI*DST-1
    size_t base = (size_t)(id & (DI * DST - 1)) + (size_t)(id >> 15) * ((size_t)NCHUNK * DI * DST);
    float h = 0.f;
    for (int k = 0; k < NCHUNK; k++) {
        size_t idx = base + (size_t)k * (DI * DST);
        float Pv = P_h0[idx];
        float hv = hend[idx];
        P_h0[idx] = h;
        h = Pv * h + hv;
    }
}

__global__ __launch_bounds__(256) void scan_p3(const float* __restrict__ dtv,
                                               const float* __restrict__ uc,
                                               const float* __restrict__ dbc,
                                               const float* __restrict__ U,
                                               const float* __restrict__ A_log,
                                               const float* __restrict__ Dp,
                                               const float* __restrict__ h0,
                                               unsigned short* __restrict__ Gb,
                                               int dir) {
    int c     = blockIdx.x * 256 + threadIdx.x;
    int chunk = blockIdx.y;
    int b     = blockIdx.z;

    __shared__ float BCs[CLEN][32];
    for (int i = threadIdx.x; i < CLEN * 32; i += 256) {
        int s = i >> 5, j = i & 31;
        int sigma = chunk * CLEN + s;
        int t = dir ? (LSEQ - 1 - sigma) : sigma;
        BCs[s][j] = dbc[((size_t)b * LSEQ + t) * 96 + DTR + j];
    }
    __syncthreads();

    const float LOG2E = 1.4426950408889634f;
    float A2[16], h[16];
    size_t base = (((size_t)b * NCHUNK + chunk) * DI + c) * DST;
#pragma unroll
    for (int n = 0; n < 16; n++) {
        A2[n] = -__expf(A_log[c * DST + n]) * LOG2E;
        h[n]  = h0[base + n];
    }
    float Dv = Dp[c];

    int s0 = chunk * CLEN;
#pragma unroll 2
    for (int s = 0; s < CLEN; s++) {
        int sigma = s0 + s;
        int t = dir ? (LSEQ - 1 - sigma) : sigma;
        size_t row = (size_t)b * LSEQ + t;
        float dt = dtv[row * DI + c];
        float u  = uc[row * DI + c];
        float du = dt * u;
        float BCv[32];
#pragma unroll
        for (int q = 0; q < 8; q++)
            reinterpret_cast<float4*>(BCv)[q] = reinterpret_cast<const float4*>(BCs[s])[q];
        float y = 0.f;
#pragma unroll
        for (int n = 0; n < 16; n++) {
            float dA = exp2f(dt * A2[n]);
            h[n] = dA * h[n] + du * BCv[n];
            y = fmaf(h[n], BCv[16 + n], y);
        }
        float yy = y + u * Dv;
        float z  = U[row * (2 * DI) + DI + c];
        Gb[row * DI + c] = f2bf(yy * silu_f(z));
    }
}

// ---------------------------------------------------------------------------
extern "C" void kernel_launch(void* const* d_in, const int* in_sizes, int n_in,
                              void* d_out, int out_size, void* d_ws, size_t ws_size,
                              hipStream_t stream) {
    const float* x    = (const float*)d_in[0];
    const float* ln_g = (const float*)d_in[1];
    const float* ln_b = (const float*)d_in[2];
    float* out = (float*)d_out;

    char* wp = (char*)d_ws;
    unsigned short* xnb = (unsigned short*)wp; wp += (size_t)BLROWS * DM * 2;     // 4 MB
    float* U    = (float*)wp; wp += (size_t)BLROWS * 2 * DI * 4;                  // 32 MB
    float* uc   = (float*)wp; wp += (size_t)BLROWS * DI * 4;                      // 16 MB
    float* dbc  = (float*)wp; wp += (size_t)BLROWS * 96 * 4;                      // .75 MB
    float* dtv  = (float*)wp; wp += (size_t)BLROWS * DI * 4;                      // 16 MB
    unsigned short* Gb = (unsigned short*)wp; wp += (size_t)BLROWS * DI * 2;      // 8 MB
    float* hend  = (float*)wp; wp += (size_t)NBAT * NCHUNK * DI * DST * 4;        // 8 MB
    float* Pprod = (float*)wp; wp += (size_t)NBAT * NCHUNK * DI * DST * 4;        // 8 MB (doubles as h0)
    unsigned short* in_wb  = (unsigned short*)wp; wp += (size_t)2 * DI * DM * 2;  // 8 MB
    // out_wb ALIASES hend: hend is dead after scan_p2; cast happens after p2.
    unsigned short* out_wb = (unsigned short*)hend;
    float* h0 = Pprod;   // alias (scan_p2 rewrites Pprod in place as h0)

    ln_kernel<<<BLROWS, 256, 0, stream>>>(x, ln_g, ln_b, xnb);

    for (int br = 0; br < 2; br++) {
        const float* in_w    = (const float*)d_in[3 + 9 * br + 0];
        const float* conv_w  = (const float*)d_in[3 + 9 * br + 1];
        const float* conv_b  = (const float*)d_in[3 + 9 * br + 2];
        const float* xproj_w = (const float*)d_in[3 + 9 * br + 3];
        const float* dt_w    = (const float*)d_in[3 + 9 * br + 4];
        const float* dt_b    = (const float*)d_in[3 + 9 * br + 5];
        const float* A_log   = (const float*)d_in[3 + 9 * br + 6];
        const float* Dp      = (const float*)d_in[3 + 9 * br + 7];
        const float* out_w   = (const float*)d_in[3 + 9 * br + 8];

        // cast in-proj weights to bf16
        cast_kernel<<<(2 * DI * DM) / 1024, 256, 0, stream>>>(in_w, in_wb, 2 * DI * DM);

        // U = xnb @ in_wb.T   (2048 x 4096 x 1024) -> f32
        gemm_mfma<0><<<dim3(2 * DI / 128, BLROWS / 128), 256, 0, stream>>>(
            xnb, in_wb, nullptr, U, 2 * DI, DM);

        // uc = silu(conv1d(u) + cb)
        conv_silu_kernel<<<(BLROWS * DI) / 256, 256, 0, stream>>>(U, conv_w, conv_b, uc, br);

        // dbc = uc @ xproj_w.T   (2048 x 96 x 2048)  f32
        gemm_nt<0><<<dim3(2, BLROWS / 64), 256, 0, stream>>>(
            uc, DI, xproj_w, DI, nullptr, dbc, 96, BLROWS, 96, DI);

        // dtv = softplus(dbc[:, :64] @ dt_w.T + dt_b)   (2048 x 2048 x 64)  f32
        gemm_nt<1><<<dim3(DI / 64, BLROWS / 64), 256, 0, stream>>>(
            dbc, 96, dt_w, DTR, dt_b, dtv, DI, BLROWS, DI, DTR);

        // chunked selective scan + gating -> Gb (bf16)
        scan_p1<<<dim3(DI / 256, NCHUNK, NBAT), 256, 0, stream>>>(
            dtv, uc, dbc, A_log, hend, Pprod, br);
        scan_p2<<<(NBAT * DI * DST) / 256, 256, 0, stream>>>(hend, Pprod);
        // hend now dead -> cast out_w into its storage
        cast_kernel<<<(DM * DI) / 1024, 256, 0, stream>>>(out_w, out_wb, DM * DI);
        scan_p3<<<dim3(DI / 256, NCHUNK, NBAT), 256, 0, stream>>>(
            dtv, uc, dbc, U, A_log, Dp, h0, Gb, br);

        // out (+)= Gb @ out_wb.T  (+ x residual on first branch)
        if (br == 0) {
            gemm_mfma<2><<<dim3(DM / 128, BLROWS / 128), 256, 0, stream>>>(
                Gb, out_wb, x, out, DM, DI);
        } else {
            gemm_mfma<3><<<dim3(DM / 128, BLROWS / 128), 256, 0, stream>>>(
                Gb, out_wb, nullptr, out, DM, DI);
        }
    }
}

// Round 5
// 440.132 us; speedup vs baseline: 6.2186x; 1.5028x over previous
//
#include <hip/hip_runtime.h>
#include <math.h>

#define DM   1024   // d_model
#define DI   2048   // d_inner
#define DST  16     // d_state
#define DTR  64     // dt_rank
#define LSEQ 1024   // L
#define NBAT 2      // B
#define BLROWS (NBAT*LSEQ)   // 2048 token rows
#define NCHUNK 32
#define CLEN   32   // LSEQ / NCHUNK
#define KSPL   16   // K-splits for xproj GEMM

typedef __bf16 bf16x8 __attribute__((ext_vector_type(8)));
typedef float  f32x4  __attribute__((ext_vector_type(4)));

__device__ __forceinline__ float silu_f(float x) {
    return x / (1.f + __expf(-x));
}
__device__ __forceinline__ float softplus_f(float x) {
    return (x > 20.f) ? x : __logf(1.f + __expf(x));
}
// round-to-nearest-even f32 -> bf16 (as ushort)
__device__ __forceinline__ unsigned short f2bf(float f) {
    unsigned int u = __float_as_uint(f);
    u = (u + 0x7FFFu + ((u >> 16) & 1u)) >> 16;
    return (unsigned short)u;
}

__device__ __forceinline__ const __attribute__((address_space(1))) void* as1(const void* p) {
    return (const __attribute__((address_space(1))) void*)(uintptr_t)p;
}
__device__ __forceinline__ __attribute__((address_space(3))) void* as3(void* p) {
    return (__attribute__((address_space(3))) void*)(uintptr_t)p;
}

// ---------------------------------------------------------------------------
// f32 -> bf16 cast, vectorized. n must be a multiple of 1024.
// ---------------------------------------------------------------------------
__global__ __launch_bounds__(256) void cast_kernel(const float* __restrict__ in,
                                                   unsigned short* __restrict__ out,
                                                   int n) {
    int i = (blockIdx.x * 256 + threadIdx.x) * 4;
    if (i >= n) return;
    float4 v = *reinterpret_cast<const float4*>(in + i);
    ushort4 o;
    o.x = f2bf(v.x); o.y = f2bf(v.y); o.z = f2bf(v.z); o.w = f2bf(v.w);
    *reinterpret_cast<ushort4*>(out + i) = o;
}

// xproj_w [96][2048] f32 -> [128][2048] bf16, rows 96..127 zeroed.
__global__ __launch_bounds__(256) void padcast_xproj(const float* __restrict__ in,
                                                     unsigned short* __restrict__ out) {
    int i = (blockIdx.x * 256 + threadIdx.x) * 4;   // over 128*2048
    int row = i >> 11;
    ushort4 o = make_ushort4(0, 0, 0, 0);
    if (row < 96) {
        float4 v = *reinterpret_cast<const float4*>(in + i);
        o.x = f2bf(v.x); o.y = f2bf(v.y); o.z = f2bf(v.z); o.w = f2bf(v.w);
    }
    *reinterpret_cast<ushort4*>(out + i) = o;
}

// ---------------------------------------------------------------------------
// LayerNorm: one block per token row (1024 elems), 256 threads. Writes bf16.
// ---------------------------------------------------------------------------
__global__ __launch_bounds__(256) void ln_kernel(const float* __restrict__ x,
                                                 const float* __restrict__ g,
                                                 const float* __restrict__ b,
                                                 unsigned short* __restrict__ xnb) {
    int row = blockIdx.x;
    const float* xr = x + (size_t)row * DM;
    float v[4];
    float s = 0.f, s2 = 0.f;
#pragma unroll
    for (int i = 0; i < 4; i++) {
        v[i] = xr[threadIdx.x + i * 256];
        s += v[i];
        s2 += v[i] * v[i];
    }
#pragma unroll
    for (int off = 32; off; off >>= 1) {
        s  += __shfl_down(s, off);
        s2 += __shfl_down(s2, off);
    }
    __shared__ float ss[4], ss2[4];
    int wid = threadIdx.x >> 6, lane = threadIdx.x & 63;
    if (lane == 0) { ss[wid] = s; ss2[wid] = s2; }
    __syncthreads();
    if (threadIdx.x == 0) {
        float a = 0.f, a2 = 0.f;
#pragma unroll
        for (int i = 0; i < 4; i++) { a += ss[i]; a2 += ss2[i]; }
        ss[0] = a; ss2[0] = a2;
    }
    __syncthreads();
    float m   = ss[0] * (1.f / DM);
    float var = ss2[0] * (1.f / DM) - m * m;
    float inv = rsqrtf(var + 1e-5f);
#pragma unroll
    for (int i = 0; i < 4; i++) {
        int c = threadIdx.x + i * 256;
        xnb[(size_t)row * DM + c] = f2bf((v[i] - m) * inv * g[c] + b[c]);
    }
}

// ---------------------------------------------------------------------------
// bf16 MFMA NT GEMM (m97 structure): 128x128 tile, BK=32, 4 waves.
// MODE 0: C = acc            MODE 1: C = softplus(acc + bias[col])
// MODE 2: C = resid + acc    MODE 3: C += acc
// A row stride = K, W row stride = K.
// ---------------------------------------------------------------------------
template <int MODE>
__global__ __launch_bounds__(256) void gemm_mfma(const unsigned short* __restrict__ A,
                                                 const unsigned short* __restrict__ W,
                                                 const float* __restrict__ resid,
                                                 const float* __restrict__ bias,
                                                 float* __restrict__ C, int ldc,
                                                 int K) {
    __shared__ unsigned short As[128 * 32];
    __shared__ unsigned short Bs[128 * 32];

    int tid  = threadIdx.x;
    int lane = tid & 63;
    int w    = tid >> 6;
    int wr   = w >> 1;
    int wc   = w & 1;
    int m_blk = blockIdx.y * 128;
    int n_blk = blockIdx.x * 128;

    int srow = (2 * w) * 16 + (lane >> 2);
    int scol = (lane & 3) * 8;
    const unsigned short* Ag0 = A + (size_t)(m_blk + srow) * K + scol;
    const unsigned short* Ag1 = Ag0 + (size_t)16 * K;
    const unsigned short* Wg0 = W + (size_t)(n_blk + srow) * K + scol;
    const unsigned short* Wg1 = Wg0 + (size_t)16 * K;
    unsigned short* AsD0 = &As[(2 * w) * 512];
    unsigned short* AsD1 = &As[(2 * w + 1) * 512];
    unsigned short* BsD0 = &Bs[(2 * w) * 512];
    unsigned short* BsD1 = &Bs[(2 * w + 1) * 512];

    f32x4 acc[4][4] = {};

    for (int k0 = 0; k0 < K; k0 += 32) {
        __builtin_amdgcn_global_load_lds(as1(Ag0 + k0), as3(AsD0), 16, 0, 0);
        __builtin_amdgcn_global_load_lds(as1(Ag1 + k0), as3(AsD1), 16, 0, 0);
        __builtin_amdgcn_global_load_lds(as1(Wg0 + k0), as3(BsD0), 16, 0, 0);
        __builtin_amdgcn_global_load_lds(as1(Wg1 + k0), as3(BsD1), 16, 0, 0);
        __syncthreads();

        bf16x8 af[4], wf[4];
#pragma unroll
        for (int i = 0; i < 4; i++)
            af[i] = *reinterpret_cast<const bf16x8*>(
                &As[(wr * 64 + i * 16 + (lane & 15)) * 32 + (lane >> 4) * 8]);
#pragma unroll
        for (int j = 0; j < 4; j++)
            wf[j] = *reinterpret_cast<const bf16x8*>(
                &Bs[(wc * 64 + j * 16 + (lane & 15)) * 32 + (lane >> 4) * 8]);
#pragma unroll
        for (int i = 0; i < 4; i++)
#pragma unroll
            for (int j = 0; j < 4; j++)
                acc[i][j] = __builtin_amdgcn_mfma_f32_16x16x32_bf16(af[i], wf[j], acc[i][j], 0, 0, 0);
        __syncthreads();
    }

    int colb = n_blk + wc * 64 + (lane & 15);
    int rowb = m_blk + wr * 64 + (lane >> 4) * 4;
#pragma unroll
    for (int i = 0; i < 4; i++) {
#pragma unroll
        for (int j = 0; j < 4; j++) {
#pragma unroll
            for (int r = 0; r < 4; r++) {
                int row = rowb + i * 16 + r;
                int col = colb + j * 16;
                size_t off = (size_t)row * ldc + col;
                float v = acc[i][j][r];
                if (MODE == 0)      C[off] = v;
                else if (MODE == 1) C[off] = softplus_f(v + bias[col]);
                else if (MODE == 2) C[off] = resid[off] + v;
                else                C[off] += v;
            }
        }
    }
}

// ---------------------------------------------------------------------------
// Split-K MFMA for xproj: A = ucb [2048][2048] bf16, W = xprojb [128][2048].
// grid (M/128, KSPL). Block (m, s) computes 128x128 over K in [s*128,(s+1)*128)
// and stores f32 partials at partial[s][2048][128].
// ---------------------------------------------------------------------------
__global__ __launch_bounds__(256) void gemm_sk(const unsigned short* __restrict__ A,
                                               const unsigned short* __restrict__ W,
                                               float* __restrict__ partial) {
    __shared__ unsigned short As[128 * 32];
    __shared__ unsigned short Bs[128 * 32];

    int tid  = threadIdx.x;
    int lane = tid & 63;
    int w    = tid >> 6;
    int wr   = w >> 1;
    int wc   = w & 1;
    int m_blk = blockIdx.x * 128;
    int s     = blockIdx.y;

    int srow = (2 * w) * 16 + (lane >> 2);
    int scol = (lane & 3) * 8;
    const unsigned short* Ag0 = A + (size_t)(m_blk + srow) * DI + scol;
    const unsigned short* Ag1 = Ag0 + (size_t)16 * DI;
    const unsigned short* Wg0 = W + (size_t)srow * DI + scol;
    const unsigned short* Wg1 = Wg0 + (size_t)16 * DI;
    unsigned short* AsD0 = &As[(2 * w) * 512];
    unsigned short* AsD1 = &As[(2 * w + 1) * 512];
    unsigned short* BsD0 = &Bs[(2 * w) * 512];
    unsigned short* BsD1 = &Bs[(2 * w + 1) * 512];

    f32x4 acc[4][4] = {};

    int kbeg = s * (DI / KSPL);
#pragma unroll 2
    for (int k0 = kbeg; k0 < kbeg + DI / KSPL; k0 += 32) {
        __builtin_amdgcn_global_load_lds(as1(Ag0 + k0), as3(AsD0), 16, 0, 0);
        __builtin_amdgcn_global_load_lds(as1(Ag1 + k0), as3(AsD1), 16, 0, 0);
        __builtin_amdgcn_global_load_lds(as1(Wg0 + k0), as3(BsD0), 16, 0, 0);
        __builtin_amdgcn_global_load_lds(as1(Wg1 + k0), as3(BsD1), 16, 0, 0);
        __syncthreads();

        bf16x8 af[4], wf[4];
#pragma unroll
        for (int i = 0; i < 4; i++)
            af[i] = *reinterpret_cast<const bf16x8*>(
                &As[(wr * 64 + i * 16 + (lane & 15)) * 32 + (lane >> 4) * 8]);
#pragma unroll
        for (int j = 0; j < 4; j++)
            wf[j] = *reinterpret_cast<const bf16x8*>(
                &Bs[(wc * 64 + j * 16 + (lane & 15)) * 32 + (lane >> 4) * 8]);
#pragma unroll
        for (int i = 0; i < 4; i++)
#pragma unroll
            for (int j = 0; j < 4; j++)
                acc[i][j] = __builtin_amdgcn_mfma_f32_16x16x32_bf16(af[i], wf[j], acc[i][j], 0, 0, 0);
        __syncthreads();
    }

    float* C = partial + (size_t)s * (BLROWS * 128);
    int colb = wc * 64 + (lane & 15);
    int rowb = m_blk + wr * 64 + (lane >> 4) * 4;
#pragma unroll
    for (int i = 0; i < 4; i++)
#pragma unroll
        for (int j = 0; j < 4; j++)
#pragma unroll
            for (int r = 0; r < 4; r++)
                C[(size_t)(rowb + i * 16 + r) * 128 + colb + j * 16] = acc[i][j][r];
}

// Reduce split-K partials -> dbc f32 [2048][96] and dbcb bf16 [2048][64].
__global__ __launch_bounds__(256) void reduce_dbc(const float* __restrict__ partial,
                                                  float* __restrict__ dbc,
                                                  unsigned short* __restrict__ dbcb) {
    int id = blockIdx.x * 256 + threadIdx.x;   // 0 .. 2048*96-1
    int r = id / 96;
    int j = id - r * 96;
    float s = 0.f;
#pragma unroll
    for (int k = 0; k < KSPL; k++)
        s += partial[(size_t)k * (BLROWS * 128) + (size_t)r * 128 + j];
    dbc[(size_t)r * 96 + j] = s;
    if (j < DTR) dbcb[(size_t)r * DTR + j] = f2bf(s);
}

// ---------------------------------------------------------------------------
// Causal conv1d (k=4) + SiLU; writes uc f32 (for scan) and ucb bf16 (for GEMM).
// ---------------------------------------------------------------------------
__global__ __launch_bounds__(256) void conv_silu_kernel(const float* __restrict__ U,
                                                        const float* __restrict__ cw,
                                                        const float* __restrict__ cb,
                                                        float* __restrict__ uc,
                                                        unsigned short* __restrict__ ucb,
                                                        int dir) {
    int idx = blockIdx.x * 256 + threadIdx.x;       // over 2*1024*2048
    int c = idx & (DI - 1);
    int t = (idx >> 11) & (LSEQ - 1);
    int b = idx >> 21;
    float acc = cb[c];
#pragma unroll
    for (int k = 0; k < 4; k++) {
        int tt = dir ? (t + 3 - k) : (t - 3 + k);
        if (tt >= 0 && tt < LSEQ)
            acc = fmaf(cw[c * 4 + k], U[((size_t)(b * LSEQ + tt)) * (2 * DI) + c], acc);
    }
    float v = silu_f(acc);
    uc[idx]  = v;
    ucb[idx] = f2bf(v);
}

// ---------------------------------------------------------------------------
// Chunked selective scan, lane-per-channel layout (16 states in registers).
// ---------------------------------------------------------------------------
__global__ __launch_bounds__(256) void scan_p1(const float* __restrict__ dtv,
                                               const float* __restrict__ uc,
                                               const float* __restrict__ dbc,
                                               const float* __restrict__ A_log,
                                               float* __restrict__ hend,
                                               float* __restrict__ Pprod,
                                               int dir) {
    int c     = blockIdx.x * 256 + threadIdx.x;
    int chunk = blockIdx.y;
    int b     = blockIdx.z;

    __shared__ float Bs[CLEN][16];
    for (int i = threadIdx.x; i < CLEN * 16; i += 256) {
        int s = i >> 4, j = i & 15;
        int sigma = chunk * CLEN + s;
        int t = dir ? (LSEQ - 1 - sigma) : sigma;
        Bs[s][j] = dbc[((size_t)b * LSEQ + t) * 96 + DTR + j];
    }
    __syncthreads();

    const float LOG2E = 1.4426950408889634f;
    float A2[16], h[16], P[16];
#pragma unroll
    for (int n = 0; n < 16; n++) {
        A2[n] = -__expf(A_log[c * DST + n]) * LOG2E;
        h[n] = 0.f;
        P[n] = 1.f;
    }

    int s0 = chunk * CLEN;
#pragma unroll 2
    for (int s = 0; s < CLEN; s++) {
        int sigma = s0 + s;
        int t = dir ? (LSEQ - 1 - sigma) : sigma;
        size_t row = (size_t)b * LSEQ + t;
        float dt = dtv[row * DI + c];
        float u  = uc[row * DI + c];
        float du = dt * u;
        float Bv[16];
#pragma unroll
        for (int q = 0; q < 4; q++)
            reinterpret_cast<float4*>(Bv)[q] = reinterpret_cast<const float4*>(Bs[s])[q];
#pragma unroll
        for (int n = 0; n < 16; n++) {
            float dA = exp2f(dt * A2[n]);
            h[n] = dA * h[n] + du * Bv[n];
            P[n] *= dA;
        }
    }
    size_t base = (((size_t)b * NCHUNK + chunk) * DI + c) * DST;
#pragma unroll
    for (int n = 0; n < 16; n++) {
        hend[base + n]  = h[n];
        Pprod[base + n] = P[n];
    }
}

// Combine: per (b,c,n), prefix over chunks. h0 ALIASES Pprod (read P first!).
__global__ __launch_bounds__(256) void scan_p2(const float* __restrict__ hend,
                                               float* __restrict__ P_h0) {
    int id = blockIdx.x * 256 + threadIdx.x;     // 0 .. NBAT*DI*DST-1
    size_t base = (size_t)(id & (DI * DST - 1)) + (size_t)(id >> 15) * ((size_t)NCHUNK * DI * DST);
    float h = 0.f;
    for (int k = 0; k < NCHUNK; k++) {
        size_t idx = base + (size_t)k * (DI * DST);
        float Pv = P_h0[idx];
        float hv = hend[idx];
        P_h0[idx] = h;
        h = Pv * h + hv;
    }
}

__global__ __launch_bounds__(256) void scan_p3(const float* __restrict__ dtv,
                                               const float* __restrict__ uc,
                                               const float* __restrict__ dbc,
                                               const float* __restrict__ U,
                                               const float* __restrict__ A_log,
                                               const float* __restrict__ Dp,
                                               const float* __restrict__ h0,
                                               unsigned short* __restrict__ Gb,
                                               int dir) {
    int c     = blockIdx.x * 256 + threadIdx.x;
    int chunk = blockIdx.y;
    int b     = blockIdx.z;

    __shared__ float BCs[CLEN][32];
    for (int i = threadIdx.x; i < CLEN * 32; i += 256) {
        int s = i >> 5, j = i & 31;
        int sigma = chunk * CLEN + s;
        int t = dir ? (LSEQ - 1 - sigma) : sigma;
        BCs[s][j] = dbc[((size_t)b * LSEQ + t) * 96 + DTR + j];
    }
    __syncthreads();

    const float LOG2E = 1.4426950408889634f;
    float A2[16], h[16];
    size_t base = (((size_t)b * NCHUNK + chunk) * DI + c) * DST;
#pragma unroll
    for (int n = 0; n < 16; n++) {
        A2[n] = -__expf(A_log[c * DST + n]) * LOG2E;
        h[n]  = h0[base + n];
    }
    float Dv = Dp[c];

    int s0 = chunk * CLEN;
#pragma unroll 2
    for (int s = 0; s < CLEN; s++) {
        int sigma = s0 + s;
        int t = dir ? (LSEQ - 1 - sigma) : sigma;
        size_t row = (size_t)b * LSEQ + t;
        float dt = dtv[row * DI + c];
        float u  = uc[row * DI + c];
        float du = dt * u;
        float BCv[32];
#pragma unroll
        for (int q = 0; q < 8; q++)
            reinterpret_cast<float4*>(BCv)[q] = reinterpret_cast<const float4*>(BCs[s])[q];
        float y = 0.f;
#pragma unroll
        for (int n = 0; n < 16; n++) {
            float dA = exp2f(dt * A2[n]);
            h[n] = dA * h[n] + du * BCv[n];
            y = fmaf(h[n], BCv[16 + n], y);
        }
        float yy = y + u * Dv;
        float z  = U[row * (2 * DI) + DI + c];
        Gb[row * DI + c] = f2bf(yy * silu_f(z));
    }
}

// ---------------------------------------------------------------------------
extern "C" void kernel_launch(void* const* d_in, const int* in_sizes, int n_in,
                              void* d_out, int out_size, void* d_ws, size_t ws_size,
                              hipStream_t stream) {
    const float* x    = (const float*)d_in[0];
    const float* ln_g = (const float*)d_in[1];
    const float* ln_b = (const float*)d_in[2];
    float* out = (float*)d_out;

    char* wp = (char*)d_ws;
    unsigned short* xnb = (unsigned short*)wp; wp += (size_t)BLROWS * DM * 2;     // 4 MB
    float* U    = (float*)wp; wp += (size_t)BLROWS * 2 * DI * 4;                  // 32 MB
    float* uc   = (float*)wp; wp += (size_t)BLROWS * DI * 4;                      // 16 MB
    float* dbc  = (float*)wp; wp += (size_t)BLROWS * 96 * 4;                      // .75 MB
    float* dtv  = (float*)wp; wp += (size_t)BLROWS * DI * 4;                      // 16 MB (aliases split-K partial)
    unsigned short* Gb = (unsigned short*)wp; wp += (size_t)BLROWS * DI * 2;      // 8 MB (aliases ucb)
    float* hend  = (float*)wp; wp += (size_t)NBAT * NCHUNK * DI * DST * 4;        // 8 MB (out_wb aliases)
    float* Pprod = (float*)wp; wp += (size_t)NBAT * NCHUNK * DI * DST * 4;        // 8 MB (doubles as h0)
    unsigned short* in_wb  = (unsigned short*)wp; wp += (size_t)2 * DI * DM * 2;  // 8 MB
    unsigned short* xprojb = (unsigned short*)wp; wp += (size_t)128 * DI * 2;     // 0.5 MB
    unsigned short* dt_wb  = (unsigned short*)wp; wp += (size_t)DI * DTR * 2;     // 0.25 MB
    unsigned short* dbcb   = (unsigned short*)wp; wp += (size_t)BLROWS * DTR * 2; // 0.25 MB

    // aliases (disjoint lifetimes within a branch)
    float* partial = dtv;                         // [KSPL][2048][128] f32 = 16 MB
    unsigned short* ucb = Gb;                     // [2048][2048] bf16 = 8 MB
    unsigned short* out_wb = (unsigned short*)hend;
    float* h0 = Pprod;

    ln_kernel<<<BLROWS, 256, 0, stream>>>(x, ln_g, ln_b, xnb);

    for (int br = 0; br < 2; br++) {
        const float* in_w    = (const float*)d_in[3 + 9 * br + 0];
        const float* conv_w  = (const float*)d_in[3 + 9 * br + 1];
        const float* conv_b  = (const float*)d_in[3 + 9 * br + 2];
        const float* xproj_w = (const float*)d_in[3 + 9 * br + 3];
        const float* dt_w    = (const float*)d_in[3 + 9 * br + 4];
        const float* dt_b    = (const float*)d_in[3 + 9 * br + 5];
        const float* A_log   = (const float*)d_in[3 + 9 * br + 6];
        const float* Dp      = (const float*)d_in[3 + 9 * br + 7];
        const float* out_w   = (const float*)d_in[3 + 9 * br + 8];

        // weight casts
        cast_kernel<<<(2 * DI * DM) / 1024, 256, 0, stream>>>(in_w, in_wb, 2 * DI * DM);
        padcast_xproj<<<(128 * DI) / 1024, 256, 0, stream>>>(xproj_w, xprojb);
        cast_kernel<<<(DI * DTR) / 1024, 256, 0, stream>>>(dt_w, dt_wb, DI * DTR);

        // U = xnb @ in_wb.T   (2048 x 4096 x 1024) -> f32
        gemm_mfma<0><<<dim3(2 * DI / 128, BLROWS / 128), 256, 0, stream>>>(
            xnb, in_wb, nullptr, nullptr, U, 2 * DI, DM);

        // uc/ucb = silu(conv1d(u) + cb)
        conv_silu_kernel<<<(BLROWS * DI) / 256, 256, 0, stream>>>(U, conv_w, conv_b, uc, ucb, br);

        // dbc = ucb @ xprojb.T  via split-K MFMA + reduce
        gemm_sk<<<dim3(BLROWS / 128, KSPL), 256, 0, stream>>>(ucb, xprojb, partial);
        reduce_dbc<<<(BLROWS * 96) / 256, 256, 0, stream>>>(partial, dbc, dbcb);

        // dtv = softplus(dbcb @ dt_wb.T + dt_b)   (2048 x 2048 x 64) MFMA
        gemm_mfma<1><<<dim3(DI / 128, BLROWS / 128), 256, 0, stream>>>(
            dbcb, dt_wb, nullptr, dt_b, dtv, DI, DTR);

        // chunked selective scan + gating -> Gb (bf16)
        scan_p1<<<dim3(DI / 256, NCHUNK, NBAT), 256, 0, stream>>>(
            dtv, uc, dbc, A_log, hend, Pprod, br);
        scan_p2<<<(NBAT * DI * DST) / 256, 256, 0, stream>>>(hend, Pprod);
        // hend now dead -> cast out_w into its storage
        cast_kernel<<<(DM * DI) / 1024, 256, 0, stream>>>(out_w, out_wb, DM * DI);
        scan_p3<<<dim3(DI / 256, NCHUNK, NBAT), 256, 0, stream>>>(
            dtv, uc, dbc, U, A_log, Dp, h0, Gb, br);

        // out (+)= Gb @ out_wb.T  (+ x residual on first branch)
        if (br == 0) {
            gemm_mfma<2><<<dim3(DM / 128, BLROWS / 128), 256, 0, stream>>>(
                Gb, out_wb, x, nullptr, out, DM, DI);
        } else {
            gemm_mfma<3><<<dim3(DM / 128, BLROWS / 128), 256, 0, stream>>>(
                Gb, out_wb, nullptr, nullptr, out, DM, DI);
        }
    }
}

// Round 6
// 374.269 us; speedup vs baseline: 7.3129x; 1.1760x over previous
//
#include <hip/hip_runtime.h>
#include <math.h>

#define DM   1024   // d_model
#define DI   2048   // d_inner
#define DST  16     // d_state
#define DTR  64     // dt_rank
#define LSEQ 1024   // L
#define NBAT 2      // B
#define BLROWS (NBAT*LSEQ)   // 2048 token rows
#define NCHUNK 32
#define CLEN   32   // LSEQ / NCHUNK
#define KSPL   16   // K-splits for xproj GEMM

typedef __bf16 bf16x8 __attribute__((ext_vector_type(8)));
typedef float  f32x4  __attribute__((ext_vector_type(4)));

__device__ __forceinline__ float silu_f(float x) {
    return x / (1.f + __expf(-x));
}
__device__ __forceinline__ float softplus_f(float x) {
    return (x > 20.f) ? x : __logf(1.f + __expf(x));
}
// round-to-nearest-even f32 -> bf16 (as ushort)
__device__ __forceinline__ unsigned short f2bf(float f) {
    unsigned int u = __float_as_uint(f);
    u = (u + 0x7FFFu + ((u >> 16) & 1u)) >> 16;
    return (unsigned short)u;
}
__device__ __forceinline__ float b2f(unsigned short u) {
    return __uint_as_float(((unsigned int)u) << 16);
}

__device__ __forceinline__ const __attribute__((address_space(1))) void* as1(const void* p) {
    return (const __attribute__((address_space(1))) void*)(uintptr_t)p;
}
__device__ __forceinline__ __attribute__((address_space(3))) void* as3(void* p) {
    return (__attribute__((address_space(3))) void*)(uintptr_t)p;
}

// ---------------------------------------------------------------------------
// f32 -> bf16 cast, vectorized. n must be a multiple of 1024.
// ---------------------------------------------------------------------------
__global__ __launch_bounds__(256) void cast_kernel(const float* __restrict__ in,
                                                   unsigned short* __restrict__ out,
                                                   int n) {
    int i = (blockIdx.x * 256 + threadIdx.x) * 4;
    if (i >= n) return;
    float4 v = *reinterpret_cast<const float4*>(in + i);
    ushort4 o;
    o.x = f2bf(v.x); o.y = f2bf(v.y); o.z = f2bf(v.z); o.w = f2bf(v.w);
    *reinterpret_cast<ushort4*>(out + i) = o;
}

// out_w [1024][2048] f32 -> out_wb2 [1024][4096] bf16 at column offset dstoff.
__global__ __launch_bounds__(256) void cast_cc(const float* __restrict__ in,
                                               unsigned short* __restrict__ out,
                                               int dstoff) {
    int i = (blockIdx.x * 256 + threadIdx.x) * 4;   // over 1024*2048
    int r = i >> 11, c = i & 2047;
    float4 v = *reinterpret_cast<const float4*>(in + i);
    ushort4 o;
    o.x = f2bf(v.x); o.y = f2bf(v.y); o.z = f2bf(v.z); o.w = f2bf(v.w);
    *reinterpret_cast<ushort4*>(out + (size_t)r * 4096 + dstoff + c) = o;
}

// xproj_w [96][2048] f32 -> [128][2048] bf16, rows 96..127 zeroed.
__global__ __launch_bounds__(256) void padcast_xproj(const float* __restrict__ in,
                                                     unsigned short* __restrict__ out) {
    int i = (blockIdx.x * 256 + threadIdx.x) * 4;   // over 128*2048
    int row = i >> 11;
    ushort4 o = make_ushort4(0, 0, 0, 0);
    if (row < 96) {
        float4 v = *reinterpret_cast<const float4*>(in + i);
        o.x = f2bf(v.x); o.y = f2bf(v.y); o.z = f2bf(v.z); o.w = f2bf(v.w);
    }
    *reinterpret_cast<ushort4*>(out + i) = o;
}

// ---------------------------------------------------------------------------
// LayerNorm: one block per token row (1024 elems), 256 threads. Writes bf16.
// ---------------------------------------------------------------------------
__global__ __launch_bounds__(256) void ln_kernel(const float* __restrict__ x,
                                                 const float* __restrict__ g,
                                                 const float* __restrict__ b,
                                                 unsigned short* __restrict__ xnb) {
    int row = blockIdx.x;
    const float* xr = x + (size_t)row * DM;
    float v[4];
    float s = 0.f, s2 = 0.f;
#pragma unroll
    for (int i = 0; i < 4; i++) {
        v[i] = xr[threadIdx.x + i * 256];
        s += v[i];
        s2 += v[i] * v[i];
    }
#pragma unroll
    for (int off = 32; off; off >>= 1) {
        s  += __shfl_down(s, off);
        s2 += __shfl_down(s2, off);
    }
    __shared__ float ss[4], ss2[4];
    int wid = threadIdx.x >> 6, lane = threadIdx.x & 63;
    if (lane == 0) { ss[wid] = s; ss2[wid] = s2; }
    __syncthreads();
    if (threadIdx.x == 0) {
        float a = 0.f, a2 = 0.f;
#pragma unroll
        for (int i = 0; i < 4; i++) { a += ss[i]; a2 += ss2[i]; }
        ss[0] = a; ss2[0] = a2;
    }
    __syncthreads();
    float m   = ss[0] * (1.f / DM);
    float var = ss2[0] * (1.f / DM) - m * m;
    float inv = rsqrtf(var + 1e-5f);
#pragma unroll
    for (int i = 0; i < 4; i++) {
        int c = threadIdx.x + i * 256;
        xnb[(size_t)row * DM + c] = f2bf((v[i] - m) * inv * g[c] + b[c]);
    }
}

// ---------------------------------------------------------------------------
// Unified bf16 MFMA NT GEMM, 128x128 tile, BK=32, 4 waves, double-buffered
// LDS (T3-minimum 2-phase: stage k+1 before compute k, one barrier/iter).
// Kst = row stride of A and W (full K); klen = per-z K slice;
// kbeg = blockIdx.z*klen; C (MODE 0) offset by blockIdx.z*zstride.
// MODE 0: f32 store    MODE 4: bf16 store    MODE 5: bf16 softplus(acc+bias)
// ---------------------------------------------------------------------------
template <int MODE>
__global__ __launch_bounds__(256) void gemm_mfma(const unsigned short* __restrict__ A,
                                                 const unsigned short* __restrict__ W,
                                                 const float* __restrict__ bias,
                                                 void* __restrict__ Cv, int ldc,
                                                 int Kst, int klen, size_t zstride) {
    __shared__ unsigned short As[2][128 * 32];
    __shared__ unsigned short Bs[2][128 * 32];

    int tid  = threadIdx.x;
    int lane = tid & 63;
    int w    = tid >> 6;
    int wr   = w >> 1;
    int wc   = w & 1;
    int m_blk = blockIdx.y * 128;
    int n_blk = blockIdx.x * 128;
    int kbeg  = blockIdx.z * klen;

    int srow = (2 * w) * 16 + (lane >> 2);
    int scol = (lane & 3) * 8;
    const unsigned short* Ag0 = A + (size_t)(m_blk + srow) * Kst + scol;
    const unsigned short* Ag1 = Ag0 + (size_t)16 * Kst;
    const unsigned short* Wg0 = W + (size_t)(n_blk + srow) * Kst + scol;
    const unsigned short* Wg1 = Wg0 + (size_t)16 * Kst;
    int d0 = (2 * w) * 512, d1 = (2 * w + 1) * 512;

    f32x4 acc[4][4] = {};

    auto STAGE = [&](int buf, int k0) {
        __builtin_amdgcn_global_load_lds(as1(Ag0 + k0), as3(&As[buf][d0]), 16, 0, 0);
        __builtin_amdgcn_global_load_lds(as1(Ag1 + k0), as3(&As[buf][d1]), 16, 0, 0);
        __builtin_amdgcn_global_load_lds(as1(Wg0 + k0), as3(&Bs[buf][d0]), 16, 0, 0);
        __builtin_amdgcn_global_load_lds(as1(Wg1 + k0), as3(&Bs[buf][d1]), 16, 0, 0);
    };
    auto COMPUTE = [&](int buf) {
        bf16x8 af[4], wf[4];
#pragma unroll
        for (int i = 0; i < 4; i++)
            af[i] = *reinterpret_cast<const bf16x8*>(
                &As[buf][(wr * 64 + i * 16 + (lane & 15)) * 32 + (lane >> 4) * 8]);
#pragma unroll
        for (int j = 0; j < 4; j++)
            wf[j] = *reinterpret_cast<const bf16x8*>(
                &Bs[buf][(wc * 64 + j * 16 + (lane & 15)) * 32 + (lane >> 4) * 8]);
#pragma unroll
        for (int i = 0; i < 4; i++)
#pragma unroll
            for (int j = 0; j < 4; j++)
                acc[i][j] = __builtin_amdgcn_mfma_f32_16x16x32_bf16(af[i], wf[j], acc[i][j], 0, 0, 0);
    };

    STAGE(0, kbeg);
    asm volatile("s_waitcnt vmcnt(0)" ::: "memory");
    __syncthreads();
    int cur = 0;
    for (int k0 = kbeg + 32; k0 < kbeg + klen; k0 += 32) {
        STAGE(cur ^ 1, k0);      // prefetch next tile (in flight during compute)
        COMPUTE(cur);
        asm volatile("s_waitcnt vmcnt(0)" ::: "memory");
        __syncthreads();
        cur ^= 1;
    }
    COMPUTE(cur);

    int colb = n_blk + wc * 64 + (lane & 15);
    int rowb = m_blk + wr * 64 + (lane >> 4) * 4;
#pragma unroll
    for (int i = 0; i < 4; i++) {
#pragma unroll
        for (int j = 0; j < 4; j++) {
#pragma unroll
            for (int r = 0; r < 4; r++) {
                int row = rowb + i * 16 + r;
                int col = colb + j * 16;
                size_t off = (size_t)row * ldc + col;
                float v = acc[i][j][r];
                if (MODE == 0) {
                    ((float*)Cv + blockIdx.z * zstride)[off] = v;
                } else if (MODE == 4) {
                    ((unsigned short*)Cv)[off] = f2bf(v);
                } else { // 5
                    ((unsigned short*)Cv)[off] = f2bf(softplus_f(v + bias[col]));
                }
            }
        }
    }
}

// Reduce xproj split-K partials -> dbc f32 [2048][96] and dbcb bf16 [2048][64].
__global__ __launch_bounds__(256) void reduce_dbc(const float* __restrict__ partial,
                                                  float* __restrict__ dbc,
                                                  unsigned short* __restrict__ dbcb) {
    int id = blockIdx.x * 256 + threadIdx.x;   // 0 .. 2048*96-1
    int r = id / 96;
    int j = id - r * 96;
    float s = 0.f;
#pragma unroll
    for (int k = 0; k < KSPL; k++)
        s += partial[(size_t)k * (BLROWS * 128) + (size_t)r * 128 + j];
    dbc[(size_t)r * 96 + j] = s;
    if (j < DTR) dbcb[(size_t)r * DTR + j] = f2bf(s);
}

// out = x + partial2[0] + partial2[1]   (2048*1024 f32)
__global__ __launch_bounds__(256) void reduce_out(const float* __restrict__ p,
                                                  const float* __restrict__ x,
                                                  float* __restrict__ out) {
    int i = (blockIdx.x * 256 + threadIdx.x) * 4;
    float4 a  = *reinterpret_cast<const float4*>(p + i);
    float4 b  = *reinterpret_cast<const float4*>(p + 2097152 + i);
    float4 xv = *reinterpret_cast<const float4*>(x + i);
    float4 o;
    o.x = xv.x + a.x + b.x; o.y = xv.y + a.y + b.y;
    o.z = xv.z + a.z + b.z; o.w = xv.w + a.w + b.w;
    *reinterpret_cast<float4*>(out + i) = o;
}

// ---------------------------------------------------------------------------
// Causal conv1d (k=4) + SiLU over branch's u half of Ub (bf16 in, bf16 out).
// Ubr = Ub + br*4096 (row stride 8192).
// ---------------------------------------------------------------------------
__global__ __launch_bounds__(256) void conv_silu_kernel(const unsigned short* __restrict__ Ubr,
                                                        const float* __restrict__ cw,
                                                        const float* __restrict__ cb,
                                                        unsigned short* __restrict__ ucb,
                                                        int dir) {
    int idx = blockIdx.x * 256 + threadIdx.x;       // over 2*1024*2048
    int c = idx & (DI - 1);
    int t = (idx >> 11) & (LSEQ - 1);
    int b = idx >> 21;
    float acc = cb[c];
#pragma unroll
    for (int k = 0; k < 4; k++) {
        int tt = dir ? (t + 3 - k) : (t - 3 + k);
        if (tt >= 0 && tt < LSEQ)
            acc = fmaf(cw[c * 4 + k], b2f(Ubr[((size_t)(b * LSEQ + tt)) * (2 * 2 * DI) + c]), acc);
    }
    ucb[idx] = f2bf(silu_f(acc));
}

// ---------------------------------------------------------------------------
// Chunked selective scan, lane-per-channel layout (16 states in registers).
// ---------------------------------------------------------------------------
__global__ __launch_bounds__(256) void scan_p1(const unsigned short* __restrict__ dtvb,
                                               const unsigned short* __restrict__ ucb,
                                               const float* __restrict__ dbc,
                                               const float* __restrict__ A_log,
                                               float* __restrict__ hend,
                                               float* __restrict__ Pprod,
                                               int dir) {
    int c     = blockIdx.x * 256 + threadIdx.x;
    int chunk = blockIdx.y;
    int b     = blockIdx.z;

    __shared__ float Bs[CLEN][16];
    for (int i = threadIdx.x; i < CLEN * 16; i += 256) {
        int s = i >> 4, j = i & 15;
        int sigma = chunk * CLEN + s;
        int t = dir ? (LSEQ - 1 - sigma) : sigma;
        Bs[s][j] = dbc[((size_t)b * LSEQ + t) * 96 + DTR + j];
    }
    __syncthreads();

    const float LOG2E = 1.4426950408889634f;
    float A2[16], h[16], P[16];
#pragma unroll
    for (int n = 0; n < 16; n++) {
        A2[n] = -__expf(A_log[c * DST + n]) * LOG2E;
        h[n] = 0.f;
        P[n] = 1.f;
    }

    int s0 = chunk * CLEN;
#pragma unroll 2
    for (int s = 0; s < CLEN; s++) {
        int sigma = s0 + s;
        int t = dir ? (LSEQ - 1 - sigma) : sigma;
        size_t row = (size_t)b * LSEQ + t;
        float dt = b2f(dtvb[row * DI + c]);
        float u  = b2f(ucb[row * DI + c]);
        float du = dt * u;
        float Bv[16];
#pragma unroll
        for (int q = 0; q < 4; q++)
            reinterpret_cast<float4*>(Bv)[q] = reinterpret_cast<const float4*>(Bs[s])[q];
#pragma unroll
        for (int n = 0; n < 16; n++) {
            float dA = exp2f(dt * A2[n]);
            h[n] = dA * h[n] + du * Bv[n];
            P[n] *= dA;
        }
    }
    size_t base = (((size_t)b * NCHUNK + chunk) * DI + c) * DST;
#pragma unroll
    for (int n = 0; n < 16; n++) {
        hend[base + n]  = h[n];
        Pprod[base + n] = P[n];
    }
}

// Combine: per (b,c,n), prefix over chunks. h0 ALIASES Pprod (read P first!).
__global__ __launch_bounds__(256) void scan_p2(const float* __restrict__ hend,
                                               float* __restrict__ P_h0) {
    int id = blockIdx.x * 256 + threadIdx.x;     // 0 .. NBAT*DI*DST-1
    size_t base = (size_t)(id & (DI * DST - 1)) + (size_t)(id >> 15) * ((size_t)NCHUNK * DI * DST);
    float h = 0.f;
    for (int k = 0; k < NCHUNK; k++) {
        size_t idx = base + (size_t)k * (DI * DST);
        float Pv = P_h0[idx];
        float hv = hend[idx];
        P_h0[idx] = h;
        h = Pv * h + hv;
    }
}

__global__ __launch_bounds__(256) void scan_p3(const unsigned short* __restrict__ dtvb,
                                               const unsigned short* __restrict__ ucb,
                                               const float* __restrict__ dbc,
                                               const unsigned short* __restrict__ Ubz, // +br*4096+2048
                                               const float* __restrict__ A_log,
                                               const float* __restrict__ Dp,
                                               const float* __restrict__ h0,
                                               unsigned short* __restrict__ Gp,  // G2 + br*2048
                                               int dir) {
    int c     = blockIdx.x * 256 + threadIdx.x;
    int chunk = blockIdx.y;
    int b     = blockIdx.z;

    __shared__ float BCs[CLEN][32];
    for (int i = threadIdx.x; i < CLEN * 32; i += 256) {
        int s = i >> 5, j = i & 31;
        int sigma = chunk * CLEN + s;
        int t = dir ? (LSEQ - 1 - sigma) : sigma;
        BCs[s][j] = dbc[((size_t)b * LSEQ + t) * 96 + DTR + j];
    }
    __syncthreads();

    const float LOG2E = 1.4426950408889634f;
    float A2[16], h[16];
    size_t base = (((size_t)b * NCHUNK + chunk) * DI + c) * DST;
#pragma unroll
    for (int n = 0; n < 16; n++) {
        A2[n] = -__expf(A_log[c * DST + n]) * LOG2E;
        h[n]  = h0[base + n];
    }
    float Dv = Dp[c];

    int s0 = chunk * CLEN;
#pragma unroll 2
    for (int s = 0; s < CLEN; s++) {
        int sigma = s0 + s;
        int t = dir ? (LSEQ - 1 - sigma) : sigma;
        size_t row = (size_t)b * LSEQ + t;
        float dt = b2f(dtvb[row * DI + c]);
        float u  = b2f(ucb[row * DI + c]);
        float du = dt * u;
        float BCv[32];
#pragma unroll
        for (int q = 0; q < 8; q++)
            reinterpret_cast<float4*>(BCv)[q] = reinterpret_cast<const float4*>(BCs[s])[q];
        float y = 0.f;
#pragma unroll
        for (int n = 0; n < 16; n++) {
            float dA = exp2f(dt * A2[n]);
            h[n] = dA * h[n] + du * BCv[n];
            y = fmaf(h[n], BCv[16 + n], y);
        }
        float yy = y + u * Dv;
        float z  = b2f(Ubz[row * (2 * 2 * DI) + c]);
        Gp[row * (2 * DI) + c] = f2bf(yy * silu_f(z));
    }
}

// ---------------------------------------------------------------------------
extern "C" void kernel_launch(void* const* d_in, const int* in_sizes, int n_in,
                              void* d_out, int out_size, void* d_ws, size_t ws_size,
                              hipStream_t stream) {
    const float* x    = (const float*)d_in[0];
    const float* ln_g = (const float*)d_in[1];
    const float* ln_b = (const float*)d_in[2];
    float* out = (float*)d_out;

    char* wp = (char*)d_ws;
    unsigned short* xnb    = (unsigned short*)wp; wp += (size_t)BLROWS * DM * 2;      // 4 MB
    unsigned short* Ub     = (unsigned short*)wp; wp += (size_t)BLROWS * 4 * DI * 2;  // 32 MB [2048][8192]
    unsigned short* in_wb2 = (unsigned short*)wp; wp += (size_t)4 * DI * DM * 2;      // 16 MB [8192][1024]
    unsigned short* ucb    = (unsigned short*)wp; wp += (size_t)BLROWS * DI * 2;      // 8 MB (per-branch reuse)
    float* dbc             = (float*)wp;          wp += (size_t)BLROWS * 96 * 4;      // .75 MB
    unsigned short* dbcb   = (unsigned short*)wp; wp += (size_t)BLROWS * DTR * 2;     // .25 MB
    unsigned short* dtvb   = (unsigned short*)wp; wp += (size_t)BLROWS * DI * 2;      // 8 MB (per-branch reuse)
    unsigned short* G2     = (unsigned short*)wp; wp += (size_t)BLROWS * 2 * DI * 2;  // 16 MB [2048][4096]
    float* hend            = (float*)wp;          wp += (size_t)NBAT * NCHUNK * DI * DST * 4; // 8 MB
    float* Pprod           = (float*)wp;          wp += (size_t)NBAT * NCHUNK * DI * DST * 4; // 8 MB
    unsigned short* xprojb = (unsigned short*)wp; wp += (size_t)128 * DI * 2;         // .5 MB
    unsigned short* dt_wb  = (unsigned short*)wp; wp += (size_t)DI * DTR * 2;         // .25 MB
    // total 101.75 MB

    // aliases (disjoint lifetimes):
    float* partial  = hend;                        // [16][2048][128] f32 = 16 MB, dead before scan_p1
    float* partial2 = hend;                        // [2][2048][1024] f32 = 16 MB, used after scan_p3 (br=1)
    unsigned short* out_wb2 = in_wb2;              // [1024][4096] bf16 = 8 MB, in_wb2 dead after in-proj
    float* h0 = Pprod;                             // scan_p2 rewrites Pprod in place

    ln_kernel<<<BLROWS, 256, 0, stream>>>(x, ln_g, ln_b, xnb);

    // cast both branches' in_w into one [8192][1024] buffer
    cast_kernel<<<(2 * DI * DM) / 1024, 256, 0, stream>>>(
        (const float*)d_in[3], in_wb2, 2 * DI * DM);
    cast_kernel<<<(2 * DI * DM) / 1024, 256, 0, stream>>>(
        (const float*)d_in[12], in_wb2 + (size_t)2 * DI * DM, 2 * DI * DM);

    // batched in-proj: Ub = xnb @ in_wb2.T  (2048 x 8192 x 1024), bf16 out
    gemm_mfma<4><<<dim3(4 * DI / 128, BLROWS / 128, 1), 256, 0, stream>>>(
        xnb, in_wb2, nullptr, Ub, 4 * DI, DM, DM, 0);

    for (int br = 0; br < 2; br++) {
        const float* conv_w  = (const float*)d_in[3 + 9 * br + 1];
        const float* conv_b  = (const float*)d_in[3 + 9 * br + 2];
        const float* xproj_w = (const float*)d_in[3 + 9 * br + 3];
        const float* dt_w    = (const float*)d_in[3 + 9 * br + 4];
        const float* dt_b    = (const float*)d_in[3 + 9 * br + 5];
        const float* A_log   = (const float*)d_in[3 + 9 * br + 6];
        const float* Dp      = (const float*)d_in[3 + 9 * br + 7];

        padcast_xproj<<<(128 * DI) / 1024, 256, 0, stream>>>(xproj_w, xprojb);
        cast_kernel<<<(DI * DTR) / 1024, 256, 0, stream>>>(dt_w, dt_wb, DI * DTR);

        // ucb = silu(conv1d(u) + cb)  (bf16)
        conv_silu_kernel<<<(BLROWS * DI) / 256, 256, 0, stream>>>(
            Ub + (size_t)br * 2 * DI, conv_w, conv_b, ucb, br);

        // dbc = ucb @ xprojb.T via split-K MFMA + reduce
        gemm_mfma<0><<<dim3(1, BLROWS / 128, KSPL), 256, 0, stream>>>(
            ucb, xprojb, nullptr, partial, 128, DI, DI / KSPL, (size_t)BLROWS * 128);
        reduce_dbc<<<(BLROWS * 96) / 256, 256, 0, stream>>>(partial, dbc, dbcb);

        // dtvb = softplus(dbcb @ dt_wb.T + dt_b)  (2048 x 2048 x 64), bf16 out
        gemm_mfma<5><<<dim3(DI / 128, BLROWS / 128, 1), 256, 0, stream>>>(
            dbcb, dt_wb, dt_b, dtvb, DI, DTR, DTR, 0);

        // chunked selective scan + gating -> G2 columns [br*2048, br*2048+2048)
        scan_p1<<<dim3(DI / 256, NCHUNK, NBAT), 256, 0, stream>>>(
            dtvb, ucb, dbc, A_log, hend, Pprod, br);
        scan_p2<<<(NBAT * DI * DST) / 256, 256, 0, stream>>>(hend, Pprod);
        scan_p3<<<dim3(DI / 256, NCHUNK, NBAT), 256, 0, stream>>>(
            dtvb, ucb, dbc, Ub + (size_t)br * 2 * DI + DI, A_log, Dp, h0,
            G2 + (size_t)br * DI, br);
    }

    // combined out-proj: out = x + [G_f|G_b] @ [W_f|W_b].T  (K = 4096, split-K 2)
    cast_cc<<<(DM * DI) / 1024, 256, 0, stream>>>((const float*)d_in[11], out_wb2, 0);
    cast_cc<<<(DM * DI) / 1024, 256, 0, stream>>>((const float*)d_in[20], out_wb2, DI);
    gemm_mfma<0><<<dim3(DM / 128, BLROWS / 128, 2), 256, 0, stream>>>(
        G2, out_wb2, nullptr, partial2, DM, 2 * DI, DI, (size_t)BLROWS * DM);
    reduce_out<<<(BLROWS * DM) / 1024, 256, 0, stream>>>(partial2, x, out);
}

// Round 8
// 320.988 us; speedup vs baseline: 8.5268x; 1.1660x over previous
//
#include <hip/hip_runtime.h>
#include <math.h>

#define DM   1024   // d_model
#define DI   2048   // d_inner
#define DST  16     // d_state
#define DTR  64     // dt_rank
#define LSEQ 1024   // L
#define NBAT 2      // B
#define BLROWS (NBAT*LSEQ)   // 2048 token rows
#define NCHUNK 32
#define CLEN   32   // LSEQ / NCHUNK
#define KSPL   16   // K-splits for xproj GEMM
#define NSEQ   4    // batch x branch scan sequences

typedef __bf16 bf16x8 __attribute__((ext_vector_type(8)));
typedef float  f32x4  __attribute__((ext_vector_type(4)));

__device__ __forceinline__ float silu_f(float x) {
    return x / (1.f + __expf(-x));
}
__device__ __forceinline__ float softplus_f(float x) {
    return (x > 20.f) ? x : __logf(1.f + __expf(x));
}
// round-to-nearest-even f32 -> bf16 (as ushort)
__device__ __forceinline__ unsigned short f2bf(float f) {
    unsigned int u = __float_as_uint(f);
    u = (u + 0x7FFFu + ((u >> 16) & 1u)) >> 16;
    return (unsigned short)u;
}
__device__ __forceinline__ float b2f(unsigned short u) {
    return __uint_as_float(((unsigned int)u) << 16);
}

__device__ __forceinline__ const __attribute__((address_space(1))) void* as1(const void* p) {
    return (const __attribute__((address_space(1))) void*)(uintptr_t)p;
}
__device__ __forceinline__ __attribute__((address_space(3))) void* as3(void* p) {
    return (__attribute__((address_space(3))) void*)(uintptr_t)p;
}

// ---------------------------------------------------------------------------
// f32 -> bf16 cast, vectorized. n must be a multiple of 1024.
// ---------------------------------------------------------------------------
__global__ __launch_bounds__(256) void cast_kernel(const float* __restrict__ in,
                                                   unsigned short* __restrict__ out,
                                                   int n) {
    int i = (blockIdx.x * 256 + threadIdx.x) * 4;
    if (i >= n) return;
    float4 v = *reinterpret_cast<const float4*>(in + i);
    ushort4 o;
    o.x = f2bf(v.x); o.y = f2bf(v.y); o.z = f2bf(v.z); o.w = f2bf(v.w);
    *reinterpret_cast<ushort4*>(out + i) = o;
}

// out_w [1024][2048] f32 -> out_wb2 [1024][4096] bf16 at column offset dstoff.
__global__ __launch_bounds__(256) void cast_cc(const float* __restrict__ in,
                                               unsigned short* __restrict__ out,
                                               int dstoff) {
    int i = (blockIdx.x * 256 + threadIdx.x) * 4;   // over 1024*2048
    int r = i >> 11, c = i & 2047;
    float4 v = *reinterpret_cast<const float4*>(in + i);
    ushort4 o;
    o.x = f2bf(v.x); o.y = f2bf(v.y); o.z = f2bf(v.z); o.w = f2bf(v.w);
    *reinterpret_cast<ushort4*>(out + (size_t)r * 4096 + dstoff + c) = o;
}

// xproj_w [96][2048] f32 -> [128][2048] bf16, rows 96..127 zeroed.
__global__ __launch_bounds__(256) void padcast_xproj(const float* __restrict__ in,
                                                     unsigned short* __restrict__ out) {
    int i = (blockIdx.x * 256 + threadIdx.x) * 4;   // over 128*2048
    int row = i >> 11;
    ushort4 o = make_ushort4(0, 0, 0, 0);
    if (row < 96) {
        float4 v = *reinterpret_cast<const float4*>(in + i);
        o.x = f2bf(v.x); o.y = f2bf(v.y); o.z = f2bf(v.z); o.w = f2bf(v.w);
    }
    *reinterpret_cast<ushort4*>(out + i) = o;
}

// ---------------------------------------------------------------------------
// LayerNorm: one block per token row (1024 elems), 256 threads. Writes bf16.
// ---------------------------------------------------------------------------
__global__ __launch_bounds__(256) void ln_kernel(const float* __restrict__ x,
                                                 const float* __restrict__ g,
                                                 const float* __restrict__ b,
                                                 unsigned short* __restrict__ xnb) {
    int row = blockIdx.x;
    const float* xr = x + (size_t)row * DM;
    float v[4];
    float s = 0.f, s2 = 0.f;
#pragma unroll
    for (int i = 0; i < 4; i++) {
        v[i] = xr[threadIdx.x + i * 256];
        s += v[i];
        s2 += v[i] * v[i];
    }
#pragma unroll
    for (int off = 32; off; off >>= 1) {
        s  += __shfl_down(s, off);
        s2 += __shfl_down(s2, off);
    }
    __shared__ float ss[4], ss2[4];
    int wid = threadIdx.x >> 6, lane = threadIdx.x & 63;
    if (lane == 0) { ss[wid] = s; ss2[wid] = s2; }
    __syncthreads();
    if (threadIdx.x == 0) {
        float a = 0.f, a2 = 0.f;
#pragma unroll
        for (int i = 0; i < 4; i++) { a += ss[i]; a2 += ss2[i]; }
        ss[0] = a; ss2[0] = a2;
    }
    __syncthreads();
    float m   = ss[0] * (1.f / DM);
    float var = ss2[0] * (1.f / DM) - m * m;
    float inv = rsqrtf(var + 1e-5f);
#pragma unroll
    for (int i = 0; i < 4; i++) {
        int c = threadIdx.x + i * 256;
        xnb[(size_t)row * DM + c] = f2bf((v[i] - m) * inv * g[c] + b[c]);
    }
}

// ---------------------------------------------------------------------------
// Unified bf16 MFMA NT GEMM, 128x128 tile, BK=32, 4 waves, double-buffered
// LDS (2-phase: stage k+1 before compute k, one barrier/iter).
// MODE 0: f32 store (+ blockIdx.z*zstride offset, for split-K)
// MODE 5: bf16 softplus(acc + bias[col])
// MODE 6: route columns to u2 (Cv) / z2 (Cv2): col -> [row][br*2048 + c&2047]
// ---------------------------------------------------------------------------
template <int MODE>
__global__ __launch_bounds__(256) void gemm_mfma(const unsigned short* __restrict__ A,
                                                 const unsigned short* __restrict__ W,
                                                 const float* __restrict__ bias,
                                                 void* __restrict__ Cv,
                                                 void* __restrict__ Cv2,
                                                 int ldc,
                                                 int Kst, int klen, size_t zstride) {
    __shared__ unsigned short As[2][128 * 32];
    __shared__ unsigned short Bs[2][128 * 32];

    int tid  = threadIdx.x;
    int lane = tid & 63;
    int w    = tid >> 6;
    int wr   = w >> 1;
    int wc   = w & 1;
    int m_blk = blockIdx.y * 128;
    int n_blk = blockIdx.x * 128;
    int kbeg  = blockIdx.z * klen;

    int srow = (2 * w) * 16 + (lane >> 2);
    int scol = (lane & 3) * 8;
    const unsigned short* Ag0 = A + (size_t)(m_blk + srow) * Kst + scol;
    const unsigned short* Ag1 = Ag0 + (size_t)16 * Kst;
    const unsigned short* Wg0 = W + (size_t)(n_blk + srow) * Kst + scol;
    const unsigned short* Wg1 = Wg0 + (size_t)16 * Kst;
    int d0 = (2 * w) * 512, d1 = (2 * w + 1) * 512;

    f32x4 acc[4][4] = {};

    auto STAGE = [&](int buf, int k0) {
        __builtin_amdgcn_global_load_lds(as1(Ag0 + k0), as3(&As[buf][d0]), 16, 0, 0);
        __builtin_amdgcn_global_load_lds(as1(Ag1 + k0), as3(&As[buf][d1]), 16, 0, 0);
        __builtin_amdgcn_global_load_lds(as1(Wg0 + k0), as3(&Bs[buf][d0]), 16, 0, 0);
        __builtin_amdgcn_global_load_lds(as1(Wg1 + k0), as3(&Bs[buf][d1]), 16, 0, 0);
    };
    auto COMPUTE = [&](int buf) {
        bf16x8 af[4], wf[4];
#pragma unroll
        for (int i = 0; i < 4; i++)
            af[i] = *reinterpret_cast<const bf16x8*>(
                &As[buf][(wr * 64 + i * 16 + (lane & 15)) * 32 + (lane >> 4) * 8]);
#pragma unroll
        for (int j = 0; j < 4; j++)
            wf[j] = *reinterpret_cast<const bf16x8*>(
                &Bs[buf][(wc * 64 + j * 16 + (lane & 15)) * 32 + (lane >> 4) * 8]);
#pragma unroll
        for (int i = 0; i < 4; i++)
#pragma unroll
            for (int j = 0; j < 4; j++)
                acc[i][j] = __builtin_amdgcn_mfma_f32_16x16x32_bf16(af[i], wf[j], acc[i][j], 0, 0, 0);
    };

    STAGE(0, kbeg);
    asm volatile("s_waitcnt vmcnt(0)" ::: "memory");
    __syncthreads();
    int cur = 0;
    for (int k0 = kbeg + 32; k0 < kbeg + klen; k0 += 32) {
        STAGE(cur ^ 1, k0);      // prefetch next tile (in flight during compute)
        COMPUTE(cur);
        asm volatile("s_waitcnt vmcnt(0)" ::: "memory");
        __syncthreads();
        cur ^= 1;
    }
    COMPUTE(cur);

    int colb = n_blk + wc * 64 + (lane & 15);
    int rowb = m_blk + wr * 64 + (lane >> 4) * 4;
#pragma unroll
    for (int i = 0; i < 4; i++) {
#pragma unroll
        for (int j = 0; j < 4; j++) {
            int col = colb + j * 16;
#pragma unroll
            for (int r = 0; r < 4; r++) {
                int row = rowb + i * 16 + r;
                float v = acc[i][j][r];
                if (MODE == 0) {
                    ((float*)Cv + blockIdx.z * zstride)[(size_t)row * ldc + col] = v;
                } else if (MODE == 5) {
                    ((unsigned short*)Cv)[(size_t)row * ldc + col] =
                        f2bf(softplus_f(v + bias[col]));
                } else { // MODE 6
                    int brn  = col >> 12;
                    int half = (col >> 11) & 1;
                    int cc   = col & 2047;
                    unsigned short* dst = half ? (unsigned short*)Cv2 : (unsigned short*)Cv;
                    dst[(size_t)row * 4096 + brn * 2048 + cc] = f2bf(v);
                }
            }
        }
    }
}

// Reduce xproj split-K partials -> dbc f32 [2048][96] and dbcb bf16 [2048][64].
__global__ __launch_bounds__(256) void reduce_dbc(const float* __restrict__ partial,
                                                  float* __restrict__ dbc,
                                                  unsigned short* __restrict__ dbcb) {
    int id = blockIdx.x * 256 + threadIdx.x;   // 0 .. 2048*96-1
    int r = id / 96;
    int j = id - r * 96;
    float s = 0.f;
#pragma unroll
    for (int k = 0; k < KSPL; k++)
        s += partial[(size_t)k * (BLROWS * 128) + (size_t)r * 128 + j];
    dbc[(size_t)r * 96 + j] = s;
    if (j < DTR) dbcb[(size_t)r * DTR + j] = f2bf(s);
}

// out = x + partial2[0] + partial2[1]   (2048*1024 f32)
__global__ __launch_bounds__(256) void reduce_out(const float* __restrict__ p,
                                                  const float* __restrict__ x,
                                                  float* __restrict__ out) {
    int i = (blockIdx.x * 256 + threadIdx.x) * 4;
    float4 a  = *reinterpret_cast<const float4*>(p + i);
    float4 b  = *reinterpret_cast<const float4*>(p + 2097152 + i);
    float4 xv = *reinterpret_cast<const float4*>(x + i);
    float4 o;
    o.x = xv.x + a.x + b.x; o.y = xv.y + a.y + b.y;
    o.z = xv.z + a.z + b.z; o.w = xv.w + a.w + b.w;
    *reinterpret_cast<float4*>(out + i) = o;
}

// ---------------------------------------------------------------------------
// Causal conv1d (k=4) + SiLU, both branches in one dispatch (blockIdx.y = br).
// u2 is [2048][4096] bf16 (branch col offset br*2048). Writes ucb2[br].
// ---------------------------------------------------------------------------
__global__ __launch_bounds__(256) void conv_silu2(const unsigned short* __restrict__ u2,
                                                  const float* __restrict__ cwf,
                                                  const float* __restrict__ cbf,
                                                  const float* __restrict__ cwb,
                                                  const float* __restrict__ cbb,
                                                  unsigned short* __restrict__ ucb2) {
    int br = blockIdx.y;
    const float* cw = br ? cwb : cwf;
    const float* cb = br ? cbb : cbf;
    int idx = blockIdx.x * 256 + threadIdx.x;       // over 2*1024*2048
    int c = idx & (DI - 1);
    int t = (idx >> 11) & (LSEQ - 1);
    int b = idx >> 21;
    float acc = cb[c];
#pragma unroll
    for (int k = 0; k < 4; k++) {
        int tt = br ? (t + 3 - k) : (t - 3 + k);
        if (tt >= 0 && tt < LSEQ)
            acc = fmaf(cw[c * 4 + k], b2f(u2[((size_t)(b * LSEQ + tt)) * 4096 + br * 2048 + c]), acc);
    }
    ucb2[(size_t)br * BLROWS * DI + idx] = f2bf(silu_f(acc));
}

// ---------------------------------------------------------------------------
// Chunked selective scan, 2 threads per channel (8 states each), both
// branches + batches in one dispatch: blockIdx.z = b*2 + br.
// ---------------------------------------------------------------------------
__global__ __launch_bounds__(256) void scan_p1(const unsigned short* __restrict__ dtvb2,
                                               const unsigned short* __restrict__ ucb2,
                                               const float* __restrict__ dbc2,
                                               const float* __restrict__ Alog_f,
                                               const float* __restrict__ Alog_b,
                                               float* __restrict__ hend,
                                               float* __restrict__ Pprod) {
    int chl = threadIdx.x >> 1;          // 0..127
    int sub = threadIdx.x & 1;
    int n0  = sub * 8;
    int c     = blockIdx.x * 128 + chl;
    int chunk = blockIdx.y;
    int z     = blockIdx.z;
    int br = z & 1, b = z >> 1;

    const unsigned short* dtv = dtvb2 + (size_t)br * BLROWS * DI;
    const unsigned short* uc  = ucb2  + (size_t)br * BLROWS * DI;
    const float* dbc   = dbc2 + (size_t)br * BLROWS * 96;
    const float* A_log = br ? Alog_b : Alog_f;

    __shared__ float Bs[CLEN][16];
    for (int i = threadIdx.x; i < CLEN * 16; i += 256) {
        int s = i >> 4, j = i & 15;
        int sigma = chunk * CLEN + s;
        int t = br ? (LSEQ - 1 - sigma) : sigma;
        Bs[s][j] = dbc[((size_t)b * LSEQ + t) * 96 + DTR + j];
    }
    __syncthreads();

    const float LOG2E = 1.4426950408889634f;
    float A2[8], h[8], P[8];
#pragma unroll
    for (int n = 0; n < 8; n++) {
        A2[n] = -__expf(A_log[c * DST + n0 + n]) * LOG2E;
        h[n] = 0.f;
        P[n] = 1.f;
    }

    int s0 = chunk * CLEN;
#pragma unroll 2
    for (int s = 0; s < CLEN; s++) {
        int sigma = s0 + s;
        int t = br ? (LSEQ - 1 - sigma) : sigma;
        size_t row = (size_t)b * LSEQ + t;
        float dt = b2f(dtv[row * DI + c]);
        float u  = b2f(uc[row * DI + c]);
        float du = dt * u;
        float Bv[8];
#pragma unroll
        for (int q = 0; q < 2; q++)
            reinterpret_cast<float4*>(Bv)[q] =
                *reinterpret_cast<const float4*>(&Bs[s][n0 + q * 4]);
#pragma unroll
        for (int n = 0; n < 8; n++) {
            float dA = exp2f(dt * A2[n]);
            h[n] = dA * h[n] + du * Bv[n];
            P[n] *= dA;
        }
    }
    size_t base = (((size_t)z * NCHUNK + chunk) * DI + c) * DST + n0;
#pragma unroll
    for (int q = 0; q < 2; q++) {
        *reinterpret_cast<float4*>(&hend[base + q * 4])  = reinterpret_cast<float4*>(h)[q];
        *reinterpret_cast<float4*>(&Pprod[base + q * 4]) = reinterpret_cast<float4*>(P)[q];
    }
}

// Combine: per (z,c,n), prefix over chunks. h0 ALIASES Pprod (read P first!).
__global__ __launch_bounds__(256) void scan_p2(const float* __restrict__ hend,
                                               float* __restrict__ P_h0) {
    int id = blockIdx.x * 256 + threadIdx.x;     // 0 .. NSEQ*DI*DST-1
    int cn = id & (DI * DST - 1);
    int z  = id >> 15;
    size_t base = (size_t)z * NCHUNK * DI * DST + cn;
    float h = 0.f;
    for (int k = 0; k < NCHUNK; k++) {
        size_t idx = base + (size_t)k * (DI * DST);
        float Pv = P_h0[idx];
        float hv = hend[idx];
        P_h0[idx] = h;
        h = Pv * h + hv;
    }
}

__global__ __launch_bounds__(256) void scan_p3(const unsigned short* __restrict__ dtvb2,
                                               const unsigned short* __restrict__ ucb2,
                                               const float* __restrict__ dbc2,
                                               const unsigned short* __restrict__ z2,
                                               const float* __restrict__ Alog_f,
                                               const float* __restrict__ Alog_b,
                                               const float* __restrict__ Dp_f,
                                               const float* __restrict__ Dp_b,
                                               const float* __restrict__ h0,
                                               unsigned short* __restrict__ G2) {
    int chl = threadIdx.x >> 1;
    int sub = threadIdx.x & 1;
    int n0  = sub * 8;
    int c     = blockIdx.x * 128 + chl;
    int chunk = blockIdx.y;
    int z     = blockIdx.z;
    int br = z & 1, b = z >> 1;

    const unsigned short* dtv = dtvb2 + (size_t)br * BLROWS * DI;
    const unsigned short* uc  = ucb2  + (size_t)br * BLROWS * DI;
    const float* dbc   = dbc2 + (size_t)br * BLROWS * 96;
    const float* A_log = br ? Alog_b : Alog_f;
    const float* Dp    = br ? Dp_b : Dp_f;

    __shared__ float BCs[CLEN][32];
    for (int i = threadIdx.x; i < CLEN * 32; i += 256) {
        int s = i >> 5, j = i & 31;
        int sigma = chunk * CLEN + s;
        int t = br ? (LSEQ - 1 - sigma) : sigma;
        BCs[s][j] = dbc[((size_t)b * LSEQ + t) * 96 + DTR + j];
    }
    __syncthreads();

    const float LOG2E = 1.4426950408889634f;
    float A2[8], h[8];
    size_t base = (((size_t)z * NCHUNK + chunk) * DI + c) * DST + n0;
#pragma unroll
    for (int n = 0; n < 8; n++) {
        A2[n] = -__expf(A_log[c * DST + n0 + n]) * LOG2E;
        h[n]  = h0[base + n];
    }
    float Dv = Dp[c];

    int s0 = chunk * CLEN;
#pragma unroll 2
    for (int s = 0; s < CLEN; s++) {
        int sigma = s0 + s;
        int t = br ? (LSEQ - 1 - sigma) : sigma;
        size_t row = (size_t)b * LSEQ + t;
        float dt = b2f(dtv[row * DI + c]);
        float u  = b2f(uc[row * DI + c]);
        float du = dt * u;
        float Bv[8], Cvv[8];
#pragma unroll
        for (int q = 0; q < 2; q++) {
            reinterpret_cast<float4*>(Bv)[q] =
                *reinterpret_cast<const float4*>(&BCs[s][n0 + q * 4]);
            reinterpret_cast<float4*>(Cvv)[q] =
                *reinterpret_cast<const float4*>(&BCs[s][16 + n0 + q * 4]);
        }
        float y = 0.f;
#pragma unroll
        for (int n = 0; n < 8; n++) {
            float dA = exp2f(dt * A2[n]);
            h[n] = dA * h[n] + du * Bv[n];
            y = fmaf(h[n], Cvv[n], y);
        }
        float yo = y + __shfl_xor(y, 1);
        if (sub == 0) {
            float yy = yo + u * Dv;
            float zg = b2f(z2[row * 4096 + br * 2048 + c]);
            G2[row * (2 * DI) + br * DI + c] = f2bf(yy * silu_f(zg));
        }
    }
}

// ---------------------------------------------------------------------------
extern "C" void kernel_launch(void* const* d_in, const int* in_sizes, int n_in,
                              void* d_out, int out_size, void* d_ws, size_t ws_size,
                              hipStream_t stream) {
    const float* x    = (const float*)d_in[0];
    const float* ln_g = (const float*)d_in[1];
    const float* ln_b = (const float*)d_in[2];
    float* out = (float*)d_out;

    char* wp = (char*)d_ws;
    // R0: xnb (4MB); after in-proj hosts dbc2 (1.5MB) + dbcb2 (0.5MB, AFTER dbc2!)
    unsigned short* xnb = (unsigned short*)wp;                 wp += (size_t)BLROWS * DM * 2;
    // R1: z2 [2048][4096] bf16 (z halves, live till p3)
    unsigned short* z2  = (unsigned short*)wp;                 wp += (size_t)BLROWS * 4096 * 2;
    // R2: u2 [2048][4096] bf16 (dead after conv) -> dtvb2 [2][2048][2048] bf16
    unsigned short* u2  = (unsigned short*)wp;                 wp += (size_t)BLROWS * 4096 * 2;
    // R3: in_wb2 [8192][1024] bf16 (16MB, dead after in-proj) -> partial (16MB)
    //     -> hend (16MB) -> (after p2) out_wb2 (8MB)
    unsigned short* in_wb2 = (unsigned short*)wp;              wp += (size_t)4 * DI * DM * 2;
    // R4: ucb2 [2][2048][2048] bf16
    unsigned short* ucb2 = (unsigned short*)wp;                wp += (size_t)2 * BLROWS * DI * 2;
    // R5: Pprod/h0 (16MB) -> (after p3) partial2 (16MB)
    float* Pprod = (float*)wp;                                 wp += (size_t)NSEQ * NCHUNK * DI * DST * 4;
    // R6: G2 [2048][4096] bf16
    unsigned short* G2 = (unsigned short*)wp;                  wp += (size_t)BLROWS * 2 * DI * 2;
    // R7: xprojb + dt_wb (per-branch reuse)
    unsigned short* xprojb = (unsigned short*)wp;              wp += (size_t)128 * DI * 2;
    unsigned short* dt_wb  = (unsigned short*)wp;              wp += (size_t)DI * DTR * 2;
    // total = 100.75 MB

    // aliases (disjoint lifetimes)
    float* dbc2           = (float*)xnb;                       // [2][2048][96] f32 = 1.5MB
    // FIX (round-7 NaN): dbcb2 must start AFTER the full 2-branch dbc2 region
    // (2*BLROWS*96*4 bytes = 2*BLROWS*96*2 ushorts), not after one branch.
    unsigned short* dbcb2 = xnb + (size_t)2 * BLROWS * 96 * 2; // [2][2048][64] bf16 = 0.5MB
    unsigned short* dtvb2 = u2;                                // R2
    float* partial        = (float*)in_wb2;                    // R3
    float* hend           = (float*)in_wb2;                    // R3
    unsigned short* out_wb2 = in_wb2;                          // R3 front 8MB, after p2
    float* h0             = Pprod;                             // R5 (p2 in-place)
    float* partial2       = Pprod;                             // R5, after p3

    // 1. LayerNorm -> xnb
    ln_kernel<<<BLROWS, 256, 0, stream>>>(x, ln_g, ln_b, xnb);

    // 2. cast both in_w into [8192][1024]
    cast_kernel<<<(2 * DI * DM) / 1024, 256, 0, stream>>>(
        (const float*)d_in[3], in_wb2, 2 * DI * DM);
    cast_kernel<<<(2 * DI * DM) / 1024, 256, 0, stream>>>(
        (const float*)d_in[12], in_wb2 + (size_t)2 * DI * DM, 2 * DI * DM);

    // 3. batched in-proj (2048 x 8192 x 1024) -> u2 / z2 (bf16, routed)
    gemm_mfma<6><<<dim3(4 * DI / 128, BLROWS / 128, 1), 256, 0, stream>>>(
        xnb, in_wb2, nullptr, u2, z2, 4096, DM, DM, 0);

    // 4. conv + SiLU, both branches -> ucb2
    conv_silu2<<<dim3((BLROWS * DI) / 256, 2), 256, 0, stream>>>(
        u2, (const float*)d_in[4], (const float*)d_in[5],
        (const float*)d_in[13], (const float*)d_in[14], ucb2);

    // 5/6. per-branch xproj (split-K) + reduce, dt GEMM
    for (int br = 0; br < 2; br++) {
        const float* xproj_w = (const float*)d_in[3 + 9 * br + 3];
        const float* dt_w    = (const float*)d_in[3 + 9 * br + 4];
        const float* dt_b    = (const float*)d_in[3 + 9 * br + 5];

        padcast_xproj<<<(128 * DI) / 1024, 256, 0, stream>>>(xproj_w, xprojb);
        gemm_mfma<0><<<dim3(1, BLROWS / 128, KSPL), 256, 0, stream>>>(
            ucb2 + (size_t)br * BLROWS * DI, xprojb, nullptr, partial, nullptr,
            128, DI, DI / KSPL, (size_t)BLROWS * 128);
        reduce_dbc<<<(BLROWS * 96) / 256, 256, 0, stream>>>(
            partial, dbc2 + (size_t)br * BLROWS * 96,
            dbcb2 + (size_t)br * BLROWS * DTR);

        cast_kernel<<<(DI * DTR) / 1024, 256, 0, stream>>>(dt_w, dt_wb, DI * DTR);
        gemm_mfma<5><<<dim3(DI / 128, BLROWS / 128, 1), 256, 0, stream>>>(
            dbcb2 + (size_t)br * BLROWS * DTR, dt_wb, dt_b,
            dtvb2 + (size_t)br * BLROWS * DI, nullptr, DI, DTR, DTR, 0);
    }

    // 7-8. combined scans (both batches x branches in one dispatch)
    scan_p1<<<dim3(DI / 128, NCHUNK, NSEQ), 256, 0, stream>>>(
        dtvb2, ucb2, dbc2, (const float*)d_in[9], (const float*)d_in[18],
        hend, Pprod);
    scan_p2<<<(NSEQ * DI * DST) / 256, 256, 0, stream>>>(hend, Pprod);

    // 9. cast out_w (R3, after p2 freed hend)
    cast_cc<<<(DM * DI) / 1024, 256, 0, stream>>>((const float*)d_in[11], out_wb2, 0);
    cast_cc<<<(DM * DI) / 1024, 256, 0, stream>>>((const float*)d_in[20], out_wb2, DI);

    // 10. scan p3 -> G2
    scan_p3<<<dim3(DI / 128, NCHUNK, NSEQ), 256, 0, stream>>>(
        dtvb2, ucb2, dbc2, z2, (const float*)d_in[9], (const float*)d_in[18],
        (const float*)d_in[10], (const float*)d_in[19], h0, G2);

    // 11-12. combined out-proj (K=4096, split-K 2) + reduce with residual
    gemm_mfma<0><<<dim3(DM / 128, BLROWS / 128, 2), 256, 0, stream>>>(
        G2, out_wb2, nullptr, partial2, nullptr, DM, 2 * DI, DI, (size_t)BLROWS * DM);
    reduce_out<<<(BLROWS * DM) / 1024, 256, 0, stream>>>(partial2, x, out);
}

// Round 9
// 303.126 us; speedup vs baseline: 9.0292x; 1.0589x over previous
//
#include <hip/hip_runtime.h>
#include <math.h>

#define DM   1024   // d_model
#define DI   2048   // d_inner
#define DST  16     // d_state
#define DTR  64     // dt_rank
#define LSEQ 1024   // L
#define NBAT 2      // B
#define BLROWS (NBAT*LSEQ)   // 2048 token rows
#define NCHUNK 32
#define CLEN   32   // LSEQ / NCHUNK
#define KSPL   8    // K-splits for xproj GEMM (both branches combined)
#define NSEQ   4    // batch x branch scan sequences

typedef __bf16 bf16x8 __attribute__((ext_vector_type(8)));
typedef float  f32x4  __attribute__((ext_vector_type(4)));

__device__ __forceinline__ float silu_f(float x) {
    return x / (1.f + __expf(-x));
}
__device__ __forceinline__ float softplus_f(float x) {
    return (x > 20.f) ? x : __logf(1.f + __expf(x));
}
// round-to-nearest-even f32 -> bf16 (as ushort)
__device__ __forceinline__ unsigned short f2bf(float f) {
    unsigned int u = __float_as_uint(f);
    u = (u + 0x7FFFu + ((u >> 16) & 1u)) >> 16;
    return (unsigned short)u;
}
__device__ __forceinline__ float b2f(unsigned short u) {
    return __uint_as_float(((unsigned int)u) << 16);
}

__device__ __forceinline__ const __attribute__((address_space(1))) void* as1(const void* p) {
    return (const __attribute__((address_space(1))) void*)(uintptr_t)p;
}
__device__ __forceinline__ __attribute__((address_space(3))) void* as3(void* p) {
    return (__attribute__((address_space(3))) void*)(uintptr_t)p;
}

// ---------------------------------------------------------------------------
// f32 -> bf16 cast, vectorized. n must be a multiple of 1024.
// ---------------------------------------------------------------------------
__global__ __launch_bounds__(256) void cast_kernel(const float* __restrict__ in,
                                                   unsigned short* __restrict__ out,
                                                   int n) {
    int i = (blockIdx.x * 256 + threadIdx.x) * 4;
    if (i >= n) return;
    float4 v = *reinterpret_cast<const float4*>(in + i);
    ushort4 o;
    o.x = f2bf(v.x); o.y = f2bf(v.y); o.z = f2bf(v.z); o.w = f2bf(v.w);
    *reinterpret_cast<ushort4*>(out + i) = o;
}

// out_w [1024][2048] f32 -> out_wb2 [1024][4096] bf16 at column offset dstoff.
__global__ __launch_bounds__(256) void cast_cc(const float* __restrict__ in,
                                               unsigned short* __restrict__ out,
                                               int dstoff) {
    int i = (blockIdx.x * 256 + threadIdx.x) * 4;   // over 1024*2048
    int r = i >> 11, c = i & 2047;
    float4 v = *reinterpret_cast<const float4*>(in + i);
    ushort4 o;
    o.x = f2bf(v.x); o.y = f2bf(v.y); o.z = f2bf(v.z); o.w = f2bf(v.w);
    *reinterpret_cast<ushort4*>(out + (size_t)r * 4096 + dstoff + c) = o;
}

// xproj_w [96][2048] f32 -> [2][128][2048] bf16, rows 96..127 zeroed. grid.y=br
__global__ __launch_bounds__(256) void padcast_xproj2(const float* __restrict__ inF,
                                                      const float* __restrict__ inB,
                                                      unsigned short* __restrict__ out) {
    int br = blockIdx.y;
    const float* in = br ? inB : inF;
    int i = (blockIdx.x * 256 + threadIdx.x) * 4;   // over 128*2048
    int row = i >> 11;
    ushort4 o = make_ushort4(0, 0, 0, 0);
    if (row < 96) {
        float4 v = *reinterpret_cast<const float4*>(in + i);
        o.x = f2bf(v.x); o.y = f2bf(v.y); o.z = f2bf(v.z); o.w = f2bf(v.w);
    }
    *reinterpret_cast<ushort4*>(out + (size_t)br * 128 * DI + i) = o;
}

// ---------------------------------------------------------------------------
// LayerNorm: one block per token row (1024 elems), 256 threads. Writes bf16.
// ---------------------------------------------------------------------------
__global__ __launch_bounds__(256) void ln_kernel(const float* __restrict__ x,
                                                 const float* __restrict__ g,
                                                 const float* __restrict__ b,
                                                 unsigned short* __restrict__ xnb) {
    int row = blockIdx.x;
    const float* xr = x + (size_t)row * DM;
    float v[4];
    float s = 0.f, s2 = 0.f;
#pragma unroll
    for (int i = 0; i < 4; i++) {
        v[i] = xr[threadIdx.x + i * 256];
        s += v[i];
        s2 += v[i] * v[i];
    }
#pragma unroll
    for (int off = 32; off; off >>= 1) {
        s  += __shfl_down(s, off);
        s2 += __shfl_down(s2, off);
    }
    __shared__ float ss[4], ss2[4];
    int wid = threadIdx.x >> 6, lane = threadIdx.x & 63;
    if (lane == 0) { ss[wid] = s; ss2[wid] = s2; }
    __syncthreads();
    if (threadIdx.x == 0) {
        float a = 0.f, a2 = 0.f;
#pragma unroll
        for (int i = 0; i < 4; i++) { a += ss[i]; a2 += ss2[i]; }
        ss[0] = a; ss2[0] = a2;
    }
    __syncthreads();
    float m   = ss[0] * (1.f / DM);
    float var = ss2[0] * (1.f / DM) - m * m;
    float inv = rsqrtf(var + 1e-5f);
#pragma unroll
    for (int i = 0; i < 4; i++) {
        int c = threadIdx.x + i * 256;
        xnb[(size_t)row * DM + c] = f2bf((v[i] - m) * inv * g[c] + b[c]);
    }
}

// ---------------------------------------------------------------------------
// Unified bf16 MFMA NT GEMM, 128x128 tile, BK=32, 4 waves, double-buffered.
// MODE 0: f32 store + blockIdx.z*zstride (split-K, single W)
// MODE 6: in-proj routing to u2 (Cv) / z2 (Cv2)
// MODE 7: dt GEMM, M=4096 (2 branches): W/bias selected by row>>11; packs
//         (u16<<16)|softplus16 into dtu0/dtu1 u32 arrays
// MODE 8: split-K f32 store with per-branch W select (xproj, M=4096)
// ---------------------------------------------------------------------------
template <int MODE>
__global__ __launch_bounds__(256) void gemm_mfma(const unsigned short* __restrict__ A,
                                                 const unsigned short* __restrict__ W,
                                                 const float* __restrict__ bias,
                                                 const float* __restrict__ biasB,
                                                 const unsigned short* __restrict__ upack,
                                                 void* __restrict__ Cv,
                                                 void* __restrict__ Cv2,
                                                 int ldc,
                                                 int Kst, int klen, size_t zstride,
                                                 int wbrstride) {
    __shared__ unsigned short As[2][128 * 32];
    __shared__ unsigned short Bs[2][128 * 32];

    int tid  = threadIdx.x;
    int lane = tid & 63;
    int w    = tid >> 6;
    int wr   = w >> 1;
    int wc   = w & 1;
    int m_blk = blockIdx.y * 128;
    int n_blk = blockIdx.x * 128;
    int kbeg  = blockIdx.z * klen;

    if (MODE == 7 || MODE == 8) W += (size_t)(m_blk >> 11) * wbrstride;

    int srow = (2 * w) * 16 + (lane >> 2);
    int scol = (lane & 3) * 8;
    const unsigned short* Ag0 = A + (size_t)(m_blk + srow) * Kst + scol;
    const unsigned short* Ag1 = Ag0 + (size_t)16 * Kst;
    const unsigned short* Wg0 = W + (size_t)(n_blk + srow) * Kst + scol;
    const unsigned short* Wg1 = Wg0 + (size_t)16 * Kst;
    int d0 = (2 * w) * 512, d1 = (2 * w + 1) * 512;

    f32x4 acc[4][4] = {};

    auto STAGE = [&](int buf, int k0) {
        __builtin_amdgcn_global_load_lds(as1(Ag0 + k0), as3(&As[buf][d0]), 16, 0, 0);
        __builtin_amdgcn_global_load_lds(as1(Ag1 + k0), as3(&As[buf][d1]), 16, 0, 0);
        __builtin_amdgcn_global_load_lds(as1(Wg0 + k0), as3(&Bs[buf][d0]), 16, 0, 0);
        __builtin_amdgcn_global_load_lds(as1(Wg1 + k0), as3(&Bs[buf][d1]), 16, 0, 0);
    };
    auto COMPUTE = [&](int buf) {
        bf16x8 af[4], wf[4];
#pragma unroll
        for (int i = 0; i < 4; i++)
            af[i] = *reinterpret_cast<const bf16x8*>(
                &As[buf][(wr * 64 + i * 16 + (lane & 15)) * 32 + (lane >> 4) * 8]);
#pragma unroll
        for (int j = 0; j < 4; j++)
            wf[j] = *reinterpret_cast<const bf16x8*>(
                &Bs[buf][(wc * 64 + j * 16 + (lane & 15)) * 32 + (lane >> 4) * 8]);
#pragma unroll
        for (int i = 0; i < 4; i++)
#pragma unroll
            for (int j = 0; j < 4; j++)
                acc[i][j] = __builtin_amdgcn_mfma_f32_16x16x32_bf16(af[i], wf[j], acc[i][j], 0, 0, 0);
    };

    STAGE(0, kbeg);
    asm volatile("s_waitcnt vmcnt(0)" ::: "memory");
    __syncthreads();
    int cur = 0;
    for (int k0 = kbeg + 32; k0 < kbeg + klen; k0 += 32) {
        STAGE(cur ^ 1, k0);
        COMPUTE(cur);
        asm volatile("s_waitcnt vmcnt(0)" ::: "memory");
        __syncthreads();
        cur ^= 1;
    }
    COMPUTE(cur);

    int colb = n_blk + wc * 64 + (lane & 15);
    int rowb = m_blk + wr * 64 + (lane >> 4) * 4;
#pragma unroll
    for (int i = 0; i < 4; i++) {
#pragma unroll
        for (int j = 0; j < 4; j++) {
            int col = colb + j * 16;
#pragma unroll
            for (int r = 0; r < 4; r++) {
                int row = rowb + i * 16 + r;
                float v = acc[i][j][r];
                if (MODE == 0 || MODE == 8) {
                    ((float*)Cv + blockIdx.z * zstride)[(size_t)row * ldc + col] = v;
                } else if (MODE == 6) {
                    int brn  = col >> 12;
                    int half = (col >> 11) & 1;
                    int cc   = col & 2047;
                    unsigned short* dst = half ? (unsigned short*)Cv2 : (unsigned short*)Cv;
                    dst[(size_t)row * 4096 + brn * 2048 + cc] = f2bf(v);
                } else { // MODE 7
                    const float* bs = (row >> 11) ? biasB : bias;
                    unsigned short u16 = upack[(size_t)row * DI + col];
                    unsigned int pk = ((unsigned int)u16 << 16) |
                                      (unsigned int)f2bf(softplus_f(v + bs[col]));
                    unsigned int* dst = (row >> 11) ? (unsigned int*)Cv2 : (unsigned int*)Cv;
                    dst[(size_t)(row & 2047) * DI + col] = pk;
                }
            }
        }
    }
}

// Reduce xproj split-K partials (both branches, M=4096) ->
// dbc2 f32 [2][2048][96] and dbcb2 bf16 [2][2048][64].
__global__ __launch_bounds__(256) void reduce_dbc(const float* __restrict__ partial,
                                                  float* __restrict__ dbc2,
                                                  unsigned short* __restrict__ dbcb2) {
    int id = blockIdx.x * 256 + threadIdx.x;   // 0 .. 4096*96-1
    int r = id / 96;                           // 0..4095 (br*2048 + row)
    int j = id - r * 96;
    float s = 0.f;
#pragma unroll
    for (int k = 0; k < KSPL; k++)
        s += partial[(size_t)k * (4096 * 128) + (size_t)r * 128 + j];
    dbc2[(size_t)r * 96 + j] = s;
    if (j < DTR) dbcb2[(size_t)r * DTR + j] = f2bf(s);
}

// out = x + partial2[0] + partial2[1]   (2048*1024 f32)
__global__ __launch_bounds__(256) void reduce_out(const float* __restrict__ p,
                                                  const float* __restrict__ x,
                                                  float* __restrict__ out) {
    int i = (blockIdx.x * 256 + threadIdx.x) * 4;
    float4 a  = *reinterpret_cast<const float4*>(p + i);
    float4 b  = *reinterpret_cast<const float4*>(p + 2097152 + i);
    float4 xv = *reinterpret_cast<const float4*>(x + i);
    float4 o;
    o.x = xv.x + a.x + b.x; o.y = xv.y + a.y + b.y;
    o.z = xv.z + a.z + b.z; o.w = xv.w + a.w + b.w;
    *reinterpret_cast<float4*>(out + i) = o;
}

// ---------------------------------------------------------------------------
// Causal conv1d (k=4) + SiLU, both branches in one dispatch (blockIdx.y = br).
// ---------------------------------------------------------------------------
__global__ __launch_bounds__(256) void conv_silu2(const unsigned short* __restrict__ u2,
                                                  const float* __restrict__ cwf,
                                                  const float* __restrict__ cbf,
                                                  const float* __restrict__ cwb,
                                                  const float* __restrict__ cbb,
                                                  unsigned short* __restrict__ ucb2) {
    int br = blockIdx.y;
    const float* cw = br ? cwb : cwf;
    const float* cb = br ? cbb : cbf;
    int idx = blockIdx.x * 256 + threadIdx.x;       // over 2*1024*2048
    int c = idx & (DI - 1);
    int t = (idx >> 11) & (LSEQ - 1);
    int b = idx >> 21;
    float acc = cb[c];
#pragma unroll
    for (int k = 0; k < 4; k++) {
        int tt = br ? (t + 3 - k) : (t - 3 + k);
        if (tt >= 0 && tt < LSEQ)
            acc = fmaf(cw[c * 4 + k], b2f(u2[((size_t)(b * LSEQ + tt)) * 4096 + br * 2048 + c]), acc);
    }
    ucb2[(size_t)br * BLROWS * DI + idx] = f2bf(silu_f(acc));
}

// ---------------------------------------------------------------------------
// Chunked selective scan, 2 threads per channel (8 states each).
// dtu = packed (u16<<16)|dt16 per (row, c). blockIdx.z = b*2 + br.
// p1: local scan, writes hend + per-chunk dt-sum (P reconstructed in p2).
// ---------------------------------------------------------------------------
__global__ __launch_bounds__(256) void scan_p1(const unsigned int* __restrict__ dtu0,
                                               const unsigned int* __restrict__ dtu1,
                                               const float* __restrict__ dbc2,
                                               const float* __restrict__ Alog_f,
                                               const float* __restrict__ Alog_b,
                                               float* __restrict__ hend,
                                               float* __restrict__ dtsum) {
    int chl = threadIdx.x >> 1;          // 0..127
    int sub = threadIdx.x & 1;
    int n0  = sub * 8;
    int c     = blockIdx.x * 128 + chl;
    int chunk = blockIdx.y;
    int z     = blockIdx.z;
    int br = z & 1, b = z >> 1;

    const unsigned int* dtu = br ? dtu1 : dtu0;
    const float* dbc   = dbc2 + (size_t)br * BLROWS * 96;
    const float* A_log = br ? Alog_b : Alog_f;

    __shared__ float Bs[CLEN][16];
    for (int i = threadIdx.x; i < CLEN * 16; i += 256) {
        int s = i >> 4, j = i & 15;
        int sigma = chunk * CLEN + s;
        int t = br ? (LSEQ - 1 - sigma) : sigma;
        Bs[s][j] = dbc[((size_t)b * LSEQ + t) * 96 + DTR + j];
    }
    __syncthreads();

    const float LOG2E = 1.4426950408889634f;
    float A2[8], h[8];
#pragma unroll
    for (int n = 0; n < 8; n++) {
        A2[n] = -__expf(A_log[c * DST + n0 + n]) * LOG2E;
        h[n] = 0.f;
    }
    float dts = 0.f;

    int s0 = chunk * CLEN;
#pragma unroll 4
    for (int s = 0; s < CLEN; s++) {
        int sigma = s0 + s;
        int t = br ? (LSEQ - 1 - sigma) : sigma;
        size_t row = (size_t)b * LSEQ + t;
        unsigned int pk = dtu[row * DI + c];
        float dt = __uint_as_float(pk << 16);
        float u  = __uint_as_float(pk & 0xFFFF0000u);
        float du = dt * u;
        dts += dt;
        float Bv[8];
#pragma unroll
        for (int q = 0; q < 2; q++)
            reinterpret_cast<float4*>(Bv)[q] =
                *reinterpret_cast<const float4*>(&Bs[s][n0 + q * 4]);
#pragma unroll
        for (int n = 0; n < 8; n++) {
            float dA = exp2f(dt * A2[n]);
            h[n] = dA * h[n] + du * Bv[n];
        }
    }
    size_t base = (((size_t)z * NCHUNK + chunk) * DI + c) * DST + n0;
#pragma unroll
    for (int q = 0; q < 2; q++)
        *reinterpret_cast<float4*>(&hend[base + q * 4]) = reinterpret_cast<float4*>(h)[q];
    if (sub == 0)
        dtsum[((size_t)z * NCHUNK + chunk) * DI + c] = dts;
}

// Combine: per (z,c,n), prefix over chunks. P = exp2(dtsum * A2). Writes h0.
__global__ __launch_bounds__(256) void scan_p2(const float* __restrict__ hend,
                                               const float* __restrict__ dtsum,
                                               const float* __restrict__ Alog_f,
                                               const float* __restrict__ Alog_b,
                                               float* __restrict__ h0) {
    int id = blockIdx.x * 256 + threadIdx.x;     // 0 .. NSEQ*DI*DST-1
    int n  = id & (DST - 1);
    int c  = (id >> 4) & (DI - 1);
    int z  = id >> 15;
    int br = z & 1;
    const float* A_log = br ? Alog_b : Alog_f;
    const float LOG2E = 1.4426950408889634f;
    float A2 = -__expf(A_log[c * DST + n]) * LOG2E;

    float h = 0.f;
    for (int k = 0; k < NCHUNK; k++) {
        size_t idx = (((size_t)z * NCHUNK + k) * DI + c) * DST + n;
        float P = exp2f(dtsum[((size_t)z * NCHUNK + k) * DI + c] * A2);
        h0[idx] = h;
        h = P * h + hend[idx];
    }
}

__global__ __launch_bounds__(256) void scan_p3(const unsigned int* __restrict__ dtu0,
                                               const unsigned int* __restrict__ dtu1,
                                               const float* __restrict__ dbc2,
                                               const unsigned short* __restrict__ z2,
                                               const float* __restrict__ Alog_f,
                                               const float* __restrict__ Alog_b,
                                               const float* __restrict__ Dp_f,
                                               const float* __restrict__ Dp_b,
                                               const float* __restrict__ h0,
                                               unsigned short* __restrict__ G2) {
    int chl = threadIdx.x >> 1;
    int sub = threadIdx.x & 1;
    int n0  = sub * 8;
    int c     = blockIdx.x * 128 + chl;
    int chunk = blockIdx.y;
    int z     = blockIdx.z;
    int br = z & 1, b = z >> 1;

    const unsigned int* dtu = br ? dtu1 : dtu0;
    const float* dbc   = dbc2 + (size_t)br * BLROWS * 96;
    const float* A_log = br ? Alog_b : Alog_f;
    const float* Dp    = br ? Dp_b : Dp_f;

    __shared__ float BCs[CLEN][32];
    for (int i = threadIdx.x; i < CLEN * 32; i += 256) {
        int s = i >> 5, j = i & 31;
        int sigma = chunk * CLEN + s;
        int t = br ? (LSEQ - 1 - sigma) : sigma;
        BCs[s][j] = dbc[((size_t)b * LSEQ + t) * 96 + DTR + j];
    }
    __syncthreads();

    const float LOG2E = 1.4426950408889634f;
    float A2[8], h[8];
    size_t base = (((size_t)z * NCHUNK + chunk) * DI + c) * DST + n0;
#pragma unroll
    for (int n = 0; n < 8; n++) {
        A2[n] = -__expf(A_log[c * DST + n0 + n]) * LOG2E;
        h[n]  = h0[base + n];
    }
    float Dv = Dp[c];

    int s0 = chunk * CLEN;
#pragma unroll 4
    for (int s = 0; s < CLEN; s++) {
        int sigma = s0 + s;
        int t = br ? (LSEQ - 1 - sigma) : sigma;
        size_t row = (size_t)b * LSEQ + t;
        unsigned int pk = dtu[row * DI + c];
        float dt = __uint_as_float(pk << 16);
        float u  = __uint_as_float(pk & 0xFFFF0000u);
        float du = dt * u;
        float Bv[8], Cvv[8];
#pragma unroll
        for (int q = 0; q < 2; q++) {
            reinterpret_cast<float4*>(Bv)[q] =
                *reinterpret_cast<const float4*>(&BCs[s][n0 + q * 4]);
            reinterpret_cast<float4*>(Cvv)[q] =
                *reinterpret_cast<const float4*>(&BCs[s][16 + n0 + q * 4]);
        }
        float y = 0.f;
#pragma unroll
        for (int n = 0; n < 8; n++) {
            float dA = exp2f(dt * A2[n]);
            h[n] = dA * h[n] + du * Bv[n];
            y = fmaf(h[n], Cvv[n], y);
        }
        float yo = y + __shfl_xor(y, 1);
        if (sub == 0) {
            float yy = yo + u * Dv;
            float zg = b2f(z2[row * 4096 + br * 2048 + c]);
            G2[row * (2 * DI) + br * DI + c] = f2bf(yy * silu_f(zg));
        }
    }
}

// ---------------------------------------------------------------------------
extern "C" void kernel_launch(void* const* d_in, const int* in_sizes, int n_in,
                              void* d_out, int out_size, void* d_ws, size_t ws_size,
                              hipStream_t stream) {
    const float* x    = (const float*)d_in[0];
    const float* ln_g = (const float*)d_in[1];
    const float* ln_b = (const float*)d_in[2];
    float* out = (float*)d_out;

    char* wp = (char*)d_ws;
    // R0 (4MB): xnb; after in-proj: dbc2 (1.5MB) + dbcb2 (0.5MB) + dtsum (1MB)
    unsigned short* xnb = (unsigned short*)wp;                 wp += (size_t)BLROWS * DM * 2;
    // R1 (16MB): z2 [2048][4096] bf16, live till p3
    unsigned short* z2  = (unsigned short*)wp;                 wp += (size_t)BLROWS * 4096 * 2;
    // R2 (16MB): u2 (dead after conv) -> dtu0 [2048][2048] u32
    unsigned short* u2  = (unsigned short*)wp;                 wp += (size_t)BLROWS * 4096 * 2;
    // R3 (16MB): in_wb2 -> partial(xproj) -> dtu1 [2048][2048] u32
    unsigned short* in_wb2 = (unsigned short*)wp;              wp += (size_t)4 * DI * DM * 2;
    // R4 (16MB): ucb2 [2][2048][2048] bf16 (dead after dt GEMM) -> hend (16MB)
    //            -> after p2: front 8MB = out_wb2
    unsigned short* ucb2 = (unsigned short*)wp;                wp += (size_t)2 * BLROWS * DI * 2;
    // R5 (16MB): h0 [NSEQ][NCHUNK][DI][DST] f32 -> after p3: partial2
    float* h0r = (float*)wp;                                   wp += (size_t)NSEQ * NCHUNK * DI * DST * 4;
    // R6 (16MB): G2 [2048][4096] bf16
    unsigned short* G2 = (unsigned short*)wp;                  wp += (size_t)BLROWS * 2 * DI * 2;
    // R7: xprojb2 [2][128][2048] bf16 (1MB) + dt_wb2 [2][2048][64] bf16 (0.5MB)
    unsigned short* xprojb2 = (unsigned short*)wp;             wp += (size_t)2 * 128 * DI * 2;
    unsigned short* dt_wb2  = (unsigned short*)wp;             wp += (size_t)2 * DI * DTR * 2;
    // total = 101.5 MB

    // aliases (lifetime-audited)
    float* dbc2           = (float*)xnb;                           // [2][2048][96] f32
    unsigned short* dbcb2 = xnb + (size_t)2 * BLROWS * 96 * 2;     // [2][2048][64] bf16 (after full dbc2)
    float* dtsum          = (float*)((char*)xnb + 2097152);        // [NSEQ][NCHUNK][DI] f32, 1MB
    unsigned int* dtu0    = (unsigned int*)u2;                     // R2
    float* partial        = (float*)in_wb2;                        // R3 (xproj split-K)
    unsigned int* dtu1    = (unsigned int*)in_wb2;                 // R3 (after reduce_dbc)
    float* hend           = (float*)ucb2;                          // R4 (after dt GEMM)
    unsigned short* out_wb2 = ucb2;                                // R4 front 8MB (after p2)
    float* h0             = h0r;                                   // R5
    float* partial2       = h0r;                                   // R5 (after p3)

    // 1. LayerNorm -> xnb
    ln_kernel<<<BLROWS, 256, 0, stream>>>(x, ln_g, ln_b, xnb);

    // 2. cast both in_w into [8192][1024]
    cast_kernel<<<(2 * DI * DM) / 1024, 256, 0, stream>>>(
        (const float*)d_in[3], in_wb2, 2 * DI * DM);
    cast_kernel<<<(2 * DI * DM) / 1024, 256, 0, stream>>>(
        (const float*)d_in[12], in_wb2 + (size_t)2 * DI * DM, 2 * DI * DM);

    // 3. batched in-proj (2048 x 8192 x 1024) -> u2 / z2 (bf16, routed)
    gemm_mfma<6><<<dim3(4 * DI / 128, BLROWS / 128, 1), 256, 0, stream>>>(
        xnb, in_wb2, nullptr, nullptr, nullptr, u2, z2, 4096, DM, DM, 0, 0);

    // 4. conv + SiLU, both branches -> ucb2
    conv_silu2<<<dim3((BLROWS * DI) / 256, 2), 256, 0, stream>>>(
        u2, (const float*)d_in[4], (const float*)d_in[5],
        (const float*)d_in[13], (const float*)d_in[14], ucb2);

    // 5. weight prep (both branches, batched)
    padcast_xproj2<<<dim3((128 * DI) / 1024, 2), 256, 0, stream>>>(
        (const float*)d_in[6], (const float*)d_in[15], xprojb2);
    cast_kernel<<<(DI * DTR) / 1024, 256, 0, stream>>>(
        (const float*)d_in[7], dt_wb2, DI * DTR);
    cast_kernel<<<(DI * DTR) / 1024, 256, 0, stream>>>(
        (const float*)d_in[16], dt_wb2 + (size_t)DI * DTR, DI * DTR);

    // 6. xproj both branches: M=4096, split-K 8 -> partial (R3)
    gemm_mfma<8><<<dim3(1, 4096 / 128, KSPL), 256, 0, stream>>>(
        ucb2, xprojb2, nullptr, nullptr, nullptr, partial, nullptr,
        128, DI, DI / KSPL, (size_t)4096 * 128, 128 * DI);
    reduce_dbc<<<(4096 * 96) / 256, 256, 0, stream>>>(partial, dbc2, dbcb2);

    // 7. dt GEMM both branches (M=4096), packed epilogue -> dtu0/dtu1
    gemm_mfma<7><<<dim3(DI / 128, 4096 / 128, 1), 256, 0, stream>>>(
        dbcb2, dt_wb2, (const float*)d_in[8], (const float*)d_in[17], ucb2,
        dtu0, dtu1, DI, DTR, DTR, 0, DI * DTR);

    // 8. scan phase 1 + combine
    scan_p1<<<dim3(DI / 128, NCHUNK, NSEQ), 256, 0, stream>>>(
        dtu0, dtu1, dbc2, (const float*)d_in[9], (const float*)d_in[18],
        hend, dtsum);
    scan_p2<<<(NSEQ * DI * DST) / 256, 256, 0, stream>>>(
        hend, dtsum, (const float*)d_in[9], (const float*)d_in[18], h0);

    // 9. cast out_w into R4 front (hend dead after p2)
    cast_cc<<<(DM * DI) / 1024, 256, 0, stream>>>((const float*)d_in[11], out_wb2, 0);
    cast_cc<<<(DM * DI) / 1024, 256, 0, stream>>>((const float*)d_in[20], out_wb2, DI);

    // 10. scan phase 3 -> G2
    scan_p3<<<dim3(DI / 128, NCHUNK, NSEQ), 256, 0, stream>>>(
        dtu0, dtu1, dbc2, z2, (const float*)d_in[9], (const float*)d_in[18],
        (const float*)d_in[10], (const float*)d_in[19], h0, G2);

    // 11. combined out-proj (K=4096, split-K 2) + reduce with residual
    gemm_mfma<0><<<dim3(DM / 128, BLROWS / 128, 2), 256, 0, stream>>>(
        G2, out_wb2, nullptr, nullptr, nullptr, partial2, nullptr,
        DM, 2 * DI, DI, (size_t)BLROWS * DM, 0);
    reduce_out<<<(BLROWS * DM) / 1024, 256, 0, stream>>>(partial2, x, out);
}

// Round 10
// 291.231 us; speedup vs baseline: 9.3980x; 1.0408x over previous
//
#include <hip/hip_runtime.h>
#include <math.h>

#define DM   1024   // d_model
#define DI   2048   // d_inner
#define DST  16     // d_state
#define DTR  64     // dt_rank
#define LSEQ 1024   // L
#define NBAT 2      // B
#define BLROWS (NBAT*LSEQ)   // 2048 token rows
#define NCHUNK 32
#define CLEN   32   // LSEQ / NCHUNK
#define KSPL   8    // K-splits for xproj GEMM (both branches combined)
#define NSEQ   4    // batch x branch scan sequences

typedef __bf16 bf16x8 __attribute__((ext_vector_type(8)));
typedef float  f32x4  __attribute__((ext_vector_type(4)));

__device__ __forceinline__ float silu_f(float x) {
    return x / (1.f + __expf(-x));
}
__device__ __forceinline__ float softplus_f(float x) {
    return (x > 20.f) ? x : __logf(1.f + __expf(x));
}
// round-to-nearest-even f32 -> bf16 (as ushort)
__device__ __forceinline__ unsigned short f2bf(float f) {
    unsigned int u = __float_as_uint(f);
    u = (u + 0x7FFFu + ((u >> 16) & 1u)) >> 16;
    return (unsigned short)u;
}
__device__ __forceinline__ float b2f(unsigned short u) {
    return __uint_as_float(((unsigned int)u) << 16);
}

__device__ __forceinline__ const __attribute__((address_space(1))) void* as1(const void* p) {
    return (const __attribute__((address_space(1))) void*)(uintptr_t)p;
}
__device__ __forceinline__ __attribute__((address_space(3))) void* as3(void* p) {
    return (__attribute__((address_space(3))) void*)(uintptr_t)p;
}

// ---------------------------------------------------------------------------
// f32 -> bf16 cast, vectorized. n must be a multiple of 1024.
// ---------------------------------------------------------------------------
__global__ __launch_bounds__(256) void cast_kernel(const float* __restrict__ in,
                                                   unsigned short* __restrict__ out,
                                                   int n) {
    int i = (blockIdx.x * 256 + threadIdx.x) * 4;
    if (i >= n) return;
    float4 v = *reinterpret_cast<const float4*>(in + i);
    ushort4 o;
    o.x = f2bf(v.x); o.y = f2bf(v.y); o.z = f2bf(v.z); o.w = f2bf(v.w);
    *reinterpret_cast<ushort4*>(out + i) = o;
}

// out_w [1024][2048] f32 -> out_wb2 [1024][4096] bf16 at column offset dstoff.
__global__ __launch_bounds__(256) void cast_cc(const float* __restrict__ in,
                                               unsigned short* __restrict__ out,
                                               int dstoff) {
    int i = (blockIdx.x * 256 + threadIdx.x) * 4;   // over 1024*2048
    int r = i >> 11, c = i & 2047;
    float4 v = *reinterpret_cast<const float4*>(in + i);
    ushort4 o;
    o.x = f2bf(v.x); o.y = f2bf(v.y); o.z = f2bf(v.z); o.w = f2bf(v.w);
    *reinterpret_cast<ushort4*>(out + (size_t)r * 4096 + dstoff + c) = o;
}

// xproj_w [96][2048] f32 -> [2][128][2048] bf16, rows 96..127 zeroed. grid.y=br
__global__ __launch_bounds__(256) void padcast_xproj2(const float* __restrict__ inF,
                                                      const float* __restrict__ inB,
                                                      unsigned short* __restrict__ out) {
    int br = blockIdx.y;
    const float* in = br ? inB : inF;
    int i = (blockIdx.x * 256 + threadIdx.x) * 4;   // over 128*2048
    int row = i >> 11;
    ushort4 o = make_ushort4(0, 0, 0, 0);
    if (row < 96) {
        float4 v = *reinterpret_cast<const float4*>(in + i);
        o.x = f2bf(v.x); o.y = f2bf(v.y); o.z = f2bf(v.z); o.w = f2bf(v.w);
    }
    *reinterpret_cast<ushort4*>(out + (size_t)br * 128 * DI + i) = o;
}

// ---------------------------------------------------------------------------
// LayerNorm: one block per token row (1024 elems), 256 threads. Writes bf16.
// ---------------------------------------------------------------------------
__global__ __launch_bounds__(256) void ln_kernel(const float* __restrict__ x,
                                                 const float* __restrict__ g,
                                                 const float* __restrict__ b,
                                                 unsigned short* __restrict__ xnb) {
    int row = blockIdx.x;
    const float* xr = x + (size_t)row * DM;
    float v[4];
    float s = 0.f, s2 = 0.f;
#pragma unroll
    for (int i = 0; i < 4; i++) {
        v[i] = xr[threadIdx.x + i * 256];
        s += v[i];
        s2 += v[i] * v[i];
    }
#pragma unroll
    for (int off = 32; off; off >>= 1) {
        s  += __shfl_down(s, off);
        s2 += __shfl_down(s2, off);
    }
    __shared__ float ss[4], ss2[4];
    int wid = threadIdx.x >> 6, lane = threadIdx.x & 63;
    if (lane == 0) { ss[wid] = s; ss2[wid] = s2; }
    __syncthreads();
    if (threadIdx.x == 0) {
        float a = 0.f, a2 = 0.f;
#pragma unroll
        for (int i = 0; i < 4; i++) { a += ss[i]; a2 += ss2[i]; }
        ss[0] = a; ss2[0] = a2;
    }
    __syncthreads();
    float m   = ss[0] * (1.f / DM);
    float var = ss2[0] * (1.f / DM) - m * m;
    float inv = rsqrtf(var + 1e-5f);
#pragma unroll
    for (int i = 0; i < 4; i++) {
        int c = threadIdx.x + i * 256;
        xnb[(size_t)row * DM + c] = f2bf((v[i] - m) * inv * g[c] + b[c]);
    }
}

// ---------------------------------------------------------------------------
// Unified bf16 MFMA NT GEMM, 128x128 tile, BK=32, 4 waves, double-buffered.
// MODE 0: f32 store + blockIdx.z*zstride (split-K, single W)
// MODE 6: in-proj routing to u2 (Cv) / z2 (Cv2)
// MODE 7: dt GEMM, M=4096 (2 branches): W/bias selected by row>>11; packs
//         (u16<<16)|softplus16 into dtu0/dtu1 u32 arrays
// MODE 8: split-K f32 store with per-branch W select (xproj, M=4096)
// ---------------------------------------------------------------------------
template <int MODE>
__global__ __launch_bounds__(256) void gemm_mfma(const unsigned short* __restrict__ A,
                                                 const unsigned short* __restrict__ W,
                                                 const float* __restrict__ bias,
                                                 const float* __restrict__ biasB,
                                                 const unsigned short* __restrict__ upack,
                                                 void* __restrict__ Cv,
                                                 void* __restrict__ Cv2,
                                                 int ldc,
                                                 int Kst, int klen, size_t zstride,
                                                 int wbrstride) {
    __shared__ unsigned short As[2][128 * 32];
    __shared__ unsigned short Bs[2][128 * 32];

    int tid  = threadIdx.x;
    int lane = tid & 63;
    int w    = tid >> 6;
    int wr   = w >> 1;
    int wc   = w & 1;
    int m_blk = blockIdx.y * 128;
    int n_blk = blockIdx.x * 128;
    int kbeg  = blockIdx.z * klen;

    if (MODE == 7 || MODE == 8) W += (size_t)(m_blk >> 11) * wbrstride;

    int srow = (2 * w) * 16 + (lane >> 2);
    int scol = (lane & 3) * 8;
    const unsigned short* Ag0 = A + (size_t)(m_blk + srow) * Kst + scol;
    const unsigned short* Ag1 = Ag0 + (size_t)16 * Kst;
    const unsigned short* Wg0 = W + (size_t)(n_blk + srow) * Kst + scol;
    const unsigned short* Wg1 = Wg0 + (size_t)16 * Kst;
    int d0 = (2 * w) * 512, d1 = (2 * w + 1) * 512;

    f32x4 acc[4][4] = {};

    auto STAGE = [&](int buf, int k0) {
        __builtin_amdgcn_global_load_lds(as1(Ag0 + k0), as3(&As[buf][d0]), 16, 0, 0);
        __builtin_amdgcn_global_load_lds(as1(Ag1 + k0), as3(&As[buf][d1]), 16, 0, 0);
        __builtin_amdgcn_global_load_lds(as1(Wg0 + k0), as3(&Bs[buf][d0]), 16, 0, 0);
        __builtin_amdgcn_global_load_lds(as1(Wg1 + k0), as3(&Bs[buf][d1]), 16, 0, 0);
    };
    auto COMPUTE = [&](int buf) {
        bf16x8 af[4], wf[4];
#pragma unroll
        for (int i = 0; i < 4; i++)
            af[i] = *reinterpret_cast<const bf16x8*>(
                &As[buf][(wr * 64 + i * 16 + (lane & 15)) * 32 + (lane >> 4) * 8]);
#pragma unroll
        for (int j = 0; j < 4; j++)
            wf[j] = *reinterpret_cast<const bf16x8*>(
                &Bs[buf][(wc * 64 + j * 16 + (lane & 15)) * 32 + (lane >> 4) * 8]);
#pragma unroll
        for (int i = 0; i < 4; i++)
#pragma unroll
            for (int j = 0; j < 4; j++)
                acc[i][j] = __builtin_amdgcn_mfma_f32_16x16x32_bf16(af[i], wf[j], acc[i][j], 0, 0, 0);
    };

    STAGE(0, kbeg);
    asm volatile("s_waitcnt vmcnt(0)" ::: "memory");
    __syncthreads();
    int cur = 0;
    for (int k0 = kbeg + 32; k0 < kbeg + klen; k0 += 32) {
        STAGE(cur ^ 1, k0);
        COMPUTE(cur);
        asm volatile("s_waitcnt vmcnt(0)" ::: "memory");
        __syncthreads();
        cur ^= 1;
    }
    COMPUTE(cur);

    int colb = n_blk + wc * 64 + (lane & 15);
    int rowb = m_blk + wr * 64 + (lane >> 4) * 4;
#pragma unroll
    for (int i = 0; i < 4; i++) {
#pragma unroll
        for (int j = 0; j < 4; j++) {
            int col = colb + j * 16;
#pragma unroll
            for (int r = 0; r < 4; r++) {
                int row = rowb + i * 16 + r;
                float v = acc[i][j][r];
                if (MODE == 0 || MODE == 8) {
                    ((float*)Cv + blockIdx.z * zstride)[(size_t)row * ldc + col] = v;
                } else if (MODE == 6) {
                    int brn  = col >> 12;
                    int half = (col >> 11) & 1;
                    int cc   = col & 2047;
                    unsigned short* dst = half ? (unsigned short*)Cv2 : (unsigned short*)Cv;
                    dst[(size_t)row * 4096 + brn * 2048 + cc] = f2bf(v);
                } else { // MODE 7
                    const float* bs = (row >> 11) ? biasB : bias;
                    unsigned short u16 = upack[(size_t)row * DI + col];
                    unsigned int pk = ((unsigned int)u16 << 16) |
                                      (unsigned int)f2bf(softplus_f(v + bs[col]));
                    unsigned int* dst = (row >> 11) ? (unsigned int*)Cv2 : (unsigned int*)Cv;
                    dst[(size_t)(row & 2047) * DI + col] = pk;
                }
            }
        }
    }
}

// Reduce xproj split-K partials (both branches, M=4096) ->
// dbc2 f32 [2][2048][96] and dbcb2 bf16 [2][2048][64].
__global__ __launch_bounds__(256) void reduce_dbc(const float* __restrict__ partial,
                                                  float* __restrict__ dbc2,
                                                  unsigned short* __restrict__ dbcb2) {
    int id = blockIdx.x * 256 + threadIdx.x;   // 0 .. 4096*96-1
    int r = id / 96;                           // 0..4095 (br*2048 + row)
    int j = id - r * 96;
    float s = 0.f;
#pragma unroll
    for (int k = 0; k < KSPL; k++)
        s += partial[(size_t)k * (4096 * 128) + (size_t)r * 128 + j];
    dbc2[(size_t)r * 96 + j] = s;
    if (j < DTR) dbcb2[(size_t)r * DTR + j] = f2bf(s);
}

// out = x + partial2[0] + partial2[1]   (2048*1024 f32)
__global__ __launch_bounds__(256) void reduce_out(const float* __restrict__ p,
                                                  const float* __restrict__ x,
                                                  float* __restrict__ out) {
    int i = (blockIdx.x * 256 + threadIdx.x) * 4;
    float4 a  = *reinterpret_cast<const float4*>(p + i);
    float4 b  = *reinterpret_cast<const float4*>(p + 2097152 + i);
    float4 xv = *reinterpret_cast<const float4*>(x + i);
    float4 o;
    o.x = xv.x + a.x + b.x; o.y = xv.y + a.y + b.y;
    o.z = xv.z + a.z + b.z; o.w = xv.w + a.w + b.w;
    *reinterpret_cast<float4*>(out + i) = o;
}

// ---------------------------------------------------------------------------
// Causal conv1d (k=4) + SiLU, both branches in one dispatch (blockIdx.y = br).
// ---------------------------------------------------------------------------
__global__ __launch_bounds__(256) void conv_silu2(const unsigned short* __restrict__ u2,
                                                  const float* __restrict__ cwf,
                                                  const float* __restrict__ cbf,
                                                  const float* __restrict__ cwb,
                                                  const float* __restrict__ cbb,
                                                  unsigned short* __restrict__ ucb2) {
    int br = blockIdx.y;
    const float* cw = br ? cwb : cwf;
    const float* cb = br ? cbb : cbf;
    int idx = blockIdx.x * 256 + threadIdx.x;       // over 2*1024*2048
    int c = idx & (DI - 1);
    int t = (idx >> 11) & (LSEQ - 1);
    int b = idx >> 21;
    float acc = cb[c];
#pragma unroll
    for (int k = 0; k < 4; k++) {
        int tt = br ? (t + 3 - k) : (t - 3 + k);
        if (tt >= 0 && tt < LSEQ)
            acc = fmaf(cw[c * 4 + k], b2f(u2[((size_t)(b * LSEQ + tt)) * 4096 + br * 2048 + c]), acc);
    }
    ucb2[(size_t)br * BLROWS * DI + idx] = f2bf(silu_f(acc));
}

// ---------------------------------------------------------------------------
// Chunked selective scan, ONE thread per channel (16 states in registers),
// register-double-buffered prefetch of the packed dtu stream (8-step groups).
// blockIdx = (DI/256, NCHUNK, NSEQ), z = b*2 + br.
// ---------------------------------------------------------------------------
#define PF1(PK, S0) \
    _Pragma("unroll") for (int j = 0; j < 8; j++) { PK[j] = dp[(S0 + j) * dstr]; }

#define CG1(PK, S0) \
    _Pragma("unroll") for (int j = 0; j < 8; j++) { \
        unsigned int pk = PK[j]; \
        float dt = __uint_as_float(pk << 16); \
        float u  = __uint_as_float(pk & 0xFFFF0000u); \
        float du = dt * u; \
        dts += dt; \
        int s = S0 + j; \
        _Pragma("unroll") for (int q = 0; q < 4; q++) { \
            f32x4 Bq = *reinterpret_cast<const f32x4*>(&Bsh[s][q * 4]); \
            _Pragma("unroll") for (int k = 0; k < 4; k++) { \
                int n = q * 4 + k; \
                float dA = exp2f(dt * A2[n]); \
                h[n] = dA * h[n] + du * Bq[k]; \
            } \
        } \
    }

__global__ __launch_bounds__(256) void scan_p1(const unsigned int* __restrict__ dtu0,
                                               const unsigned int* __restrict__ dtu1,
                                               const float* __restrict__ dbc2,
                                               const float* __restrict__ Alog_f,
                                               const float* __restrict__ Alog_b,
                                               float* __restrict__ hend,
                                               float* __restrict__ dtsum) {
    int c     = blockIdx.x * 256 + threadIdx.x;
    int chunk = blockIdx.y;
    int z     = blockIdx.z;
    int br = z & 1, b = z >> 1;

    const unsigned int* dtu = br ? dtu1 : dtu0;
    const float* dbc   = dbc2 + (size_t)br * BLROWS * 96;
    const float* A_log = br ? Alog_b : Alog_f;

    __shared__ float Bsh[CLEN][16];
    for (int i = threadIdx.x; i < CLEN * 16; i += 256) {
        int s = i >> 4, j = i & 15;
        int sigma = chunk * CLEN + s;
        int t = br ? (LSEQ - 1 - sigma) : sigma;
        Bsh[s][j] = dbc[((size_t)b * LSEQ + t) * 96 + DTR + j];
    }
    __syncthreads();

    int sigma0 = chunk * CLEN;
    int t0 = br ? (LSEQ - 1 - sigma0) : sigma0;
    const unsigned int* dp = dtu + ((size_t)b * LSEQ + t0) * DI + c;
    long long dstr = br ? -(long long)DI : (long long)DI;

    const float LOG2E = 1.4426950408889634f;
    float A2[16], h[16];
#pragma unroll
    for (int n = 0; n < 16; n++) {
        A2[n] = -__expf(A_log[c * DST + n]) * LOG2E;
        h[n] = 0.f;
    }
    float dts = 0.f;

    unsigned int pkA[8], pkB[8];
    PF1(pkA, 0)
    PF1(pkB, 8)
    CG1(pkA, 0)
    PF1(pkA, 16)
    CG1(pkB, 8)
    PF1(pkB, 24)
    CG1(pkA, 16)
    CG1(pkB, 24)

    size_t base = (((size_t)z * NCHUNK + chunk) * DI + c) * DST;
#pragma unroll
    for (int q = 0; q < 4; q++)
        *reinterpret_cast<f32x4*>(&hend[base + q * 4]) = *reinterpret_cast<f32x4*>(&h[q * 4]);
    dtsum[((size_t)z * NCHUNK + chunk) * DI + c] = dts;
}

// Combine: per (z,c,n), prefix over chunks. P = exp2(dtsum * A2). Writes h0.
__global__ __launch_bounds__(256) void scan_p2(const float* __restrict__ hend,
                                               const float* __restrict__ dtsum,
                                               const float* __restrict__ Alog_f,
                                               const float* __restrict__ Alog_b,
                                               float* __restrict__ h0) {
    int id = blockIdx.x * 256 + threadIdx.x;     // 0 .. NSEQ*DI*DST-1
    int n  = id & (DST - 1);
    int c  = (id >> 4) & (DI - 1);
    int z  = id >> 15;
    int br = z & 1;
    const float* A_log = br ? Alog_b : Alog_f;
    const float LOG2E = 1.4426950408889634f;
    float A2 = -__expf(A_log[c * DST + n]) * LOG2E;

    float h = 0.f;
    for (int k = 0; k < NCHUNK; k++) {
        size_t idx = (((size_t)z * NCHUNK + k) * DI + c) * DST + n;
        float P = exp2f(dtsum[((size_t)z * NCHUNK + k) * DI + c] * A2);
        h0[idx] = h;
        h = P * h + hend[idx];
    }
}

#define PF3(PK, ZR, S0) \
    _Pragma("unroll") for (int j = 0; j < 8; j++) { \
        PK[j] = dp[(S0 + j) * dstr]; \
        ZR[j] = zp[(S0 + j) * zstr]; \
    }

#define CG3(PK, ZR, S0) \
    _Pragma("unroll") for (int j = 0; j < 8; j++) { \
        unsigned int pk = PK[j]; \
        float dt = __uint_as_float(pk << 16); \
        float u  = __uint_as_float(pk & 0xFFFF0000u); \
        float du = dt * u; \
        int s = S0 + j; \
        float y = 0.f; \
        _Pragma("unroll") for (int q = 0; q < 4; q++) { \
            f32x4 Bq = *reinterpret_cast<const f32x4*>(&BCs[s][q * 4]); \
            f32x4 Cq = *reinterpret_cast<const f32x4*>(&BCs[s][16 + q * 4]); \
            _Pragma("unroll") for (int k = 0; k < 4; k++) { \
                int n = q * 4 + k; \
                float dA = exp2f(dt * A2[n]); \
                h[n] = dA * h[n] + du * Bq[k]; \
                y = fmaf(h[n], Cq[k], y); \
            } \
        } \
        float yy = y + u * Dv; \
        float zg = b2f(ZR[j]); \
        gp[s * gstr] = f2bf(yy * silu_f(zg)); \
    }

__global__ __launch_bounds__(256) void scan_p3(const unsigned int* __restrict__ dtu0,
                                               const unsigned int* __restrict__ dtu1,
                                               const float* __restrict__ dbc2,
                                               const unsigned short* __restrict__ z2,
                                               const float* __restrict__ Alog_f,
                                               const float* __restrict__ Alog_b,
                                               const float* __restrict__ Dp_f,
                                               const float* __restrict__ Dp_b,
                                               const float* __restrict__ h0,
                                               unsigned short* __restrict__ G2) {
    int c     = blockIdx.x * 256 + threadIdx.x;
    int chunk = blockIdx.y;
    int z     = blockIdx.z;
    int br = z & 1, b = z >> 1;

    const unsigned int* dtu = br ? dtu1 : dtu0;
    const float* dbc   = dbc2 + (size_t)br * BLROWS * 96;
    const float* A_log = br ? Alog_b : Alog_f;
    const float* Dp    = br ? Dp_b : Dp_f;

    __shared__ float BCs[CLEN][32];
    for (int i = threadIdx.x; i < CLEN * 32; i += 256) {
        int s = i >> 5, j = i & 31;
        int sigma = chunk * CLEN + s;
        int t = br ? (LSEQ - 1 - sigma) : sigma;
        BCs[s][j] = dbc[((size_t)b * LSEQ + t) * 96 + DTR + j];
    }
    __syncthreads();

    int sigma0 = chunk * CLEN;
    int t0 = br ? (LSEQ - 1 - sigma0) : sigma0;
    long long row0 = (long long)b * LSEQ + t0;
    long long rsgn = br ? -1 : 1;
    const unsigned int* dp = dtu + row0 * DI + c;
    long long dstr = rsgn * DI;
    const unsigned short* zp = z2 + row0 * 4096 + br * 2048 + c;
    long long zstr = rsgn * 4096;
    unsigned short* gp = G2 + row0 * (2 * DI) + br * DI + c;
    long long gstr = rsgn * (2 * DI);

    const float LOG2E = 1.4426950408889634f;
    float A2[16], h[16];
    size_t base = (((size_t)z * NCHUNK + chunk) * DI + c) * DST;
#pragma unroll
    for (int n = 0; n < 16; n++)
        A2[n] = -__expf(A_log[c * DST + n]) * LOG2E;
#pragma unroll
    for (int q = 0; q < 4; q++)
        *reinterpret_cast<f32x4*>(&h[q * 4]) = *reinterpret_cast<const f32x4*>(&h0[base + q * 4]);
    float Dv = Dp[c];

    unsigned int pkA[8], pkB[8];
    unsigned short zA[8], zB[8];
    PF3(pkA, zA, 0)
    PF3(pkB, zB, 8)
    CG3(pkA, zA, 0)
    PF3(pkA, zA, 16)
    CG3(pkB, zB, 8)
    PF3(pkB, zB, 24)
    CG3(pkA, zA, 16)
    CG3(pkB, zB, 24)
}

// ---------------------------------------------------------------------------
extern "C" void kernel_launch(void* const* d_in, const int* in_sizes, int n_in,
                              void* d_out, int out_size, void* d_ws, size_t ws_size,
                              hipStream_t stream) {
    const float* x    = (const float*)d_in[0];
    const float* ln_g = (const float*)d_in[1];
    const float* ln_b = (const float*)d_in[2];
    float* out = (float*)d_out;

    char* wp = (char*)d_ws;
    // R0 (4MB): xnb; after in-proj: dbc2 (1.5MB) + dbcb2 (0.5MB) + dtsum (1MB)
    unsigned short* xnb = (unsigned short*)wp;                 wp += (size_t)BLROWS * DM * 2;
    // R1 (16MB): z2 [2048][4096] bf16, live till p3
    unsigned short* z2  = (unsigned short*)wp;                 wp += (size_t)BLROWS * 4096 * 2;
    // R2 (16MB): u2 (dead after conv) -> dtu0 [2048][2048] u32
    unsigned short* u2  = (unsigned short*)wp;                 wp += (size_t)BLROWS * 4096 * 2;
    // R3 (16MB): in_wb2 -> partial(xproj) -> dtu1 [2048][2048] u32
    unsigned short* in_wb2 = (unsigned short*)wp;              wp += (size_t)4 * DI * DM * 2;
    // R4 (16MB): ucb2 [2][2048][2048] bf16 (dead after dt GEMM) -> hend (16MB)
    //            -> after p2: front 8MB = out_wb2
    unsigned short* ucb2 = (unsigned short*)wp;                wp += (size_t)2 * BLROWS * DI * 2;
    // R5 (16MB): h0 [NSEQ][NCHUNK][DI][DST] f32 -> after p3: partial2
    float* h0r = (float*)wp;                                   wp += (size_t)NSEQ * NCHUNK * DI * DST * 4;
    // R6 (16MB): G2 [2048][4096] bf16
    unsigned short* G2 = (unsigned short*)wp;                  wp += (size_t)BLROWS * 2 * DI * 2;
    // R7: xprojb2 [2][128][2048] bf16 (1MB) + dt_wb2 [2][2048][64] bf16 (0.5MB)
    unsigned short* xprojb2 = (unsigned short*)wp;             wp += (size_t)2 * 128 * DI * 2;
    unsigned short* dt_wb2  = (unsigned short*)wp;             wp += (size_t)2 * DI * DTR * 2;
    // total = 101.5 MB

    // aliases (lifetime-audited)
    float* dbc2           = (float*)xnb;                           // [2][2048][96] f32
    unsigned short* dbcb2 = xnb + (size_t)2 * BLROWS * 96 * 2;     // [2][2048][64] bf16 (after full dbc2)
    float* dtsum          = (float*)((char*)xnb + 2097152);        // [NSEQ][NCHUNK][DI] f32, 1MB
    unsigned int* dtu0    = (unsigned int*)u2;                     // R2
    float* partial        = (float*)in_wb2;                        // R3 (xproj split-K)
    unsigned int* dtu1    = (unsigned int*)in_wb2;                 // R3 (after reduce_dbc)
    float* hend           = (float*)ucb2;                          // R4 (after dt GEMM)
    unsigned short* out_wb2 = ucb2;                                // R4 front 8MB (after p2)
    float* h0             = h0r;                                   // R5
    float* partial2       = h0r;                                   // R5 (after p3)

    // 1. LayerNorm -> xnb
    ln_kernel<<<BLROWS, 256, 0, stream>>>(x, ln_g, ln_b, xnb);

    // 2. cast both in_w into [8192][1024]
    cast_kernel<<<(2 * DI * DM) / 1024, 256, 0, stream>>>(
        (const float*)d_in[3], in_wb2, 2 * DI * DM);
    cast_kernel<<<(2 * DI * DM) / 1024, 256, 0, stream>>>(
        (const float*)d_in[12], in_wb2 + (size_t)2 * DI * DM, 2 * DI * DM);

    // 3. batched in-proj (2048 x 8192 x 1024) -> u2 / z2 (bf16, routed)
    gemm_mfma<6><<<dim3(4 * DI / 128, BLROWS / 128, 1), 256, 0, stream>>>(
        xnb, in_wb2, nullptr, nullptr, nullptr, u2, z2, 4096, DM, DM, 0, 0);

    // 4. conv + SiLU, both branches -> ucb2
    conv_silu2<<<dim3((BLROWS * DI) / 256, 2), 256, 0, stream>>>(
        u2, (const float*)d_in[4], (const float*)d_in[5],
        (const float*)d_in[13], (const float*)d_in[14], ucb2);

    // 5. weight prep (both branches, batched)
    padcast_xproj2<<<dim3((128 * DI) / 1024, 2), 256, 0, stream>>>(
        (const float*)d_in[6], (const float*)d_in[15], xprojb2);
    cast_kernel<<<(DI * DTR) / 1024, 256, 0, stream>>>(
        (const float*)d_in[7], dt_wb2, DI * DTR);
    cast_kernel<<<(DI * DTR) / 1024, 256, 0, stream>>>(
        (const float*)d_in[16], dt_wb2 + (size_t)DI * DTR, DI * DTR);

    // 6. xproj both branches: M=4096, split-K 8 -> partial (R3)
    gemm_mfma<8><<<dim3(1, 4096 / 128, KSPL), 256, 0, stream>>>(
        ucb2, xprojb2, nullptr, nullptr, nullptr, partial, nullptr,
        128, DI, DI / KSPL, (size_t)4096 * 128, 128 * DI);
    reduce_dbc<<<(4096 * 96) / 256, 256, 0, stream>>>(partial, dbc2, dbcb2);

    // 7. dt GEMM both branches (M=4096), packed epilogue -> dtu0/dtu1
    gemm_mfma<7><<<dim3(DI / 128, 4096 / 128, 1), 256, 0, stream>>>(
        dbcb2, dt_wb2, (const float*)d_in[8], (const float*)d_in[17], ucb2,
        dtu0, dtu1, DI, DTR, DTR, 0, DI * DTR);

    // 8. scan phase 1 + combine
    scan_p1<<<dim3(DI / 256, NCHUNK, NSEQ), 256, 0, stream>>>(
        dtu0, dtu1, dbc2, (const float*)d_in[9], (const float*)d_in[18],
        hend, dtsum);
    scan_p2<<<(NSEQ * DI * DST) / 256, 256, 0, stream>>>(
        hend, dtsum, (const float*)d_in[9], (const float*)d_in[18], h0);

    // 9. cast out_w into R4 front (hend dead after p2)
    cast_cc<<<(DM * DI) / 1024, 256, 0, stream>>>((const float*)d_in[11], out_wb2, 0);
    cast_cc<<<(DM * DI) / 1024, 256, 0, stream>>>((const float*)d_in[20], out_wb2, DI);

    // 10. scan phase 3 -> G2
    scan_p3<<<dim3(DI / 256, NCHUNK, NSEQ), 256, 0, stream>>>(
        dtu0, dtu1, dbc2, z2, (const float*)d_in[9], (const float*)d_in[18],
        (const float*)d_in[10], (const float*)d_in[19], h0, G2);

    // 11. combined out-proj (K=4096, split-K 2) + reduce with residual
    gemm_mfma<0><<<dim3(DM / 128, BLROWS / 128, 2), 256, 0, stream>>>(
        G2, out_wb2, nullptr, nullptr, nullptr, partial2, nullptr,
        DM, 2 * DI, DI, (size_t)BLROWS * DM, 0);
    reduce_out<<<(BLROWS * DM) / 1024, 256, 0, stream>>>(partial2, x, out);
}

// Round 11
// 272.885 us; speedup vs baseline: 10.0298x; 1.0672x over previous
//
#include <hip/hip_runtime.h>
#include <math.h>

#define DM   1024   // d_model
#define DI   2048   // d_inner
#define DST  16     // d_state
#define DTR  64     // dt_rank
#define LSEQ 1024   // L
#define NBAT 2      // B
#define BLROWS (NBAT*LSEQ)   // 2048 token rows
#define NCHUNK 32
#define CLEN   32   // LSEQ / NCHUNK
#define KSPL   8    // K-splits for xproj GEMM (both branches combined)
#define NSEQ   4    // batch x branch scan sequences

typedef __bf16 bf16x8 __attribute__((ext_vector_type(8)));
typedef float  f32x4  __attribute__((ext_vector_type(4)));
typedef unsigned short u16x8 __attribute__((ext_vector_type(8)));

__device__ __forceinline__ float silu_f(float x) {
    return x / (1.f + __expf(-x));
}
__device__ __forceinline__ float softplus_f(float x) {
    return (x > 20.f) ? x : __logf(1.f + __expf(x));
}
// round-to-nearest-even f32 -> bf16 (as ushort)
__device__ __forceinline__ unsigned short f2bf(float f) {
    unsigned int u = __float_as_uint(f);
    u = (u + 0x7FFFu + ((u >> 16) & 1u)) >> 16;
    return (unsigned short)u;
}
__device__ __forceinline__ float b2f(unsigned short u) {
    return __uint_as_float(((unsigned int)u) << 16);
}

__device__ __forceinline__ const __attribute__((address_space(1))) void* as1(const void* p) {
    return (const __attribute__((address_space(1))) void*)(uintptr_t)p;
}
__device__ __forceinline__ __attribute__((address_space(3))) void* as3(void* p) {
    return (__attribute__((address_space(3))) void*)(uintptr_t)p;
}

// ---------------------------------------------------------------------------
// Paired f32 -> bf16 cast: grid.y selects src; dst offset br*n.
// ---------------------------------------------------------------------------
__global__ __launch_bounds__(256) void cast2_kernel(const float* __restrict__ inA,
                                                    const float* __restrict__ inB,
                                                    unsigned short* __restrict__ out,
                                                    int n) {
    int br = blockIdx.y;
    const float* in = br ? inB : inA;
    int i = (blockIdx.x * 256 + threadIdx.x) * 4;
    if (i >= n) return;
    float4 v = *reinterpret_cast<const float4*>(in + i);
    ushort4 o;
    o.x = f2bf(v.x); o.y = f2bf(v.y); o.z = f2bf(v.z); o.w = f2bf(v.w);
    *reinterpret_cast<ushort4*>(out + (size_t)br * n + i) = o;
}

// out_w pair [1024][2048] f32 -> out_wb2 [1024][4096] bf16; grid.y = br = col off.
__global__ __launch_bounds__(256) void cast_cc2(const float* __restrict__ inA,
                                                const float* __restrict__ inB,
                                                unsigned short* __restrict__ out) {
    int br = blockIdx.y;
    const float* in = br ? inB : inA;
    int i = (blockIdx.x * 256 + threadIdx.x) * 4;   // over 1024*2048
    int r = i >> 11, c = i & 2047;
    float4 v = *reinterpret_cast<const float4*>(in + i);
    ushort4 o;
    o.x = f2bf(v.x); o.y = f2bf(v.y); o.z = f2bf(v.z); o.w = f2bf(v.w);
    *reinterpret_cast<ushort4*>(out + (size_t)r * 4096 + br * DI + c) = o;
}

// xproj_w [96][2048] f32 -> [2][128][2048] bf16, rows 96..127 zeroed. grid.y=br
__global__ __launch_bounds__(256) void padcast_xproj2(const float* __restrict__ inF,
                                                      const float* __restrict__ inB,
                                                      unsigned short* __restrict__ out) {
    int br = blockIdx.y;
    const float* in = br ? inB : inF;
    int i = (blockIdx.x * 256 + threadIdx.x) * 4;   // over 128*2048
    int row = i >> 11;
    ushort4 o = make_ushort4(0, 0, 0, 0);
    if (row < 96) {
        float4 v = *reinterpret_cast<const float4*>(in + i);
        o.x = f2bf(v.x); o.y = f2bf(v.y); o.z = f2bf(v.z); o.w = f2bf(v.w);
    }
    *reinterpret_cast<ushort4*>(out + (size_t)br * 128 * DI + i) = o;
}

// ---------------------------------------------------------------------------
// LayerNorm: one block per token row (1024 elems), 256 threads. Writes bf16.
// ---------------------------------------------------------------------------
__global__ __launch_bounds__(256) void ln_kernel(const float* __restrict__ x,
                                                 const float* __restrict__ g,
                                                 const float* __restrict__ b,
                                                 unsigned short* __restrict__ xnb) {
    int row = blockIdx.x;
    const float* xr = x + (size_t)row * DM;
    float v[4];
    float s = 0.f, s2 = 0.f;
#pragma unroll
    for (int i = 0; i < 4; i++) {
        v[i] = xr[threadIdx.x + i * 256];
        s += v[i];
        s2 += v[i] * v[i];
    }
#pragma unroll
    for (int off = 32; off; off >>= 1) {
        s  += __shfl_down(s, off);
        s2 += __shfl_down(s2, off);
    }
    __shared__ float ss[4], ss2[4];
    int wid = threadIdx.x >> 6, lane = threadIdx.x & 63;
    if (lane == 0) { ss[wid] = s; ss2[wid] = s2; }
    __syncthreads();
    if (threadIdx.x == 0) {
        float a = 0.f, a2 = 0.f;
#pragma unroll
        for (int i = 0; i < 4; i++) { a += ss[i]; a2 += ss2[i]; }
        ss[0] = a; ss2[0] = a2;
    }
    __syncthreads();
    float m   = ss[0] * (1.f / DM);
    float var = ss2[0] * (1.f / DM) - m * m;
    float inv = rsqrtf(var + 1e-5f);
#pragma unroll
    for (int i = 0; i < 4; i++) {
        int c = threadIdx.x + i * 256;
        xnb[(size_t)row * DM + c] = f2bf((v[i] - m) * inv * g[c] + b[c]);
    }
}

// ---------------------------------------------------------------------------
// Unified bf16 MFMA NT GEMM, 128x128 tile, BK=32, 4 waves, double-buffered.
// MODE 6: in-proj routing to u2 (Cv) / z2 (Cv2)
// MODE 7: dt GEMM, M=4096 (2 branches): W/bias by row>>11; packs
//         (u16<<16)|softplus16 into dtu0/dtu1 u32 arrays
// MODE 8: split-K f32 store with per-branch W select (xproj, M=4096)
// MODE 9: split-K-4 f32 store: dst = (z<2 ? Cv : Cv2) + (z&1)*zstride
// ---------------------------------------------------------------------------
template <int MODE>
__global__ __launch_bounds__(256) void gemm_mfma(const unsigned short* __restrict__ A,
                                                 const unsigned short* __restrict__ W,
                                                 const float* __restrict__ bias,
                                                 const float* __restrict__ biasB,
                                                 const unsigned short* __restrict__ upack,
                                                 void* __restrict__ Cv,
                                                 void* __restrict__ Cv2,
                                                 int ldc,
                                                 int Kst, int klen, size_t zstride,
                                                 int wbrstride) {
    __shared__ unsigned short As[2][128 * 32];
    __shared__ unsigned short Bs[2][128 * 32];

    int tid  = threadIdx.x;
    int lane = tid & 63;
    int w    = tid >> 6;
    int wr   = w >> 1;
    int wc   = w & 1;
    int m_blk = blockIdx.y * 128;
    int n_blk = blockIdx.x * 128;
    int kbeg  = blockIdx.z * klen;

    if (MODE == 7 || MODE == 8) W += (size_t)(m_blk >> 11) * wbrstride;

    int srow = (2 * w) * 16 + (lane >> 2);
    int scol = (lane & 3) * 8;
    const unsigned short* Ag0 = A + (size_t)(m_blk + srow) * Kst + scol;
    const unsigned short* Ag1 = Ag0 + (size_t)16 * Kst;
    const unsigned short* Wg0 = W + (size_t)(n_blk + srow) * Kst + scol;
    const unsigned short* Wg1 = Wg0 + (size_t)16 * Kst;
    int d0 = (2 * w) * 512, d1 = (2 * w + 1) * 512;

    f32x4 acc[4][4] = {};

    auto STAGE = [&](int buf, int k0) {
        __builtin_amdgcn_global_load_lds(as1(Ag0 + k0), as3(&As[buf][d0]), 16, 0, 0);
        __builtin_amdgcn_global_load_lds(as1(Ag1 + k0), as3(&As[buf][d1]), 16, 0, 0);
        __builtin_amdgcn_global_load_lds(as1(Wg0 + k0), as3(&Bs[buf][d0]), 16, 0, 0);
        __builtin_amdgcn_global_load_lds(as1(Wg1 + k0), as3(&Bs[buf][d1]), 16, 0, 0);
    };
    auto COMPUTE = [&](int buf) {
        bf16x8 af[4], wf[4];
#pragma unroll
        for (int i = 0; i < 4; i++)
            af[i] = *reinterpret_cast<const bf16x8*>(
                &As[buf][(wr * 64 + i * 16 + (lane & 15)) * 32 + (lane >> 4) * 8]);
#pragma unroll
        for (int j = 0; j < 4; j++)
            wf[j] = *reinterpret_cast<const bf16x8*>(
                &Bs[buf][(wc * 64 + j * 16 + (lane & 15)) * 32 + (lane >> 4) * 8]);
#pragma unroll
        for (int i = 0; i < 4; i++)
#pragma unroll
            for (int j = 0; j < 4; j++)
                acc[i][j] = __builtin_amdgcn_mfma_f32_16x16x32_bf16(af[i], wf[j], acc[i][j], 0, 0, 0);
    };

    STAGE(0, kbeg);
    asm volatile("s_waitcnt vmcnt(0)" ::: "memory");
    __syncthreads();
    int cur = 0;
    for (int k0 = kbeg + 32; k0 < kbeg + klen; k0 += 32) {
        STAGE(cur ^ 1, k0);
        COMPUTE(cur);
        asm volatile("s_waitcnt vmcnt(0)" ::: "memory");
        __syncthreads();
        cur ^= 1;
    }
    COMPUTE(cur);

    int colb = n_blk + wc * 64 + (lane & 15);
    int rowb = m_blk + wr * 64 + (lane >> 4) * 4;
#pragma unroll
    for (int i = 0; i < 4; i++) {
#pragma unroll
        for (int j = 0; j < 4; j++) {
            int col = colb + j * 16;
#pragma unroll
            for (int r = 0; r < 4; r++) {
                int row = rowb + i * 16 + r;
                float v = acc[i][j][r];
                if (MODE == 8) {
                    ((float*)Cv + blockIdx.z * zstride)[(size_t)row * ldc + col] = v;
                } else if (MODE == 9) {
                    float* base = (blockIdx.z < 2) ? (float*)Cv : (float*)Cv2;
                    (base + (blockIdx.z & 1) * zstride)[(size_t)row * ldc + col] = v;
                } else if (MODE == 6) {
                    int brn  = col >> 12;
                    int half = (col >> 11) & 1;
                    int cc   = col & 2047;
                    unsigned short* dst = half ? (unsigned short*)Cv2 : (unsigned short*)Cv;
                    dst[(size_t)row * 4096 + brn * 2048 + cc] = f2bf(v);
                } else { // MODE 7
                    const float* bs = (row >> 11) ? biasB : bias;
                    unsigned short u16 = upack[(size_t)row * DI + col];
                    unsigned int pk = ((unsigned int)u16 << 16) |
                                      (unsigned int)f2bf(softplus_f(v + bs[col]));
                    unsigned int* dst = (row >> 11) ? (unsigned int*)Cv2 : (unsigned int*)Cv;
                    dst[(size_t)(row & 2047) * DI + col] = pk;
                }
            }
        }
    }
}

// Reduce xproj split-K partials (both branches, M=4096) ->
// dbc2 f32 [2][2048][96] and dbcb2 bf16 [2][2048][64].
__global__ __launch_bounds__(256) void reduce_dbc(const float* __restrict__ partial,
                                                  float* __restrict__ dbc2,
                                                  unsigned short* __restrict__ dbcb2) {
    int id = blockIdx.x * 256 + threadIdx.x;   // 0 .. 4096*96-1
    int r = id / 96;                           // 0..4095 (br*2048 + row)
    int j = id - r * 96;
    float s = 0.f;
#pragma unroll
    for (int k = 0; k < KSPL; k++)
        s += partial[(size_t)k * (4096 * 128) + (size_t)r * 128 + j];
    dbc2[(size_t)r * 96 + j] = s;
    if (j < DTR) dbcb2[(size_t)r * DTR + j] = f2bf(s);
}

// out = x + pA[0] + pA[1] + pB[0] + pB[1]   (2048*1024 f32)
__global__ __launch_bounds__(256) void reduce_out4(const float* __restrict__ pA,
                                                   const float* __restrict__ pB,
                                                   const float* __restrict__ x,
                                                   float* __restrict__ out) {
    int i = (blockIdx.x * 256 + threadIdx.x) * 4;
    float4 a  = *reinterpret_cast<const float4*>(pA + i);
    float4 b  = *reinterpret_cast<const float4*>(pA + 2097152 + i);
    float4 c  = *reinterpret_cast<const float4*>(pB + i);
    float4 d  = *reinterpret_cast<const float4*>(pB + 2097152 + i);
    float4 xv = *reinterpret_cast<const float4*>(x + i);
    float4 o;
    o.x = xv.x + (a.x + b.x) + (c.x + d.x);
    o.y = xv.y + (a.y + b.y) + (c.y + d.y);
    o.z = xv.z + (a.z + b.z) + (c.z + d.z);
    o.w = xv.w + (a.w + b.w) + (c.w + d.w);
    *reinterpret_cast<float4*>(out + i) = o;
}

// ---------------------------------------------------------------------------
// Causal conv1d (k=4) + SiLU, vectorized 8 channels/thread; grid.y = br.
// ---------------------------------------------------------------------------
__global__ __launch_bounds__(256) void conv_silu8(const unsigned short* __restrict__ u2,
                                                  const float* __restrict__ cwf,
                                                  const float* __restrict__ cbf,
                                                  const float* __restrict__ cwb,
                                                  const float* __restrict__ cbb,
                                                  unsigned short* __restrict__ ucb2) {
    int br = blockIdx.y;
    const float* cw = br ? cwb : cwf;
    const float* cb = br ? cbb : cbf;
    int idx8 = blockIdx.x * 256 + threadIdx.x;      // over 2*1024*256
    int c8 = (idx8 & 255) * 8;                      // channel base
    int t  = (idx8 >> 8) & (LSEQ - 1);
    int b  = idx8 >> 18;

    float acc[8];
    float4 cwr[8];
#pragma unroll
    for (int j = 0; j < 8; j++) {
        acc[j] = cb[c8 + j];
        cwr[j] = *reinterpret_cast<const float4*>(cw + (c8 + j) * 4);
    }
#pragma unroll
    for (int k = 0; k < 4; k++) {
        int tt = br ? (t + 3 - k) : (t - 3 + k);
        if (tt >= 0 && tt < LSEQ) {
            u16x8 s8 = *reinterpret_cast<const u16x8*>(
                &u2[((size_t)(b * LSEQ + tt)) * 4096 + br * 2048 + c8]);
#pragma unroll
            for (int j = 0; j < 8; j++) {
                float wv = (k == 0) ? cwr[j].x : (k == 1) ? cwr[j].y
                         : (k == 2) ? cwr[j].z : cwr[j].w;
                acc[j] = fmaf(wv, b2f(s8[j]), acc[j]);
            }
        }
    }
    u16x8 o;
#pragma unroll
    for (int j = 0; j < 8; j++) o[j] = f2bf(silu_f(acc[j]));
    *reinterpret_cast<u16x8*>(
        &ucb2[(size_t)br * BLROWS * DI + ((size_t)(b * LSEQ + t)) * DI + c8]) = o;
}

// ---------------------------------------------------------------------------
// Chunked selective scan, ONE thread per channel (16 states in registers),
// register-double-buffered prefetch of the packed dtu stream (8-step groups).
// blockIdx = (DI/256, NCHUNK, NSEQ), z = b*2 + br.
// ---------------------------------------------------------------------------
#define PF1(PK, S0) \
    _Pragma("unroll") for (int j = 0; j < 8; j++) { PK[j] = dp[(S0 + j) * dstr]; }

#define CG1(PK, S0) \
    _Pragma("unroll") for (int j = 0; j < 8; j++) { \
        unsigned int pk = PK[j]; \
        float dt = __uint_as_float(pk << 16); \
        float u  = __uint_as_float(pk & 0xFFFF0000u); \
        float du = dt * u; \
        dts += dt; \
        int s = S0 + j; \
        _Pragma("unroll") for (int q = 0; q < 4; q++) { \
            f32x4 Bq = *reinterpret_cast<const f32x4*>(&Bsh[s][q * 4]); \
            _Pragma("unroll") for (int k = 0; k < 4; k++) { \
                int n = q * 4 + k; \
                float dA = exp2f(dt * A2[n]); \
                h[n] = dA * h[n] + du * Bq[k]; \
            } \
        } \
    }

__global__ __launch_bounds__(256) void scan_p1(const unsigned int* __restrict__ dtu0,
                                               const unsigned int* __restrict__ dtu1,
                                               const float* __restrict__ dbc2,
                                               const float* __restrict__ Alog_f,
                                               const float* __restrict__ Alog_b,
                                               float* __restrict__ hend,
                                               float* __restrict__ dtsum) {
    int c     = blockIdx.x * 256 + threadIdx.x;
    int chunk = blockIdx.y;
    int z     = blockIdx.z;
    int br = z & 1, b = z >> 1;

    const unsigned int* dtu = br ? dtu1 : dtu0;
    const float* dbc   = dbc2 + (size_t)br * BLROWS * 96;
    const float* A_log = br ? Alog_b : Alog_f;

    __shared__ float Bsh[CLEN][16];
    for (int i = threadIdx.x; i < CLEN * 16; i += 256) {
        int s = i >> 4, j = i & 15;
        int sigma = chunk * CLEN + s;
        int t = br ? (LSEQ - 1 - sigma) : sigma;
        Bsh[s][j] = dbc[((size_t)b * LSEQ + t) * 96 + DTR + j];
    }
    __syncthreads();

    int sigma0 = chunk * CLEN;
    int t0 = br ? (LSEQ - 1 - sigma0) : sigma0;
    const unsigned int* dp = dtu + ((size_t)b * LSEQ + t0) * DI + c;
    long long dstr = br ? -(long long)DI : (long long)DI;

    const float LOG2E = 1.4426950408889634f;
    float A2[16], h[16];
#pragma unroll
    for (int n = 0; n < 16; n++) {
        A2[n] = -__expf(A_log[c * DST + n]) * LOG2E;
        h[n] = 0.f;
    }
    float dts = 0.f;

    unsigned int pkA[8], pkB[8];
    PF1(pkA, 0)
    PF1(pkB, 8)
    CG1(pkA, 0)
    PF1(pkA, 16)
    CG1(pkB, 8)
    PF1(pkB, 24)
    CG1(pkA, 16)
    CG1(pkB, 24)

    size_t base = (((size_t)z * NCHUNK + chunk) * DI + c) * DST;
#pragma unroll
    for (int q = 0; q < 4; q++)
        *reinterpret_cast<f32x4*>(&hend[base + q * 4]) = *reinterpret_cast<f32x4*>(&h[q * 4]);
    dtsum[((size_t)z * NCHUNK + chunk) * DI + c] = dts;
}

// Combine: per (z,c,n), prefix over chunks. P = exp2(dtsum * A2). Writes h0.
__global__ __launch_bounds__(256) void scan_p2(const float* __restrict__ hend,
                                               const float* __restrict__ dtsum,
                                               const float* __restrict__ Alog_f,
                                               const float* __restrict__ Alog_b,
                                               float* __restrict__ h0) {
    int id = blockIdx.x * 256 + threadIdx.x;     // 0 .. NSEQ*DI*DST-1
    int n  = id & (DST - 1);
    int c  = (id >> 4) & (DI - 1);
    int z  = id >> 15;
    int br = z & 1;
    const float* A_log = br ? Alog_b : Alog_f;
    const float LOG2E = 1.4426950408889634f;
    float A2 = -__expf(A_log[c * DST + n]) * LOG2E;

    float h = 0.f;
    for (int k = 0; k < NCHUNK; k++) {
        size_t idx = (((size_t)z * NCHUNK + k) * DI + c) * DST + n;
        float P = exp2f(dtsum[((size_t)z * NCHUNK + k) * DI + c] * A2);
        h0[idx] = h;
        h = P * h + hend[idx];
    }
}

#define PF3(PK, ZR, S0) \
    _Pragma("unroll") for (int j = 0; j < 8; j++) { \
        PK[j] = dp[(S0 + j) * dstr]; \
        ZR[j] = zp[(S0 + j) * zstr]; \
    }

#define CG3(PK, ZR, S0) \
    _Pragma("unroll") for (int j = 0; j < 8; j++) { \
        unsigned int pk = PK[j]; \
        float dt = __uint_as_float(pk << 16); \
        float u  = __uint_as_float(pk & 0xFFFF0000u); \
        float du = dt * u; \
        int s = S0 + j; \
        float y = 0.f; \
        _Pragma("unroll") for (int q = 0; q < 4; q++) { \
            f32x4 Bq = *reinterpret_cast<const f32x4*>(&BCs[s][q * 4]); \
            f32x4 Cq = *reinterpret_cast<const f32x4*>(&BCs[s][16 + q * 4]); \
            _Pragma("unroll") for (int k = 0; k < 4; k++) { \
                int n = q * 4 + k; \
                float dA = exp2f(dt * A2[n]); \
                h[n] = dA * h[n] + du * Bq[k]; \
                y = fmaf(h[n], Cq[k], y); \
            } \
        } \
        float yy = y + u * Dv; \
        float zg = b2f(ZR[j]); \
        gp[s * gstr] = f2bf(yy * silu_f(zg)); \
    }

__global__ __launch_bounds__(256) void scan_p3(const unsigned int* __restrict__ dtu0,
                                               const unsigned int* __restrict__ dtu1,
                                               const float* __restrict__ dbc2,
                                               const unsigned short* __restrict__ z2,
                                               const float* __restrict__ Alog_f,
                                               const float* __restrict__ Alog_b,
                                               const float* __restrict__ Dp_f,
                                               const float* __restrict__ Dp_b,
                                               const float* __restrict__ h0,
                                               unsigned short* __restrict__ G2) {
    int c     = blockIdx.x * 256 + threadIdx.x;
    int chunk = blockIdx.y;
    int z     = blockIdx.z;
    int br = z & 1, b = z >> 1;

    const unsigned int* dtu = br ? dtu1 : dtu0;
    const float* dbc   = dbc2 + (size_t)br * BLROWS * 96;
    const float* A_log = br ? Alog_b : Alog_f;
    const float* Dp    = br ? Dp_b : Dp_f;

    __shared__ float BCs[CLEN][32];
    for (int i = threadIdx.x; i < CLEN * 32; i += 256) {
        int s = i >> 5, j = i & 31;
        int sigma = chunk * CLEN + s;
        int t = br ? (LSEQ - 1 - sigma) : sigma;
        BCs[s][j] = dbc[((size_t)b * LSEQ + t) * 96 + DTR + j];
    }
    __syncthreads();

    int sigma0 = chunk * CLEN;
    int t0 = br ? (LSEQ - 1 - sigma0) : sigma0;
    long long row0 = (long long)b * LSEQ + t0;
    long long rsgn = br ? -1 : 1;
    const unsigned int* dp = dtu + row0 * DI + c;
    long long dstr = rsgn * DI;
    const unsigned short* zp = z2 + row0 * 4096 + br * 2048 + c;
    long long zstr = rsgn * 4096;
    unsigned short* gp = G2 + row0 * (2 * DI) + br * DI + c;
    long long gstr = rsgn * (2 * DI);

    const float LOG2E = 1.4426950408889634f;
    float A2[16], h[16];
    size_t base = (((size_t)z * NCHUNK + chunk) * DI + c) * DST;
#pragma unroll
    for (int n = 0; n < 16; n++)
        A2[n] = -__expf(A_log[c * DST + n]) * LOG2E;
#pragma unroll
    for (int q = 0; q < 4; q++)
        *reinterpret_cast<f32x4*>(&h[q * 4]) = *reinterpret_cast<const f32x4*>(&h0[base + q * 4]);
    float Dv = Dp[c];

    unsigned int pkA[8], pkB[8];
    unsigned short zA[8], zB[8];
    PF3(pkA, zA, 0)
    PF3(pkB, zB, 8)
    CG3(pkA, zA, 0)
    PF3(pkA, zA, 16)
    CG3(pkB, zB, 8)
    PF3(pkB, zB, 24)
    CG3(pkA, zA, 16)
    CG3(pkB, zB, 24)
}

// ---------------------------------------------------------------------------
extern "C" void kernel_launch(void* const* d_in, const int* in_sizes, int n_in,
                              void* d_out, int out_size, void* d_ws, size_t ws_size,
                              hipStream_t stream) {
    const float* x    = (const float*)d_in[0];
    const float* ln_g = (const float*)d_in[1];
    const float* ln_b = (const float*)d_in[2];
    float* out = (float*)d_out;

    char* wp = (char*)d_ws;
    // R0 (4MB): xnb; after in-proj: dbc2 (1.5MB) + dbcb2 (0.5MB) + dtsum (1MB)
    unsigned short* xnb = (unsigned short*)wp;                 wp += (size_t)BLROWS * DM * 2;
    // R1 (16MB): z2 [2048][4096] bf16, live till p3
    unsigned short* z2  = (unsigned short*)wp;                 wp += (size_t)BLROWS * 4096 * 2;
    // R2 (16MB): u2 (dead after conv) -> dtu0 [2048][2048] u32
    unsigned short* u2  = (unsigned short*)wp;                 wp += (size_t)BLROWS * 4096 * 2;
    // R3 (16MB): in_wb2 -> partial(xproj) -> dtu1 [2048][2048] u32 (dead after p3)
    //            -> partial2b (2 x 8MB f32)
    unsigned short* in_wb2 = (unsigned short*)wp;              wp += (size_t)4 * DI * DM * 2;
    // R4 (16MB): ucb2 [2][2048][2048] bf16 (dead after dt GEMM) -> hend (16MB)
    //            -> after p2: front 8MB = out_wb2
    unsigned short* ucb2 = (unsigned short*)wp;                wp += (size_t)2 * BLROWS * DI * 2;
    // R5 (16MB): h0 [NSEQ][NCHUNK][DI][DST] f32 (dead after p3) -> partial2a
    float* h0r = (float*)wp;                                   wp += (size_t)NSEQ * NCHUNK * DI * DST * 4;
    // R6 (16MB): G2 [2048][4096] bf16
    unsigned short* G2 = (unsigned short*)wp;                  wp += (size_t)BLROWS * 2 * DI * 2;
    // R7: xprojb2 [2][128][2048] bf16 (1MB) + dt_wb2 [2][2048][64] bf16 (0.5MB)
    unsigned short* xprojb2 = (unsigned short*)wp;             wp += (size_t)2 * 128 * DI * 2;
    unsigned short* dt_wb2  = (unsigned short*)wp;             wp += (size_t)2 * DI * DTR * 2;
    // total = 101.5 MB

    // aliases (lifetime-audited)
    float* dbc2           = (float*)xnb;                           // [2][2048][96] f32
    unsigned short* dbcb2 = xnb + (size_t)2 * BLROWS * 96 * 2;     // [2][2048][64] bf16 (after full dbc2)
    float* dtsum          = (float*)((char*)xnb + 2097152);        // [NSEQ][NCHUNK][DI] f32, 1MB
    unsigned int* dtu0    = (unsigned int*)u2;                     // R2
    float* partial        = (float*)in_wb2;                        // R3 (xproj split-K)
    unsigned int* dtu1    = (unsigned int*)in_wb2;                 // R3 (after reduce_dbc)
    float* hend           = (float*)ucb2;                          // R4 (after dt GEMM)
    unsigned short* out_wb2 = ucb2;                                // R4 front 8MB (after p2)
    float* h0             = h0r;                                   // R5
    float* partial2a      = h0r;                                   // R5 (after p3): slices 0,1
    float* partial2b      = (float*)in_wb2;                        // R3 (after p3): slices 2,3

    // 1. LayerNorm -> xnb
    ln_kernel<<<BLROWS, 256, 0, stream>>>(x, ln_g, ln_b, xnb);

    // 2. cast both in_w into [8192][1024] (one dispatch)
    cast2_kernel<<<dim3((2 * DI * DM) / 1024, 2), 256, 0, stream>>>(
        (const float*)d_in[3], (const float*)d_in[12], in_wb2, 2 * DI * DM);

    // 3. batched in-proj (2048 x 8192 x 1024) -> u2 / z2 (bf16, routed)
    gemm_mfma<6><<<dim3(4 * DI / 128, BLROWS / 128, 1), 256, 0, stream>>>(
        xnb, in_wb2, nullptr, nullptr, nullptr, u2, z2, 4096, DM, DM, 0, 0);

    // 4. conv + SiLU, both branches, 8 ch/thread -> ucb2
    conv_silu8<<<dim3((BLROWS * DI) / (256 * 8), 2), 256, 0, stream>>>(
        u2, (const float*)d_in[4], (const float*)d_in[5],
        (const float*)d_in[13], (const float*)d_in[14], ucb2);

    // 5. weight prep (both branches, batched)
    padcast_xproj2<<<dim3((128 * DI) / 1024, 2), 256, 0, stream>>>(
        (const float*)d_in[6], (const float*)d_in[15], xprojb2);
    cast2_kernel<<<dim3((DI * DTR) / 1024, 2), 256, 0, stream>>>(
        (const float*)d_in[7], (const float*)d_in[16], dt_wb2, DI * DTR);

    // 6. xproj both branches: M=4096, split-K 8 -> partial (R3)
    gemm_mfma<8><<<dim3(1, 4096 / 128, KSPL), 256, 0, stream>>>(
        ucb2, xprojb2, nullptr, nullptr, nullptr, partial, nullptr,
        128, DI, DI / KSPL, (size_t)4096 * 128, 128 * DI);
    reduce_dbc<<<(4096 * 96) / 256, 256, 0, stream>>>(partial, dbc2, dbcb2);

    // 7. dt GEMM both branches (M=4096), packed epilogue -> dtu0/dtu1
    gemm_mfma<7><<<dim3(DI / 128, 4096 / 128, 1), 256, 0, stream>>>(
        dbcb2, dt_wb2, (const float*)d_in[8], (const float*)d_in[17], ucb2,
        dtu0, dtu1, DI, DTR, DTR, 0, DI * DTR);

    // 8. scan phase 1 + combine
    scan_p1<<<dim3(DI / 256, NCHUNK, NSEQ), 256, 0, stream>>>(
        dtu0, dtu1, dbc2, (const float*)d_in[9], (const float*)d_in[18],
        hend, dtsum);
    scan_p2<<<(NSEQ * DI * DST) / 256, 256, 0, stream>>>(
        hend, dtsum, (const float*)d_in[9], (const float*)d_in[18], h0);

    // 9. cast out_w pair into R4 front (hend dead after p2)
    cast_cc2<<<dim3((DM * DI) / 1024, 2), 256, 0, stream>>>(
        (const float*)d_in[11], (const float*)d_in[20], out_wb2);

    // 10. scan phase 3 -> G2
    scan_p3<<<dim3(DI / 256, NCHUNK, NSEQ), 256, 0, stream>>>(
        dtu0, dtu1, dbc2, z2, (const float*)d_in[9], (const float*)d_in[18],
        (const float*)d_in[10], (const float*)d_in[19], h0, G2);

    // 11. combined out-proj (K=4096, split-K 4 -> 512 blocks) + reduce
    gemm_mfma<9><<<dim3(DM / 128, BLROWS / 128, 4), 256, 0, stream>>>(
        G2, out_wb2, nullptr, nullptr, nullptr, partial2a, partial2b,
        DM, 2 * DI, DI / 2, (size_t)BLROWS * DM, 0);
    reduce_out4<<<(BLROWS * DM) / 1024, 256, 0, stream>>>(partial2a, partial2b, x, out);
}